// Round 11
// baseline (585.887 us; speedup 1.0000x reference)
//
#include <hip/hip_runtime.h>

// Problem constants
static constexpr int NG   = 100000;
static constexpr int NC   = 2000;
static constexpr int D    = 256;
static constexpr int NE   = 1000000;
static constexpr int NOUTD= 64;
static constexpr int KCAT = 768;          // concatenated K: [agg | x | v]

typedef __bf16 bf16x8 __attribute__((ext_vector_type(8)));
typedef float  f32x4  __attribute__((ext_vector_type(4)));

__device__ __forceinline__ unsigned short f2bf(float f) {
    unsigned u = __float_as_uint(f);
    u += 0x7fffu + ((u >> 16) & 1u);   // RNE
    return (unsigned short)(u >> 16);
}
__device__ __forceinline__ float bflo(unsigned x) { return __uint_as_float((x & 0xffffu) << 16); }
__device__ __forceinline__ float bfhi(unsigned x) { return __uint_as_float(x & 0xffff0000u); }

__device__ __forceinline__ void async16(const void* g, void* l) {
    __builtin_amdgcn_global_load_lds(
        (const __attribute__((address_space(1))) void*)g,
        (__attribute__((address_space(3))) void*)l, 16, 0, 0);
}

// ---------------- prep (cells only): f32 -> bf16 x and v=x*w ----------------
__global__ void prep_x(const float* __restrict__ x, const float* __restrict__ w,
                       unsigned short* __restrict__ dx, unsigned short* __restrict__ dv,
                       long stride, int rows) {
    int i = blockIdx.x * blockDim.x + threadIdx.x;   // one per 4 elements
    if (i >= rows * (D / 4)) return;
    int row = i >> 6, c4 = (i & 63) * 4;
    float4 xv = *reinterpret_cast<const float4*>(x + (size_t)row * D + c4);
    float wv = w[row];
    uint2 ox, ov;
    ox.x = (unsigned)f2bf(xv.x) | ((unsigned)f2bf(xv.y) << 16);
    ox.y = (unsigned)f2bf(xv.z) | ((unsigned)f2bf(xv.w) << 16);
    ov.x = (unsigned)f2bf(xv.x * wv) | ((unsigned)f2bf(xv.y * wv) << 16);
    ov.y = (unsigned)f2bf(xv.z * wv) | ((unsigned)f2bf(xv.w * wv) << 16);
    *reinterpret_cast<uint2*>(dx + (size_t)row * stride + c4) = ox;
    *reinterpret_cast<uint2*>(dv + (size_t)row * stride + c4) = ov;
}

// -------- build weight mats + bias sums -------------------------------------
// y=0: gene L0 (ia=1, ib=2) -> PACKED fragment-major Wg0p (round 11):
//   element (n,k_global) lives at ((n>>4)*24 + kslot)*64 + ln, byte-lane e,
//   kslot = k_global>>5, ln = ((k>>3)&3)*16 + (n&15), e = k&7. A wave's
//   MFMA B-fragment load becomes 64 lanes x 16B = 1KB CONTIGUOUS (L2-hit).
// y=1: cell L0 (0,3), y=2: cell L1 (4,7) -> flat [256][768] (gemm_tile).
__global__ void build_wcat3(const float* __restrict__ Wrel, const float* __restrict__ Wroot,
                            const float* __restrict__ brel,
                            unsigned short* __restrict__ Wg0p, unsigned short* __restrict__ Wc0,
                            unsigned short* __restrict__ Wc1,
                            float* __restrict__ bg0, float* __restrict__ bc0,
                            float* __restrict__ bc1) {
    int i = blockIdx.x * blockDim.x + threadIdx.x;
    if (i >= D * D) return;
    const int WW = D * D;
    int n = i >> 8, k = i & 255;
    if (blockIdx.y == 0) {
        int r16 = n >> 4, lm = n & 15;
        int kslot = k >> 5, lq = (k >> 3) & 3, e = k & 7;
        int ln = lq * 16 + lm;
        size_t base = ((size_t)r16 * 24) * 64 * 8;
        Wg0p[base + ((size_t)(kslot     ) * 64 + ln) * 8 + e] = f2bf(Wrel[1 * WW + i]);
        Wg0p[base + ((size_t)(8  + kslot) * 64 + ln) * 8 + e] = f2bf(Wroot[1 * WW + i] + Wroot[2 * WW + i]);
        Wg0p[base + ((size_t)(16 + kslot) * 64 + ln) * 8 + e] = f2bf(Wrel[2 * WW + i]);
        if (i < D) bg0[i] = brel[1 * D + i] + brel[2 * D + i];
        return;
    }
    int ia, ib; unsigned short* wout; float* bsum;
    if (blockIdx.y == 1) { ia = 0; ib = 3; wout = Wc0; bsum = bc0; }
    else                 { ia = 4; ib = 7; wout = Wc1; bsum = bc1; }
    wout[(size_t)n * KCAT + k]        = f2bf(Wrel[ia * WW + i]);
    wout[(size_t)n * KCAT + 256 + k]  = f2bf(Wroot[ia * WW + i] + Wroot[ib * WW + i]);
    wout[(size_t)n * KCAT + 512 + k]  = f2bf(Wrel[ib * WW + i]);
    if (i < D) bsum[i] = brel[ia * D + i] + brel[ib * D + i];
}

// ------ coarse histogram (256 bins/relation) + fused x_gene conversion ------
static constexpr int CC_CHUNK = 8192;
static constexpr int CCB = (NE + CC_CHUNK - 1) / CC_CHUNK;   // 123
static constexpr int CONVB = NG * (D / 4) / 256;             // 25000
__global__ __launch_bounds__(256) void coarse_count_conv(
        const int* __restrict__ dst_g2c, const int* __restrict__ dst_c2g,
        int* __restrict__ hist,                               // [512]
        const float* __restrict__ x_gene, unsigned short* __restrict__ xg0b) {
    __shared__ int h[512];
    if (blockIdx.x >= CCB) {
        int i = (blockIdx.x - CCB) * 256 + threadIdx.x;       // quarter-row id
        int row = i >> 6, c4 = (i & 63) * 4;
        float4 xv = *reinterpret_cast<const float4*>(x_gene + (size_t)row * D + c4);
        uint2 xo;
        xo.x = (unsigned)f2bf(xv.x) | ((unsigned)f2bf(xv.y) << 16);
        xo.y = (unsigned)f2bf(xv.z) | ((unsigned)f2bf(xv.w) << 16);
        *reinterpret_cast<uint2*>(xg0b + (size_t)row * D + c4) = xo;
        return;
    }
    h[threadIdx.x] = 0; h[256 + threadIdx.x] = 0;
    __syncthreads();
    int base = blockIdx.x * CC_CHUNK;
#pragma unroll 4
    for (int t = 0; t < CC_CHUNK / 256; ++t) {
        int e = base + t * 256 + threadIdx.x;
        if (e < NE) {
            atomicAdd(&h[dst_g2c[e] >> 3], 1);          // cell bins
            atomicAdd(&h[256 + (dst_c2g[e] >> 9)], 1);  // gene bins
        }
    }
    __syncthreads();
    if (h[threadIdx.x]) atomicAdd(&hist[threadIdx.x], h[threadIdx.x]);
    if (h[256 + threadIdx.x]) atomicAdd(&hist[256 + threadIdx.x], h[256 + threadIdx.x]);
}

// ---- coarse scan: cbase[0..256]=cells, cbase[257..513]=genes; init cursors -
__global__ __launch_bounds__(256) void coarse_scan(const int* __restrict__ hist,
                                                   int* __restrict__ cbase,
                                                   int* __restrict__ ccur_c, int* __restrict__ ccur_g,
                                                   int* __restrict__ rp_c, int* __restrict__ rp_g) {
    __shared__ int sd[256];
    int t = threadIdx.x;
    {
        int v = hist[t];
        sd[t] = v; __syncthreads();
        for (int off = 1; off < 256; off <<= 1) {
            int u = (t >= off) ? sd[t - off] : 0; __syncthreads();
            sd[t] += u; __syncthreads();
        }
        int e = sd[t] - v;
        cbase[t] = e; ccur_c[t] = e;
        if (t == 255) cbase[256] = sd[255];
        __syncthreads();
    }
    {
        int v = hist[256 + t];
        sd[t] = v; __syncthreads();
        for (int off = 1; off < 256; off <<= 1) {
            int u = (t >= off) ? sd[t - off] : 0; __syncthreads();
            sd[t] += u; __syncthreads();
        }
        int e = sd[t] - v;
        cbase[257 + t] = e; ccur_g[t] = e;
        if (t == 255) cbase[513] = sd[255];
    }
    if (t == 0) { rp_c[NC] = NE; rp_g[NG] = NE; }
}

// pass1 (fused c/g via blockIdx.y): scatter edges into 256 coarse buckets
static constexpr int P1_CHUNK = 8192;
__global__ __launch_bounds__(256) void bucket_pass1(
        const int* __restrict__ srcA, const int* __restrict__ dstA, const float* __restrict__ wA,
        int* __restrict__ curA, int2* __restrict__ outA,
        const int* __restrict__ srcB, const int* __restrict__ dstB, const float* __restrict__ wB,
        int* __restrict__ curB, int2* __restrict__ outB) {
    __shared__ int hist[256], lcur[256], gbase[256];
    const int* src; const int* dst; const float* w; int* coarse_cur; int2* out;
    int shift, packshift;
    if (blockIdx.y == 0) { src = srcA; dst = dstA; w = wA; coarse_cur = curA; out = outA; shift = 3; packshift = 17; }
    else { src = srcB; dst = dstB; w = wB; coarse_cur = curB; out = outB; shift = 9; packshift = 11; }
    int tid = threadIdx.x;
    hist[tid] = 0;
    __syncthreads();
    int base = blockIdx.x * P1_CHUNK;
    int mybin[P1_CHUNK / 256];
#pragma unroll
    for (int t = 0; t < P1_CHUNK / 256; ++t) {
        int e = base + t * 256 + tid;
        if (e < NE) {
            int b = dst[e] >> shift;
            mybin[t] = b;
            atomicAdd(&hist[b], 1);
        } else mybin[t] = -1;
    }
    __syncthreads();
    int v = hist[tid];
    gbase[tid] = v ? atomicAdd(&coarse_cur[tid], v) : 0;
    lcur[tid] = 0;
    __syncthreads();
#pragma unroll
    for (int t = 0; t < P1_CHUNK / 256; ++t) {
        int b = mybin[t];
        if (b < 0) continue;
        int e = base + t * 256 + tid;
        int pos = gbase[b] + atomicAdd(&lcur[b], 1);
        int dl = dst[e] & ((1 << shift) - 1);
        out[pos] = make_int2(src[e] | (dl << packshift), __float_as_int(w[e]));
    }
}

// pass2 (fused): per bucket — fine LDS histogram + scan emits rp, then scatter
static constexpr int P2_CBLK = NC / 8;                 // 250
static constexpr int P2_GBLK = (NG + 511) / 512;       // 196
__global__ __launch_bounds__(256) void bucket_pass2(
        const int2* __restrict__ stC, int2* __restrict__ outC, int* __restrict__ rpC,
        const int2* __restrict__ stG, int2* __restrict__ outG, int* __restrict__ rpG,
        const int* __restrict__ cbase) {
    __shared__ int hist[512], cur[512], sd[256];
    const int2* staged; int2* out; int* rp; const int* cb;
    int shift, packshift, ndst, b;
    if (blockIdx.x < P2_CBLK) {
        staged = stC; out = outC; rp = rpC; cb = cbase;
        shift = 3; packshift = 17; ndst = NC; b = blockIdx.x;
    } else {
        staged = stG; out = outG; rp = rpG; cb = cbase + 257;
        shift = 9; packshift = 11; ndst = NG; b = blockIdx.x - P2_CBLK;
    }
    int tid = threadIdx.x;
    int nf = 1 << shift;
    int d0 = b << shift;
    int j0 = cb[b], j1 = cb[b + 1];
    for (int f = tid; f < nf; f += 256) hist[f] = 0;
    __syncthreads();
    for (int j = j0 + tid; j < j1; j += 256)
        atomicAdd(&hist[((unsigned)staged[j].x) >> packshift], 1);
    __syncthreads();
    // exclusive scan over hist[0..nf)
    int chunk = (nf + 255) >> 8;                 // 1 or 2
    int s = 0;
#pragma unroll 2
    for (int k = 0; k < chunk; ++k) {
        int idx = tid * chunk + k;
        if (idx < nf) s += hist[idx];
    }
    sd[tid] = s; __syncthreads();
    for (int off = 1; off < 256; off <<= 1) {
        int u = (tid >= off) ? sd[tid - off] : 0; __syncthreads();
        sd[tid] += u; __syncthreads();
    }
    int run = sd[tid] - s;                       // exclusive base for this thread's chunk
#pragma unroll 2
    for (int k = 0; k < chunk; ++k) {
        int idx = tid * chunk + k;
        if (idx < nf) {
            int h = hist[idx];
            int pos = j0 + run;
            cur[idx] = pos;
            int d = d0 + idx;
            if (d < ndst) rp[d] = pos;
            run += h;
        }
    }
    __syncthreads();
    // scatter within the bucket's contiguous (cache-local) output region
    for (int j = j0 + tid; j < j1; j += 256) {
        int2 e = staged[j];
        int f = ((unsigned)e.x) >> packshift;
        int pos = atomicAdd(&cur[f], 1);
        out[pos] = make_int2(e.x & ((1 << packshift) - 1), e.y);
    }
}

// --------------- gene aggregation: one wave per destination row -------------
// Pure gather. Scalar edge records (readfirstlane'd j0/j1 -> s_loads),
// half-wave 2-edges-per-uint4 gathers, 2 in flight.
__global__ void agg_gene(const int* __restrict__ rp, const int2* __restrict__ eg,
                         const unsigned short* __restrict__ src, long sstride,
                         unsigned short* __restrict__ agg_out, int nrows) {
    int wave = (blockIdx.x * blockDim.x + threadIdx.x) >> 6;
    int lane = threadIdx.x & 63;
    if (wave >= nrows) return;
    int j0 = __builtin_amdgcn_readfirstlane(rp[wave]);
    int j1 = __builtin_amdgcn_readfirstlane(rp[wave + 1]);
    int half = lane >> 5;        // 0: edge A, 1: edge B of each gather pair
    int lh = lane & 31;          // 16B slot within the 512B row
    float a0=0.f,a1=0.f,a2=0.f,a3=0.f,a4=0.f,a5=0.f,a6=0.f,a7=0.f;
    int j = j0;
    for (; j + 4 <= j1; j += 4) {
        int2 e0 = eg[j], e1 = eg[j + 1], e2 = eg[j + 2], e3 = eg[j + 3];
        int   rA = half ? e1.x : e0.x;
        float wA = __int_as_float(half ? e1.y : e0.y);
        int   rB = half ? e3.x : e2.x;
        float wB = __int_as_float(half ? e3.y : e2.y);
        uint4 pA = *reinterpret_cast<const uint4*>(src + (size_t)rA * sstride + lh * 8);
        uint4 pB = *reinterpret_cast<const uint4*>(src + (size_t)rB * sstride + lh * 8);
        a0 += wA * bflo(pA.x) + wB * bflo(pB.x);
        a1 += wA * bfhi(pA.x) + wB * bfhi(pB.x);
        a2 += wA * bflo(pA.y) + wB * bflo(pB.y);
        a3 += wA * bfhi(pA.y) + wB * bfhi(pB.y);
        a4 += wA * bflo(pA.z) + wB * bflo(pB.z);
        a5 += wA * bfhi(pA.z) + wB * bfhi(pB.z);
        a6 += wA * bflo(pA.w) + wB * bflo(pB.w);
        a7 += wA * bfhi(pA.w) + wB * bfhi(pB.w);
    }
    for (; j < j1; j += 2) {
        int2 e0 = eg[j];
        int2 e1 = (j + 1 < j1) ? eg[j + 1] : make_int2(e0.x, 0);  // w=0 pad
        int   r = half ? e1.x : e0.x;
        float w = __int_as_float(half ? e1.y : e0.y);
        uint4 p = *reinterpret_cast<const uint4*>(src + (size_t)r * sstride + lh * 8);
        a0 += w * bflo(p.x); a1 += w * bfhi(p.x);
        a2 += w * bflo(p.y); a3 += w * bfhi(p.y);
        a4 += w * bflo(p.z); a5 += w * bfhi(p.z);
        a6 += w * bflo(p.w); a7 += w * bfhi(p.w);
    }
    // combine the two half-wave partials
    a0 += __shfl_xor(a0, 32, 64); a1 += __shfl_xor(a1, 32, 64);
    a2 += __shfl_xor(a2, 32, 64); a3 += __shfl_xor(a3, 32, 64);
    a4 += __shfl_xor(a4, 32, 64); a5 += __shfl_xor(a5, 32, 64);
    a6 += __shfl_xor(a6, 32, 64); a7 += __shfl_xor(a7, 32, 64);
    if (lane < 32) {
        uint4 o;
        o.x = (unsigned)f2bf(a0) | ((unsigned)f2bf(a1) << 16);
        o.y = (unsigned)f2bf(a2) | ((unsigned)f2bf(a3) << 16);
        o.z = (unsigned)f2bf(a4) | ((unsigned)f2bf(a5) << 16);
        o.w = (unsigned)f2bf(a6) | ((unsigned)f2bf(a7) << 16);
        *reinterpret_cast<uint4*>(agg_out + (size_t)wave * D + lane * 8) = o;
    }
}

// ---------------- gene GEMM: xg1 = relu(agg@W1^T + x@Wc^T + w*(x@W2^T) + b) -
// Round 11: B operands load DIRECTLY from the fragment-packed Wg0p — each
// b[j] is 64 lanes x 16B = 1KB contiguous (L2-resident, coalesced), so no
// Bs LDS staging. LDS 48 -> 16 KB (As only); B-loads decouple from the
// per-k-step vmcnt(0) barrier drain. (Round 8's failure was SCATTERED
// direct loads — 16 lines per instr; packed layout makes them 1 line-run.)
__global__ __launch_bounds__(256, 2) void gene_gemm(
        const unsigned short* __restrict__ Agg,  // [NG][256] bf16
        const unsigned short* __restrict__ Xb,   // [NG][256] bf16
        const float* __restrict__ w_gg,          // [NG]
        const unsigned short* __restrict__ Wp,   // packed [16][24][64][8] bf16
        const float* __restrict__ bias,          // [256]
        unsigned short* __restrict__ xg1) {      // out [NG][256]
    __shared__ unsigned short As[128 * 64];      // 16 KB (A-tile only)
    const bf16x8* Wpf = reinterpret_cast<const bf16x8*>(Wp);
    int tid = threadIdx.x;
    int wv = tid >> 6, ln = tid & 63;
    int lm = ln & 15, lq = ln >> 4;
    int m0 = blockIdx.x * 128;
    int nb = blockIdx.y * 128;
    int m0w = m0 + (wv >> 1) * 64;
    int n0w = nb + (wv & 1) * 64;
    int rbase = (nb >> 4) + (wv & 1) * 4;        // packed row-group base (+j)

    f32x4 accA[4][4], accV[4][4];
#pragma unroll
    for (int i = 0; i < 4; ++i)
#pragma unroll
        for (int j = 0; j < 4; ++j) { accA[i][j] = f32x4{0,0,0,0}; accV[i][j] = f32x4{0,0,0,0}; }

    // ---- segment A: agg @ Wrel1^T (kslot 0..7) ----
    for (int k0 = 0; k0 < 256; k0 += 64) {
#pragma unroll
        for (int t = 0; t < 4; ++t) {
            int ci = t * 256 + tid;
            int r = ci >> 3, s = ci & 7;
            int cg = s ^ (r & 7);
            int row = m0 + r; if (row >= NG) row = NG - 1;
            async16(Agg + (size_t)row * D + k0 + cg * 8, (unsigned char*)As + ci * 16);
        }
        __syncthreads();
#pragma unroll
        for (int kk = 0; kk < 2; ++kk) {
            bf16x8 a[4], b[4];
#pragma unroll
            for (int i = 0; i < 4; ++i) {
                int r = (wv >> 1) * 64 + i * 16 + lm;
                int s = (kk * 4 + lq) ^ (r & 7);
                a[i] = *reinterpret_cast<const bf16x8*>(As + (r * 8 + s) * 8);
            }
            int kslot = (k0 >> 5) + kk;
#pragma unroll
            for (int j = 0; j < 4; ++j)
                b[j] = Wpf[((size_t)(rbase + j) * 24 + kslot) * 64 + ln];
#pragma unroll
            for (int i = 0; i < 4; ++i)
#pragma unroll
                for (int j = 0; j < 4; ++j)
                    accA[i][j] = __builtin_amdgcn_mfma_f32_16x16x32_bf16(a[i], b[j], accA[i][j], 0, 0, 0);
        }
        __syncthreads();
    }

    // ---- segment X: x @ (Wroot1+Wroot2)^T (kslot 8..15) into accA,
    //                 x @ Wrel2^T (kslot 16..23) into accV ----
    for (int k0 = 0; k0 < 256; k0 += 64) {
#pragma unroll
        for (int t = 0; t < 4; ++t) {
            int ci = t * 256 + tid;
            int r = ci >> 3, s = ci & 7;
            int cg = s ^ (r & 7);
            int row = m0 + r; if (row >= NG) row = NG - 1;
            async16(Xb + (size_t)row * D + k0 + cg * 8, (unsigned char*)As + ci * 16);
        }
        __syncthreads();
#pragma unroll
        for (int kk = 0; kk < 2; ++kk) {
            bf16x8 a[4], b1[4], b2[4];
#pragma unroll
            for (int i = 0; i < 4; ++i) {
                int r = (wv >> 1) * 64 + i * 16 + lm;
                int s = (kk * 4 + lq) ^ (r & 7);
                a[i] = *reinterpret_cast<const bf16x8*>(As + (r * 8 + s) * 8);
            }
            int kslot = (k0 >> 5) + kk;
#pragma unroll
            for (int j = 0; j < 4; ++j) {
                b1[j] = Wpf[((size_t)(rbase + j) * 24 + 8  + kslot) * 64 + ln];
                b2[j] = Wpf[((size_t)(rbase + j) * 24 + 16 + kslot) * 64 + ln];
            }
#pragma unroll
            for (int i = 0; i < 4; ++i)
#pragma unroll
                for (int j = 0; j < 4; ++j) {
                    accA[i][j] = __builtin_amdgcn_mfma_f32_16x16x32_bf16(a[i], b1[j], accA[i][j], 0, 0, 0);
                    accV[i][j] = __builtin_amdgcn_mfma_f32_16x16x32_bf16(a[i], b2[j], accV[i][j], 0, 0, 0);
                }
        }
        __syncthreads();
    }

    // ---- epilogue ----
#pragma unroll
    for (int i = 0; i < 4; ++i) {
#pragma unroll
        for (int r4 = 0; r4 < 4; ++r4) {
            int row = m0w + i * 16 + lq * 4 + r4;
            if (row >= NG) continue;
            float wr = w_gg[row];
#pragma unroll
            for (int j = 0; j < 4; ++j) {
                int col = n0w + j * 16 + lm;
                float v = accA[i][j][r4] + wr * accV[i][j][r4] + bias[col];
                v = v > 0.f ? v : 0.f;
                xg1[(size_t)row * D + col] = f2bf(v);
            }
        }
    }
}

// ---------------- cell aggregation: one block per cell, LDS reduce ----------
// Half-wave 2-edges-per-uint4 gathers with scalar edge records.
// 4 waves x 4 edges (2 gathers in flight each) = 16 edges per block-iter.
__global__ __launch_bounds__(256) void agg_cell(const int* __restrict__ rp,
                                                const int2* __restrict__ ec,
                                                const unsigned short* __restrict__ src, long sstride,
                                                unsigned short* __restrict__ out, long ostride) {
    __shared__ float red[4][D];
    int c = blockIdx.x;
    int wv = threadIdx.x >> 6, ln = threadIdx.x & 63;
    int half = ln >> 5, lh = ln & 31;
    int j0 = __builtin_amdgcn_readfirstlane(rp[c]);
    int j1 = __builtin_amdgcn_readfirstlane(rp[c + 1]);
    float a0=0.f,a1=0.f,a2=0.f,a3=0.f,a4=0.f,a5=0.f,a6=0.f,a7=0.f;
    int n16 = (j1 - j0) & ~15;         // chunks of 16 = 4 waves x 4 edges
    for (int j = j0 + wv * 4; j < j0 + n16; j += 16) {
        int2 e0 = ec[j], e1 = ec[j + 1], e2 = ec[j + 2], e3 = ec[j + 3];
        int   rA = half ? e1.x : e0.x;
        float wA = __int_as_float(half ? e1.y : e0.y);
        int   rB = half ? e3.x : e2.x;
        float wB = __int_as_float(half ? e3.y : e2.y);
        uint4 pA = *reinterpret_cast<const uint4*>(src + (size_t)rA * sstride + lh * 8);
        uint4 pB = *reinterpret_cast<const uint4*>(src + (size_t)rB * sstride + lh * 8);
        a0 += wA * bflo(pA.x) + wB * bflo(pB.x);
        a1 += wA * bfhi(pA.x) + wB * bfhi(pB.x);
        a2 += wA * bflo(pA.y) + wB * bflo(pB.y);
        a3 += wA * bfhi(pA.y) + wB * bfhi(pB.y);
        a4 += wA * bflo(pA.z) + wB * bflo(pB.z);
        a5 += wA * bfhi(pA.z) + wB * bfhi(pB.z);
        a6 += wA * bflo(pA.w) + wB * bflo(pB.w);
        a7 += wA * bfhi(pA.w) + wB * bfhi(pB.w);
    }
    // tail: <=15 edges, pairs round-robin across waves, w=0 padding
    for (int j = j0 + n16 + wv * 2; j < j1; j += 8) {
        int2 e0 = ec[j];
        int2 e1 = (j + 1 < j1) ? ec[j + 1] : make_int2(e0.x, 0);
        int   r = half ? e1.x : e0.x;
        float w = __int_as_float(half ? e1.y : e0.y);
        uint4 p = *reinterpret_cast<const uint4*>(src + (size_t)r * sstride + lh * 8);
        a0 += w * bflo(p.x); a1 += w * bfhi(p.x);
        a2 += w * bflo(p.y); a3 += w * bfhi(p.y);
        a4 += w * bflo(p.z); a5 += w * bfhi(p.z);
        a6 += w * bflo(p.w); a7 += w * bfhi(p.w);
    }
    // combine half-wave partials, then cross-wave LDS reduce
    a0 += __shfl_xor(a0, 32, 64); a1 += __shfl_xor(a1, 32, 64);
    a2 += __shfl_xor(a2, 32, 64); a3 += __shfl_xor(a3, 32, 64);
    a4 += __shfl_xor(a4, 32, 64); a5 += __shfl_xor(a5, 32, 64);
    a6 += __shfl_xor(a6, 32, 64); a7 += __shfl_xor(a7, 32, 64);
    if (ln < 32) {
        *reinterpret_cast<float4*>(&red[wv][lh * 8])     = make_float4(a0, a1, a2, a3);
        *reinterpret_cast<float4*>(&red[wv][lh * 8 + 4]) = make_float4(a4, a5, a6, a7);
    }
    __syncthreads();
    int col = threadIdx.x;
    float s = red[0][col] + red[1][col] + red[2][col] + red[3][col];
    out[(size_t)c * ostride + col] = f2bf(s);
}

// ---------------- m97-style GEMM (cells): relu(A[M,768] @ W^T + bias) -------
__global__ __launch_bounds__(256, 2) void gemm_tile(
        const unsigned short* __restrict__ A,    // [M][768]
        const unsigned short* __restrict__ W,    // [256][768]
        const float* __restrict__ bias,          // [256]
        const float* __restrict__ wrow,          // nullable per-row scale for vout
        unsigned short* __restrict__ xout, long xstride,
        unsigned short* __restrict__ vout,       // nullable, same stride
        int M) {
    __shared__ unsigned short As[128 * 64];
    __shared__ unsigned short Bs[128 * 64];
    int tid = threadIdx.x;
    int wv = tid >> 6, ln = tid & 63;
    int lm = ln & 15, lq = ln >> 4;
    int m0 = blockIdx.x * 128;
    int nb = blockIdx.y * 128;
    int m0w = m0 + (wv >> 1) * 64;
    int n0w = nb + (wv & 1) * 64;

    f32x4 acc[4][4];
#pragma unroll
    for (int i = 0; i < 4; ++i)
#pragma unroll
        for (int j = 0; j < 4; ++j) acc[i][j] = f32x4{0.f, 0.f, 0.f, 0.f};

    for (int k0 = 0; k0 < KCAT; k0 += 64) {
#pragma unroll
        for (int t = 0; t < 4; ++t) {
            int ci = t * 256 + tid;
            int r = ci >> 3, s = ci & 7;
            int cg = s ^ (r & 7);
            int row = m0 + r; if (row >= M) row = M - 1;
            async16(A + (size_t)row * KCAT + k0 + cg * 8,
                    (unsigned char*)As + ci * 16);
        }
#pragma unroll
        for (int t = 0; t < 4; ++t) {
            int ci = t * 256 + tid;
            int r = ci >> 3, s = ci & 7;
            int cg = s ^ (r & 7);
            async16(W + (size_t)(nb + r) * KCAT + k0 + cg * 8,
                    (unsigned char*)Bs + ci * 16);
        }
        __syncthreads();
#pragma unroll
        for (int kk = 0; kk < 2; ++kk) {
            bf16x8 a[4], b[4];
#pragma unroll
            for (int i = 0; i < 4; ++i) {
                int r = (wv >> 1) * 64 + i * 16 + lm;
                int c = kk * 4 + lq;
                int s = c ^ (r & 7);
                a[i] = *reinterpret_cast<const bf16x8*>(As + (r * 8 + s) * 8);
            }
#pragma unroll
            for (int j = 0; j < 4; ++j) {
                int r = (wv & 1) * 64 + j * 16 + lm;
                int c = kk * 4 + lq;
                int s = c ^ (r & 7);
                b[j] = *reinterpret_cast<const bf16x8*>(Bs + (r * 8 + s) * 8);
            }
#pragma unroll
            for (int i = 0; i < 4; ++i)
#pragma unroll
                for (int j = 0; j < 4; ++j)
                    acc[i][j] = __builtin_amdgcn_mfma_f32_16x16x32_bf16(a[i], b[j], acc[i][j], 0, 0, 0);
        }
        __syncthreads();
    }

#pragma unroll
    for (int i = 0; i < 4; ++i) {
#pragma unroll
        for (int r4 = 0; r4 < 4; ++r4) {
            int rr = m0w + i * 16 + lq * 4 + r4;
            if (rr >= M) continue;
            float wr = wrow ? wrow[rr] : 0.f;
#pragma unroll
            for (int j = 0; j < 4; ++j) {
                int col = n0w + j * 16 + lm;
                float v = acc[i][j][r4] + bias[col];
                v = v > 0.f ? v : 0.f;
                xout[(size_t)rr * xstride + col] = f2bf(v);
                if (vout) vout[(size_t)rr * xstride + col] = f2bf(v * wr);
            }
        }
    }
}

// ---------------- final projection: out = xc2 @ Wout^T + bout (fp32) --------
// Wout staged in LDS (f32, +1 pad -> conflict-free) in two 32-row passes;
// Block = 8 cells x 32 outs per pass.
__global__ __launch_bounds__(256) void out_kernel(const unsigned short* __restrict__ xc,
                                                  const float* __restrict__ Wout,
                                                  const float* __restrict__ bout,
                                                  float* __restrict__ out) {
    __shared__ float srow[8][D];            // 8 KB
    __shared__ float wlds[32][D + 1];       // 32.1 KB
    int tid = threadIdx.x;
    // stage 8 cell rows (bf16 -> f32)
    for (int t = tid; t < 8 * D; t += 256) {
        int rr = blockIdx.x * 8 + (t >> 8);
        unsigned short h = xc[(size_t)rr * D + (t & 255)];
        srow[t >> 8][t & 255] = __uint_as_float(((unsigned)h) << 16);
    }
    int r = tid >> 5, ol = tid & 31;
    float res[2];
#pragma unroll
    for (int p = 0; p < 2; ++p) {
        __syncthreads();
        // stage 32 Wout rows (coalesced float4 global, scalar LDS writes)
        for (int t = tid; t < 32 * (D / 4); t += 256) {
            int o = t >> 6, k4 = (t & 63) * 4;
            float4 wv = *reinterpret_cast<const float4*>(Wout + (size_t)(p * 32 + o) * D + k4);
            wlds[o][k4 + 0] = wv.x; wlds[o][k4 + 1] = wv.y;
            wlds[o][k4 + 2] = wv.z; wlds[o][k4 + 3] = wv.w;
        }
        __syncthreads();
        float s = 0.f;
        for (int k = 0; k < D; ++k) s += srow[r][k] * wlds[ol][k];
        res[p] = s;
    }
    int c = blockIdx.x * 8 + r;
    out[(size_t)c * NOUTD + ol] = res[0] + bout[ol];
    out[(size_t)c * NOUTD + 32 + ol] = res[1] + bout[32 + ol];
}

// ---------------- orchestration ---------------------------------------------
extern "C" void kernel_launch(void* const* d_in, const int* in_sizes, int n_in,
                              void* d_out, int out_size, void* d_ws, size_t ws_size,
                              hipStream_t stream) {
    const float* x_gene = (const float*)d_in[0];
    const float* x_cell = (const float*)d_in[1];
    const int*   src_g2c = (const int*)d_in[2];
    const int*   dst_g2c = (const int*)d_in[3];
    const int*   src_c2g = (const int*)d_in[4];
    const int*   dst_c2g = (const int*)d_in[5];
    const float* w_g2c = (const float*)d_in[8];
    const float* w_c2g = (const float*)d_in[9];
    const float* w_gg  = (const float*)d_in[10];
    const float* w_cc  = (const float*)d_in[11];
    const float* Wrel  = (const float*)d_in[12];
    const float* brel  = (const float*)d_in[13];
    const float* Wroot = (const float*)d_in[14];
    const float* Wout  = (const float*)d_in[15];
    const float* bout  = (const float*)d_in[16];
    float* out = (float*)d_out;

    char* p = (char*)d_ws;
    auto alloc = [&](size_t bytes) -> char* {
        char* r = p;
        p += (bytes + 255) & ~(size_t)255;
        return r;
    };

    unsigned short* xg0b    = (unsigned short*)alloc((size_t)NG * D * 2);
    unsigned short* xg1     = (unsigned short*)alloc((size_t)NG * D * 2);
    unsigned short* agg_g   = (unsigned short*)alloc((size_t)NG * D * 2);
    unsigned short* Acat_c0 = (unsigned short*)alloc((size_t)NC * KCAT * 2);
    unsigned short* Acat_c1 = (unsigned short*)alloc((size_t)NC * KCAT * 2);
    unsigned short* xc2     = (unsigned short*)alloc((size_t)NC * D * 2);
    int* rp_g  = (int*)alloc((NG + 1) * 4);
    int* rp_c  = (int*)alloc((NC + 1) * 4);
    int2* ec = (int2*)alloc((size_t)NE * 8);       // g2c edges grouped by cell
    int2* eg = (int2*)alloc((size_t)NE * 8);       // c2g edges grouped by gene
    int2* st_c = (int2*)alloc((size_t)NE * 8);     // coarse-bucketed staging
    int2* st_g = (int2*)alloc((size_t)NE * 8);
    int* hist512 = (int*)alloc(512 * 4);
    int* cbase   = (int*)alloc(514 * 4);
    int* ccur_c  = (int*)alloc(256 * 4);
    int* ccur_g  = (int*)alloc(256 * 4);
    unsigned short* Wg0p = (unsigned short*)alloc((size_t)D * KCAT * 2);  // packed
    unsigned short* Wc0  = (unsigned short*)alloc((size_t)D * KCAT * 2);
    unsigned short* Wc1  = (unsigned short*)alloc((size_t)D * KCAT * 2);
    float* bg0 = (float*)alloc(D * 4);
    float* bc0 = (float*)alloc(D * 4);
    float* bc1 = (float*)alloc(D * 4);

    hipMemsetAsync(hist512, 0, 512 * 4, stream);

    // cell prep (x + v into Acat_c0 cols)
    prep_x<<<(NC * 64 + 255) / 256, 256, 0, stream>>>(x_cell, w_cc, Acat_c0 + 256, Acat_c0 + 512, KCAT, NC);

    // all 3 weight matrices in one launch (gene one fragment-packed)
    build_wcat3<<<dim3((D * D + 255) / 256, 3), 256, 0, stream>>>(
        Wrel, Wroot, brel, Wg0p, Wc0, Wc1, bg0, bc0, bc1);

    // ---- CSR build (+ fused x_gene conversion) ----
    coarse_count_conv<<<CCB + CONVB, 256, 0, stream>>>(dst_g2c, dst_c2g, hist512, x_gene, xg0b);
    coarse_scan<<<1, 256, 0, stream>>>(hist512, cbase, ccur_c, ccur_g, rp_c, rp_g);
    const int P1B = (NE + P1_CHUNK - 1) / P1_CHUNK;
    bucket_pass1<<<dim3(P1B, 2), 256, 0, stream>>>(
        src_g2c, dst_g2c, w_g2c, ccur_c, st_c,
        src_c2g, dst_c2g, w_c2g, ccur_g, st_g);
    bucket_pass2<<<P2_CBLK + P2_GBLK, 256, 0, stream>>>(
        st_c, ec, rp_c, st_g, eg, rp_g, cbase);
    // (sort_cell_edges deleted -- gather source is cache-resident; order-free)

    // ---- gene path ----
    agg_gene<<<(NG + 3) / 4, 256, 0, stream>>>(
        rp_g, eg, Acat_c0 + 256, KCAT, agg_g, NG);
    gene_gemm<<<dim3((NG + 127) / 128, 2), 256, 0, stream>>>(
        agg_g, xg0b, w_gg, Wg0p, bg0, xg1);

    // ---- Layer 0 cells ----
    agg_cell<<<NC, 256, 0, stream>>>(rp_c, ec, xg0b, D, Acat_c0, KCAT);
    gemm_tile<<<dim3((NC + 127) / 128, 2), 256, 0, stream>>>(
        Acat_c0, Wc0, bc0, w_cc, Acat_c1 + 256, KCAT, Acat_c1 + 512, NC);

    // ---- Layer 1 cells ----
    agg_cell<<<NC, 256, 0, stream>>>(rp_c, ec, xg1, D, Acat_c1, KCAT);
    gemm_tile<<<dim3((NC + 127) / 128, 2), 256, 0, stream>>>(
        Acat_c1, Wc1, bc1, nullptr, xc2, D, nullptr, NC);

    // ---- output projection ----
    out_kernel<<<NC / 8, 256, 0, stream>>>(xc2, Wout, bout, out);
}

// Round 12
// 566.265 us; speedup vs baseline: 1.0347x; 1.0347x over previous
//
#include <hip/hip_runtime.h>

// Problem constants
static constexpr int NG   = 100000;
static constexpr int NC   = 2000;
static constexpr int D    = 256;
static constexpr int NE   = 1000000;
static constexpr int NOUTD= 64;
static constexpr int KCAT = 768;          // concatenated K: [agg | x | v]

typedef __bf16 bf16x8 __attribute__((ext_vector_type(8)));
typedef float  f32x4  __attribute__((ext_vector_type(4)));

__device__ __forceinline__ unsigned short f2bf(float f) {
    unsigned u = __float_as_uint(f);
    u += 0x7fffu + ((u >> 16) & 1u);   // RNE
    return (unsigned short)(u >> 16);
}
__device__ __forceinline__ float bflo(unsigned x) { return __uint_as_float((x & 0xffffu) << 16); }
__device__ __forceinline__ float bfhi(unsigned x) { return __uint_as_float(x & 0xffff0000u); }

__device__ __forceinline__ void async16(const void* g, void* l) {
    __builtin_amdgcn_global_load_lds(
        (const __attribute__((address_space(1))) void*)g,
        (__attribute__((address_space(3))) void*)l, 16, 0, 0);
}

// ---------------- prep (cells only): f32 -> bf16 x and v=x*w ----------------
__global__ void prep_x(const float* __restrict__ x, const float* __restrict__ w,
                       unsigned short* __restrict__ dx, unsigned short* __restrict__ dv,
                       long stride, int rows) {
    int i = blockIdx.x * blockDim.x + threadIdx.x;   // one per 4 elements
    if (i >= rows * (D / 4)) return;
    int row = i >> 6, c4 = (i & 63) * 4;
    float4 xv = *reinterpret_cast<const float4*>(x + (size_t)row * D + c4);
    float wv = w[row];
    uint2 ox, ov;
    ox.x = (unsigned)f2bf(xv.x) | ((unsigned)f2bf(xv.y) << 16);
    ox.y = (unsigned)f2bf(xv.z) | ((unsigned)f2bf(xv.w) << 16);
    ov.x = (unsigned)f2bf(xv.x * wv) | ((unsigned)f2bf(xv.y * wv) << 16);
    ov.y = (unsigned)f2bf(xv.z * wv) | ((unsigned)f2bf(xv.w * wv) << 16);
    *reinterpret_cast<uint2*>(dx + (size_t)row * stride + c4) = ox;
    *reinterpret_cast<uint2*>(dv + (size_t)row * stride + c4) = ov;
}

// -------- build all 3 concatenated bf16 weight mats [256][768] + bias sums --
// y=0: gene L0 (ia=1, ib=2); y=1: cell L0 (0,3); y=2: cell L1 (4,7)
__global__ void build_wcat3(const float* __restrict__ Wrel, const float* __restrict__ Wroot,
                            const float* __restrict__ brel,
                            unsigned short* __restrict__ Wg0, unsigned short* __restrict__ Wc0,
                            unsigned short* __restrict__ Wc1,
                            float* __restrict__ bg0, float* __restrict__ bc0,
                            float* __restrict__ bc1) {
    int i = blockIdx.x * blockDim.x + threadIdx.x;
    if (i >= D * D) return;
    int ia, ib; unsigned short* wout; float* bsum;
    if (blockIdx.y == 0)      { ia = 1; ib = 2; wout = Wg0; bsum = bg0; }
    else if (blockIdx.y == 1) { ia = 0; ib = 3; wout = Wc0; bsum = bc0; }
    else                      { ia = 4; ib = 7; wout = Wc1; bsum = bc1; }
    const int WW = D * D;
    int n = i >> 8, k = i & 255;
    wout[(size_t)n * KCAT + k]        = f2bf(Wrel[ia * WW + i]);
    wout[(size_t)n * KCAT + 256 + k]  = f2bf(Wroot[ia * WW + i] + Wroot[ib * WW + i]);
    wout[(size_t)n * KCAT + 512 + k]  = f2bf(Wrel[ib * WW + i]);
    if (i < D) bsum[i] = brel[ia * D + i] + brel[ib * D + i];
}

// ------ coarse histogram (256 bins/relation) + fused x_gene conversion ------
static constexpr int CC_CHUNK = 8192;
static constexpr int CCB = (NE + CC_CHUNK - 1) / CC_CHUNK;   // 123
static constexpr int CONVB = NG * (D / 4) / 256;             // 25000
__global__ __launch_bounds__(256) void coarse_count_conv(
        const int* __restrict__ dst_g2c, const int* __restrict__ dst_c2g,
        int* __restrict__ hist,                               // [512]
        const float* __restrict__ x_gene, unsigned short* __restrict__ xg0b) {
    __shared__ int h[512];
    if (blockIdx.x >= CCB) {
        int i = (blockIdx.x - CCB) * 256 + threadIdx.x;       // quarter-row id
        int row = i >> 6, c4 = (i & 63) * 4;
        float4 xv = *reinterpret_cast<const float4*>(x_gene + (size_t)row * D + c4);
        uint2 xo;
        xo.x = (unsigned)f2bf(xv.x) | ((unsigned)f2bf(xv.y) << 16);
        xo.y = (unsigned)f2bf(xv.z) | ((unsigned)f2bf(xv.w) << 16);
        *reinterpret_cast<uint2*>(xg0b + (size_t)row * D + c4) = xo;
        return;
    }
    h[threadIdx.x] = 0; h[256 + threadIdx.x] = 0;
    __syncthreads();
    int base = blockIdx.x * CC_CHUNK;
#pragma unroll 4
    for (int t = 0; t < CC_CHUNK / 256; ++t) {
        int e = base + t * 256 + threadIdx.x;
        if (e < NE) {
            atomicAdd(&h[dst_g2c[e] >> 3], 1);          // cell bins
            atomicAdd(&h[256 + (dst_c2g[e] >> 9)], 1);  // gene bins
        }
    }
    __syncthreads();
    if (h[threadIdx.x]) atomicAdd(&hist[threadIdx.x], h[threadIdx.x]);
    if (h[256 + threadIdx.x]) atomicAdd(&hist[256 + threadIdx.x], h[256 + threadIdx.x]);
}

// ---- coarse scan: cbase[0..256]=cells, cbase[257..513]=genes; init cursors -
__global__ __launch_bounds__(256) void coarse_scan(const int* __restrict__ hist,
                                                   int* __restrict__ cbase,
                                                   int* __restrict__ ccur_c, int* __restrict__ ccur_g,
                                                   int* __restrict__ rp_c, int* __restrict__ rp_g) {
    __shared__ int sd[256];
    int t = threadIdx.x;
    {
        int v = hist[t];
        sd[t] = v; __syncthreads();
        for (int off = 1; off < 256; off <<= 1) {
            int u = (t >= off) ? sd[t - off] : 0; __syncthreads();
            sd[t] += u; __syncthreads();
        }
        int e = sd[t] - v;
        cbase[t] = e; ccur_c[t] = e;
        if (t == 255) cbase[256] = sd[255];
        __syncthreads();
    }
    {
        int v = hist[256 + t];
        sd[t] = v; __syncthreads();
        for (int off = 1; off < 256; off <<= 1) {
            int u = (t >= off) ? sd[t - off] : 0; __syncthreads();
            sd[t] += u; __syncthreads();
        }
        int e = sd[t] - v;
        cbase[257 + t] = e; ccur_g[t] = e;
        if (t == 255) cbase[513] = sd[255];
    }
    if (t == 0) { rp_c[NC] = NE; rp_g[NG] = NE; }
}

// pass1 (fused c/g via blockIdx.y): scatter edges into 256 coarse buckets
static constexpr int P1_CHUNK = 8192;
__global__ __launch_bounds__(256) void bucket_pass1(
        const int* __restrict__ srcA, const int* __restrict__ dstA, const float* __restrict__ wA,
        int* __restrict__ curA, int2* __restrict__ outA,
        const int* __restrict__ srcB, const int* __restrict__ dstB, const float* __restrict__ wB,
        int* __restrict__ curB, int2* __restrict__ outB) {
    __shared__ int hist[256], lcur[256], gbase[256];
    const int* src; const int* dst; const float* w; int* coarse_cur; int2* out;
    int shift, packshift;
    if (blockIdx.y == 0) { src = srcA; dst = dstA; w = wA; coarse_cur = curA; out = outA; shift = 3; packshift = 17; }
    else { src = srcB; dst = dstB; w = wB; coarse_cur = curB; out = outB; shift = 9; packshift = 11; }
    int tid = threadIdx.x;
    hist[tid] = 0;
    __syncthreads();
    int base = blockIdx.x * P1_CHUNK;
    int mybin[P1_CHUNK / 256];
#pragma unroll
    for (int t = 0; t < P1_CHUNK / 256; ++t) {
        int e = base + t * 256 + tid;
        if (e < NE) {
            int b = dst[e] >> shift;
            mybin[t] = b;
            atomicAdd(&hist[b], 1);
        } else mybin[t] = -1;
    }
    __syncthreads();
    int v = hist[tid];
    gbase[tid] = v ? atomicAdd(&coarse_cur[tid], v) : 0;
    lcur[tid] = 0;
    __syncthreads();
#pragma unroll
    for (int t = 0; t < P1_CHUNK / 256; ++t) {
        int b = mybin[t];
        if (b < 0) continue;
        int e = base + t * 256 + tid;
        int pos = gbase[b] + atomicAdd(&lcur[b], 1);
        int dl = dst[e] & ((1 << shift) - 1);
        out[pos] = make_int2(src[e] | (dl << packshift), __float_as_int(w[e]));
    }
}

// pass2 (fused): per bucket — fine LDS histogram + scan emits rp, then scatter
static constexpr int P2_CBLK = NC / 8;                 // 250
static constexpr int P2_GBLK = (NG + 511) / 512;       // 196
__global__ __launch_bounds__(256) void bucket_pass2(
        const int2* __restrict__ stC, int2* __restrict__ outC, int* __restrict__ rpC,
        const int2* __restrict__ stG, int2* __restrict__ outG, int* __restrict__ rpG,
        const int* __restrict__ cbase) {
    __shared__ int hist[512], cur[512], sd[256];
    const int2* staged; int2* out; int* rp; const int* cb;
    int shift, packshift, ndst, b;
    if (blockIdx.x < P2_CBLK) {
        staged = stC; out = outC; rp = rpC; cb = cbase;
        shift = 3; packshift = 17; ndst = NC; b = blockIdx.x;
    } else {
        staged = stG; out = outG; rp = rpG; cb = cbase + 257;
        shift = 9; packshift = 11; ndst = NG; b = blockIdx.x - P2_CBLK;
    }
    int tid = threadIdx.x;
    int nf = 1 << shift;
    int d0 = b << shift;
    int j0 = cb[b], j1 = cb[b + 1];
    for (int f = tid; f < nf; f += 256) hist[f] = 0;
    __syncthreads();
    for (int j = j0 + tid; j < j1; j += 256)
        atomicAdd(&hist[((unsigned)staged[j].x) >> packshift], 1);
    __syncthreads();
    // exclusive scan over hist[0..nf)
    int chunk = (nf + 255) >> 8;                 // 1 or 2
    int s = 0;
#pragma unroll 2
    for (int k = 0; k < chunk; ++k) {
        int idx = tid * chunk + k;
        if (idx < nf) s += hist[idx];
    }
    sd[tid] = s; __syncthreads();
    for (int off = 1; off < 256; off <<= 1) {
        int u = (tid >= off) ? sd[tid - off] : 0; __syncthreads();
        sd[tid] += u; __syncthreads();
    }
    int run = sd[tid] - s;                       // exclusive base for this thread's chunk
#pragma unroll 2
    for (int k = 0; k < chunk; ++k) {
        int idx = tid * chunk + k;
        if (idx < nf) {
            int h = hist[idx];
            int pos = j0 + run;
            cur[idx] = pos;
            int d = d0 + idx;
            if (d < ndst) rp[d] = pos;
            run += h;
        }
    }
    __syncthreads();
    // scatter within the bucket's contiguous (cache-local) output region
    for (int j = j0 + tid; j < j1; j += 256) {
        int2 e = staged[j];
        int f = ((unsigned)e.x) >> packshift;
        int pos = atomicAdd(&cur[f], 1);
        out[pos] = make_int2(e.x & ((1 << packshift) - 1), e.y);
    }
}

// --------------- gene aggregation: one wave per destination row -------------
// Pure gather. Scalar edge records (readfirstlane'd j0/j1 -> s_loads),
// half-wave 2-edges-per-uint4 gathers, 2 in flight.
__global__ void agg_gene(const int* __restrict__ rp, const int2* __restrict__ eg,
                         const unsigned short* __restrict__ src, long sstride,
                         unsigned short* __restrict__ agg_out, int nrows) {
    int wave = (blockIdx.x * blockDim.x + threadIdx.x) >> 6;
    int lane = threadIdx.x & 63;
    if (wave >= nrows) return;
    int j0 = __builtin_amdgcn_readfirstlane(rp[wave]);
    int j1 = __builtin_amdgcn_readfirstlane(rp[wave + 1]);
    int half = lane >> 5;        // 0: edge A, 1: edge B of each gather pair
    int lh = lane & 31;          // 16B slot within the 512B row
    float a0=0.f,a1=0.f,a2=0.f,a3=0.f,a4=0.f,a5=0.f,a6=0.f,a7=0.f;
    int j = j0;
    for (; j + 4 <= j1; j += 4) {
        int2 e0 = eg[j], e1 = eg[j + 1], e2 = eg[j + 2], e3 = eg[j + 3];
        int   rA = half ? e1.x : e0.x;
        float wA = __int_as_float(half ? e1.y : e0.y);
        int   rB = half ? e3.x : e2.x;
        float wB = __int_as_float(half ? e3.y : e2.y);
        uint4 pA = *reinterpret_cast<const uint4*>(src + (size_t)rA * sstride + lh * 8);
        uint4 pB = *reinterpret_cast<const uint4*>(src + (size_t)rB * sstride + lh * 8);
        a0 += wA * bflo(pA.x) + wB * bflo(pB.x);
        a1 += wA * bfhi(pA.x) + wB * bfhi(pB.x);
        a2 += wA * bflo(pA.y) + wB * bflo(pB.y);
        a3 += wA * bfhi(pA.y) + wB * bfhi(pB.y);
        a4 += wA * bflo(pA.z) + wB * bflo(pB.z);
        a5 += wA * bfhi(pA.z) + wB * bfhi(pB.z);
        a6 += wA * bflo(pA.w) + wB * bflo(pB.w);
        a7 += wA * bfhi(pA.w) + wB * bfhi(pB.w);
    }
    for (; j < j1; j += 2) {
        int2 e0 = eg[j];
        int2 e1 = (j + 1 < j1) ? eg[j + 1] : make_int2(e0.x, 0);  // w=0 pad
        int   r = half ? e1.x : e0.x;
        float w = __int_as_float(half ? e1.y : e0.y);
        uint4 p = *reinterpret_cast<const uint4*>(src + (size_t)r * sstride + lh * 8);
        a0 += w * bflo(p.x); a1 += w * bfhi(p.x);
        a2 += w * bflo(p.y); a3 += w * bfhi(p.y);
        a4 += w * bflo(p.z); a5 += w * bfhi(p.z);
        a6 += w * bflo(p.w); a7 += w * bfhi(p.w);
    }
    // combine the two half-wave partials
    a0 += __shfl_xor(a0, 32, 64); a1 += __shfl_xor(a1, 32, 64);
    a2 += __shfl_xor(a2, 32, 64); a3 += __shfl_xor(a3, 32, 64);
    a4 += __shfl_xor(a4, 32, 64); a5 += __shfl_xor(a5, 32, 64);
    a6 += __shfl_xor(a6, 32, 64); a7 += __shfl_xor(a7, 32, 64);
    if (lane < 32) {
        uint4 o;
        o.x = (unsigned)f2bf(a0) | ((unsigned)f2bf(a1) << 16);
        o.y = (unsigned)f2bf(a2) | ((unsigned)f2bf(a3) << 16);
        o.z = (unsigned)f2bf(a4) | ((unsigned)f2bf(a5) << 16);
        o.w = (unsigned)f2bf(a6) | ((unsigned)f2bf(a7) << 16);
        *reinterpret_cast<uint4*>(agg_out + (size_t)wave * D + lane * 8) = o;
    }
}

// ---------------- gene GEMM: xg1 = relu(agg@W1^T + x@Wc^T + w*(x@W2^T) + b) -
// Round-7 form (best measured across rounds 7-11): dual accumulator derives
// the w_gg term in registers; A + W async16-staged through 48 KB LDS.
// Restructure attempts (direct-B r8, input-fold r9, packed-B r11) all lost
// to the LDS-staged 2-barrier form — shelved.
__global__ __launch_bounds__(256, 2) void gene_gemm(
        const unsigned short* __restrict__ Agg,  // [NG][256] bf16
        const unsigned short* __restrict__ Xb,   // [NG][256] bf16
        const float* __restrict__ w_gg,          // [NG]
        const unsigned short* __restrict__ W,    // [256][768]: rel1|rootc|rel2
        const float* __restrict__ bias,          // [256]
        unsigned short* __restrict__ xg1) {      // out [NG][256]
    __shared__ unsigned short As[128 * 64];      // 16 KB
    __shared__ unsigned short Bs1[128 * 64];     // 16 KB
    __shared__ unsigned short Bs2[128 * 64];     // 16 KB
    int tid = threadIdx.x;
    int wv = tid >> 6, ln = tid & 63;
    int lm = ln & 15, lq = ln >> 4;
    int m0 = blockIdx.x * 128;
    int nb = blockIdx.y * 128;
    int m0w = m0 + (wv >> 1) * 64;
    int n0w = nb + (wv & 1) * 64;

    f32x4 accA[4][4], accV[4][4];
#pragma unroll
    for (int i = 0; i < 4; ++i)
#pragma unroll
        for (int j = 0; j < 4; ++j) { accA[i][j] = f32x4{0,0,0,0}; accV[i][j] = f32x4{0,0,0,0}; }

    // ---- segment A: agg @ Wrel1^T ----
    for (int k0 = 0; k0 < 256; k0 += 64) {
#pragma unroll
        for (int t = 0; t < 4; ++t) {
            int ci = t * 256 + tid;
            int r = ci >> 3, s = ci & 7;
            int cg = s ^ (r & 7);
            int row = m0 + r; if (row >= NG) row = NG - 1;
            async16(Agg + (size_t)row * D + k0 + cg * 8, (unsigned char*)As + ci * 16);
            async16(W + (size_t)(nb + r) * KCAT + k0 + cg * 8, (unsigned char*)Bs1 + ci * 16);
        }
        __syncthreads();
#pragma unroll
        for (int kk = 0; kk < 2; ++kk) {
            bf16x8 a[4], b[4];
#pragma unroll
            for (int i = 0; i < 4; ++i) {
                int r = (wv >> 1) * 64 + i * 16 + lm;
                int s = (kk * 4 + lq) ^ (r & 7);
                a[i] = *reinterpret_cast<const bf16x8*>(As + (r * 8 + s) * 8);
            }
#pragma unroll
            for (int j = 0; j < 4; ++j) {
                int r = (wv & 1) * 64 + j * 16 + lm;
                int s = (kk * 4 + lq) ^ (r & 7);
                b[j] = *reinterpret_cast<const bf16x8*>(Bs1 + (r * 8 + s) * 8);
            }
#pragma unroll
            for (int i = 0; i < 4; ++i)
#pragma unroll
                for (int j = 0; j < 4; ++j)
                    accA[i][j] = __builtin_amdgcn_mfma_f32_16x16x32_bf16(a[i], b[j], accA[i][j], 0, 0, 0);
        }
        __syncthreads();
    }

    // ---- segment X: x @ (Wroot1+Wroot2)^T into accA, x @ Wrel2^T into accV -
    for (int k0 = 0; k0 < 256; k0 += 64) {
#pragma unroll
        for (int t = 0; t < 4; ++t) {
            int ci = t * 256 + tid;
            int r = ci >> 3, s = ci & 7;
            int cg = s ^ (r & 7);
            int row = m0 + r; if (row >= NG) row = NG - 1;
            async16(Xb + (size_t)row * D + k0 + cg * 8, (unsigned char*)As + ci * 16);
            async16(W + (size_t)(nb + r) * KCAT + 256 + k0 + cg * 8, (unsigned char*)Bs1 + ci * 16);
            async16(W + (size_t)(nb + r) * KCAT + 512 + k0 + cg * 8, (unsigned char*)Bs2 + ci * 16);
        }
        __syncthreads();
#pragma unroll
        for (int kk = 0; kk < 2; ++kk) {
            bf16x8 a[4], b1[4], b2[4];
#pragma unroll
            for (int i = 0; i < 4; ++i) {
                int r = (wv >> 1) * 64 + i * 16 + lm;
                int s = (kk * 4 + lq) ^ (r & 7);
                a[i] = *reinterpret_cast<const bf16x8*>(As + (r * 8 + s) * 8);
            }
#pragma unroll
            for (int j = 0; j < 4; ++j) {
                int r = (wv & 1) * 64 + j * 16 + lm;
                int s = (kk * 4 + lq) ^ (r & 7);
                b1[j] = *reinterpret_cast<const bf16x8*>(Bs1 + (r * 8 + s) * 8);
                b2[j] = *reinterpret_cast<const bf16x8*>(Bs2 + (r * 8 + s) * 8);
            }
#pragma unroll
            for (int i = 0; i < 4; ++i)
#pragma unroll
                for (int j = 0; j < 4; ++j) {
                    accA[i][j] = __builtin_amdgcn_mfma_f32_16x16x32_bf16(a[i], b1[j], accA[i][j], 0, 0, 0);
                    accV[i][j] = __builtin_amdgcn_mfma_f32_16x16x32_bf16(a[i], b2[j], accV[i][j], 0, 0, 0);
                }
        }
        __syncthreads();
    }

    // ---- epilogue ----
#pragma unroll
    for (int i = 0; i < 4; ++i) {
#pragma unroll
        for (int r4 = 0; r4 < 4; ++r4) {
            int row = m0w + i * 16 + lq * 4 + r4;
            if (row >= NG) continue;
            float wr = w_gg[row];
#pragma unroll
            for (int j = 0; j < 4; ++j) {
                int col = n0w + j * 16 + lm;
                float v = accA[i][j][r4] + wr * accV[i][j][r4] + bias[col];
                v = v > 0.f ? v : 0.f;
                xg1[(size_t)row * D + col] = f2bf(v);
            }
        }
    }
}

// ---------------- cell aggregation: one block per cell, LDS reduce ----------
// Round 12: 8 edges/wave/iter (4 uint4 gathers in flight; was 2) — counters
// showed latency-bound (occ 72%, VALU 26%, 3.3 TB/s). deg~500 => batch-32
// waste negligible; tail keeps the proven pair loop.
__global__ __launch_bounds__(256) void agg_cell(const int* __restrict__ rp,
                                                const int2* __restrict__ ec,
                                                const unsigned short* __restrict__ src, long sstride,
                                                unsigned short* __restrict__ out, long ostride) {
    __shared__ float red[4][D];
    int c = blockIdx.x;
    int wv = threadIdx.x >> 6, ln = threadIdx.x & 63;
    int half = ln >> 5, lh = ln & 31;
    int j0 = __builtin_amdgcn_readfirstlane(rp[c]);
    int j1 = __builtin_amdgcn_readfirstlane(rp[c + 1]);
    float a0=0.f,a1=0.f,a2=0.f,a3=0.f,a4=0.f,a5=0.f,a6=0.f,a7=0.f;
    int n32 = (j1 - j0) & ~31;         // chunks of 32 = 4 waves x 8 edges
    for (int j = j0 + wv * 8; j < j0 + n32; j += 32) {
        int2 e0 = ec[j],     e1 = ec[j + 1], e2 = ec[j + 2], e3 = ec[j + 3];
        int2 e4 = ec[j + 4], e5 = ec[j + 5], e6 = ec[j + 6], e7 = ec[j + 7];
        int   rA = half ? e1.x : e0.x;  float wA = __int_as_float(half ? e1.y : e0.y);
        int   rB = half ? e3.x : e2.x;  float wB = __int_as_float(half ? e3.y : e2.y);
        int   rC = half ? e5.x : e4.x;  float wC = __int_as_float(half ? e5.y : e4.y);
        int   rD = half ? e7.x : e6.x;  float wD = __int_as_float(half ? e7.y : e6.y);
        uint4 pA = *reinterpret_cast<const uint4*>(src + (size_t)rA * sstride + lh * 8);
        uint4 pB = *reinterpret_cast<const uint4*>(src + (size_t)rB * sstride + lh * 8);
        uint4 pC = *reinterpret_cast<const uint4*>(src + (size_t)rC * sstride + lh * 8);
        uint4 pD = *reinterpret_cast<const uint4*>(src + (size_t)rD * sstride + lh * 8);
        a0 += wA * bflo(pA.x) + wB * bflo(pB.x) + wC * bflo(pC.x) + wD * bflo(pD.x);
        a1 += wA * bfhi(pA.x) + wB * bfhi(pB.x) + wC * bfhi(pC.x) + wD * bfhi(pD.x);
        a2 += wA * bflo(pA.y) + wB * bflo(pB.y) + wC * bflo(pC.y) + wD * bflo(pD.y);
        a3 += wA * bfhi(pA.y) + wB * bfhi(pB.y) + wC * bfhi(pC.y) + wD * bfhi(pD.y);
        a4 += wA * bflo(pA.z) + wB * bflo(pB.z) + wC * bflo(pC.z) + wD * bflo(pD.z);
        a5 += wA * bfhi(pA.z) + wB * bfhi(pB.z) + wC * bfhi(pC.z) + wD * bfhi(pD.z);
        a6 += wA * bflo(pA.w) + wB * bflo(pB.w) + wC * bflo(pC.w) + wD * bflo(pD.w);
        a7 += wA * bfhi(pA.w) + wB * bfhi(pB.w) + wC * bfhi(pC.w) + wD * bfhi(pD.w);
    }
    // tail: <=31 edges, pairs round-robin across waves, w=0 padding
    for (int j = j0 + n32 + wv * 2; j < j1; j += 8) {
        int2 e0 = ec[j];
        int2 e1 = (j + 1 < j1) ? ec[j + 1] : make_int2(e0.x, 0);
        int   r = half ? e1.x : e0.x;
        float w = __int_as_float(half ? e1.y : e0.y);
        uint4 p = *reinterpret_cast<const uint4*>(src + (size_t)r * sstride + lh * 8);
        a0 += w * bflo(p.x); a1 += w * bfhi(p.x);
        a2 += w * bflo(p.y); a3 += w * bfhi(p.y);
        a4 += w * bflo(p.z); a5 += w * bfhi(p.z);
        a6 += w * bflo(p.w); a7 += w * bfhi(p.w);
    }
    // combine half-wave partials, then cross-wave LDS reduce
    a0 += __shfl_xor(a0, 32, 64); a1 += __shfl_xor(a1, 32, 64);
    a2 += __shfl_xor(a2, 32, 64); a3 += __shfl_xor(a3, 32, 64);
    a4 += __shfl_xor(a4, 32, 64); a5 += __shfl_xor(a5, 32, 64);
    a6 += __shfl_xor(a6, 32, 64); a7 += __shfl_xor(a7, 32, 64);
    if (ln < 32) {
        *reinterpret_cast<float4*>(&red[wv][lh * 8])     = make_float4(a0, a1, a2, a3);
        *reinterpret_cast<float4*>(&red[wv][lh * 8 + 4]) = make_float4(a4, a5, a6, a7);
    }
    __syncthreads();
    int col = threadIdx.x;
    float s = red[0][col] + red[1][col] + red[2][col] + red[3][col];
    out[(size_t)c * ostride + col] = f2bf(s);
}

// ---------------- m97-style GEMM (cells): relu(A[M,768] @ W^T + bias) -------
__global__ __launch_bounds__(256, 2) void gemm_tile(
        const unsigned short* __restrict__ A,    // [M][768]
        const unsigned short* __restrict__ W,    // [256][768]
        const float* __restrict__ bias,          // [256]
        const float* __restrict__ wrow,          // nullable per-row scale for vout
        unsigned short* __restrict__ xout, long xstride,
        unsigned short* __restrict__ vout,       // nullable, same stride
        int M) {
    __shared__ unsigned short As[128 * 64];
    __shared__ unsigned short Bs[128 * 64];
    int tid = threadIdx.x;
    int wv = tid >> 6, ln = tid & 63;
    int lm = ln & 15, lq = ln >> 4;
    int m0 = blockIdx.x * 128;
    int nb = blockIdx.y * 128;
    int m0w = m0 + (wv >> 1) * 64;
    int n0w = nb + (wv & 1) * 64;

    f32x4 acc[4][4];
#pragma unroll
    for (int i = 0; i < 4; ++i)
#pragma unroll
        for (int j = 0; j < 4; ++j) acc[i][j] = f32x4{0.f, 0.f, 0.f, 0.f};

    for (int k0 = 0; k0 < KCAT; k0 += 64) {
#pragma unroll
        for (int t = 0; t < 4; ++t) {
            int ci = t * 256 + tid;
            int r = ci >> 3, s = ci & 7;
            int cg = s ^ (r & 7);
            int row = m0 + r; if (row >= M) row = M - 1;
            async16(A + (size_t)row * KCAT + k0 + cg * 8,
                    (unsigned char*)As + ci * 16);
        }
#pragma unroll
        for (int t = 0; t < 4; ++t) {
            int ci = t * 256 + tid;
            int r = ci >> 3, s = ci & 7;
            int cg = s ^ (r & 7);
            async16(W + (size_t)(nb + r) * KCAT + k0 + cg * 8,
                    (unsigned char*)Bs + ci * 16);
        }
        __syncthreads();
#pragma unroll
        for (int kk = 0; kk < 2; ++kk) {
            bf16x8 a[4], b[4];
#pragma unroll
            for (int i = 0; i < 4; ++i) {
                int r = (wv >> 1) * 64 + i * 16 + lm;
                int c = kk * 4 + lq;
                int s = c ^ (r & 7);
                a[i] = *reinterpret_cast<const bf16x8*>(As + (r * 8 + s) * 8);
            }
#pragma unroll
            for (int j = 0; j < 4; ++j) {
                int r = (wv & 1) * 64 + j * 16 + lm;
                int c = kk * 4 + lq;
                int s = c ^ (r & 7);
                b[j] = *reinterpret_cast<const bf16x8*>(Bs + (r * 8 + s) * 8);
            }
#pragma unroll
            for (int i = 0; i < 4; ++i)
#pragma unroll
                for (int j = 0; j < 4; ++j)
                    acc[i][j] = __builtin_amdgcn_mfma_f32_16x16x32_bf16(a[i], b[j], acc[i][j], 0, 0, 0);
        }
        __syncthreads();
    }

#pragma unroll
    for (int i = 0; i < 4; ++i) {
#pragma unroll
        for (int r4 = 0; r4 < 4; ++r4) {
            int rr = m0w + i * 16 + lq * 4 + r4;
            if (rr >= M) continue;
            float wr = wrow ? wrow[rr] : 0.f;
#pragma unroll
            for (int j = 0; j < 4; ++j) {
                int col = n0w + j * 16 + lm;
                float v = acc[i][j][r4] + bias[col];
                v = v > 0.f ? v : 0.f;
                xout[(size_t)rr * xstride + col] = f2bf(v);
                if (vout) vout[(size_t)rr * xstride + col] = f2bf(v * wr);
            }
        }
    }
}

// ---------------- final projection: out = xc2 @ Wout^T + bout (fp32) --------
// Wout staged in LDS (f32, +1 pad -> conflict-free) in two 32-row passes;
// Block = 8 cells x 32 outs per pass.
__global__ __launch_bounds__(256) void out_kernel(const unsigned short* __restrict__ xc,
                                                  const float* __restrict__ Wout,
                                                  const float* __restrict__ bout,
                                                  float* __restrict__ out) {
    __shared__ float srow[8][D];            // 8 KB
    __shared__ float wlds[32][D + 1];       // 32.1 KB
    int tid = threadIdx.x;
    // stage 8 cell rows (bf16 -> f32)
    for (int t = tid; t < 8 * D; t += 256) {
        int rr = blockIdx.x * 8 + (t >> 8);
        unsigned short h = xc[(size_t)rr * D + (t & 255)];
        srow[t >> 8][t & 255] = __uint_as_float(((unsigned)h) << 16);
    }
    int r = tid >> 5, ol = tid & 31;
    float res[2];
#pragma unroll
    for (int p = 0; p < 2; ++p) {
        __syncthreads();
        // stage 32 Wout rows (coalesced float4 global, scalar LDS writes)
        for (int t = tid; t < 32 * (D / 4); t += 256) {
            int o = t >> 6, k4 = (t & 63) * 4;
            float4 wv = *reinterpret_cast<const float4*>(Wout + (size_t)(p * 32 + o) * D + k4);
            wlds[o][k4 + 0] = wv.x; wlds[o][k4 + 1] = wv.y;
            wlds[o][k4 + 2] = wv.z; wlds[o][k4 + 3] = wv.w;
        }
        __syncthreads();
        float s = 0.f;
        for (int k = 0; k < D; ++k) s += srow[r][k] * wlds[ol][k];
        res[p] = s;
    }
    int c = blockIdx.x * 8 + r;
    out[(size_t)c * NOUTD + ol] = res[0] + bout[ol];
    out[(size_t)c * NOUTD + 32 + ol] = res[1] + bout[32 + ol];
}

// ---------------- orchestration ---------------------------------------------
extern "C" void kernel_launch(void* const* d_in, const int* in_sizes, int n_in,
                              void* d_out, int out_size, void* d_ws, size_t ws_size,
                              hipStream_t stream) {
    const float* x_gene = (const float*)d_in[0];
    const float* x_cell = (const float*)d_in[1];
    const int*   src_g2c = (const int*)d_in[2];
    const int*   dst_g2c = (const int*)d_in[3];
    const int*   src_c2g = (const int*)d_in[4];
    const int*   dst_c2g = (const int*)d_in[5];
    const float* w_g2c = (const float*)d_in[8];
    const float* w_c2g = (const float*)d_in[9];
    const float* w_gg  = (const float*)d_in[10];
    const float* w_cc  = (const float*)d_in[11];
    const float* Wrel  = (const float*)d_in[12];
    const float* brel  = (const float*)d_in[13];
    const float* Wroot = (const float*)d_in[14];
    const float* Wout  = (const float*)d_in[15];
    const float* bout  = (const float*)d_in[16];
    float* out = (float*)d_out;

    char* p = (char*)d_ws;
    auto alloc = [&](size_t bytes) -> char* {
        char* r = p;
        p += (bytes + 255) & ~(size_t)255;
        return r;
    };

    unsigned short* xg0b    = (unsigned short*)alloc((size_t)NG * D * 2);
    unsigned short* xg1     = (unsigned short*)alloc((size_t)NG * D * 2);
    unsigned short* agg_g   = (unsigned short*)alloc((size_t)NG * D * 2);
    unsigned short* Acat_c0 = (unsigned short*)alloc((size_t)NC * KCAT * 2);
    unsigned short* Acat_c1 = (unsigned short*)alloc((size_t)NC * KCAT * 2);
    unsigned short* xc2     = (unsigned short*)alloc((size_t)NC * D * 2);
    int* rp_g  = (int*)alloc((NG + 1) * 4);
    int* rp_c  = (int*)alloc((NC + 1) * 4);
    int2* ec = (int2*)alloc((size_t)NE * 8);       // g2c edges grouped by cell
    int2* eg = (int2*)alloc((size_t)NE * 8);       // c2g edges grouped by gene
    int2* st_c = (int2*)alloc((size_t)NE * 8);     // coarse-bucketed staging
    int2* st_g = (int2*)alloc((size_t)NE * 8);
    int* hist512 = (int*)alloc(512 * 4);
    int* cbase   = (int*)alloc(514 * 4);
    int* ccur_c  = (int*)alloc(256 * 4);
    int* ccur_g  = (int*)alloc(256 * 4);
    unsigned short* Wg0 = (unsigned short*)alloc((size_t)D * KCAT * 2);
    unsigned short* Wc0 = (unsigned short*)alloc((size_t)D * KCAT * 2);
    unsigned short* Wc1 = (unsigned short*)alloc((size_t)D * KCAT * 2);
    float* bg0 = (float*)alloc(D * 4);
    float* bc0 = (float*)alloc(D * 4);
    float* bc1 = (float*)alloc(D * 4);

    hipMemsetAsync(hist512, 0, 512 * 4, stream);

    // cell prep (x + v into Acat_c0 cols)
    prep_x<<<(NC * 64 + 255) / 256, 256, 0, stream>>>(x_cell, w_cc, Acat_c0 + 256, Acat_c0 + 512, KCAT, NC);

    // all 3 weight matrices in one launch
    build_wcat3<<<dim3((D * D + 255) / 256, 3), 256, 0, stream>>>(
        Wrel, Wroot, brel, Wg0, Wc0, Wc1, bg0, bc0, bc1);

    // ---- CSR build (+ fused x_gene conversion) ----
    coarse_count_conv<<<CCB + CONVB, 256, 0, stream>>>(dst_g2c, dst_c2g, hist512, x_gene, xg0b);
    coarse_scan<<<1, 256, 0, stream>>>(hist512, cbase, ccur_c, ccur_g, rp_c, rp_g);
    const int P1B = (NE + P1_CHUNK - 1) / P1_CHUNK;
    bucket_pass1<<<dim3(P1B, 2), 256, 0, stream>>>(
        src_g2c, dst_g2c, w_g2c, ccur_c, st_c,
        src_c2g, dst_c2g, w_c2g, ccur_g, st_g);
    bucket_pass2<<<P2_CBLK + P2_GBLK, 256, 0, stream>>>(
        st_c, ec, rp_c, st_g, eg, rp_g, cbase);
    // (sort_cell_edges deleted -- gather source is cache-resident; order-free)

    // ---- gene path ----
    agg_gene<<<(NG + 3) / 4, 256, 0, stream>>>(
        rp_g, eg, Acat_c0 + 256, KCAT, agg_g, NG);
    gene_gemm<<<dim3((NG + 127) / 128, 2), 256, 0, stream>>>(
        agg_g, xg0b, w_gg, Wg0, bg0, xg1);

    // ---- Layer 0 cells ----
    agg_cell<<<NC, 256, 0, stream>>>(rp_c, ec, xg0b, D, Acat_c0, KCAT);
    gemm_tile<<<dim3((NC + 127) / 128, 2), 256, 0, stream>>>(
        Acat_c0, Wc0, bc0, w_cc, Acat_c1 + 256, KCAT, Acat_c1 + 512, NC);

    // ---- Layer 1 cells ----
    agg_cell<<<NC, 256, 0, stream>>>(rp_c, ec, xg1, D, Acat_c1, KCAT);
    gemm_tile<<<dim3((NC + 127) / 128, 2), 256, 0, stream>>>(
        Acat_c1, Wc1, bc1, nullptr, xc2, D, nullptr, NC);

    // ---- output projection ----
    out_kernel<<<NC / 8, 256, 0, stream>>>(xc2, Wout, bout, out);
}

// Round 13
// 560.784 us; speedup vs baseline: 1.0448x; 1.0098x over previous
//
#include <hip/hip_runtime.h>

// Problem constants
static constexpr int NG   = 100000;
static constexpr int NC   = 2000;
static constexpr int D    = 256;
static constexpr int NE   = 1000000;
static constexpr int NOUTD= 64;
static constexpr int KCAT = 768;          // concatenated K: [agg | x | v]

typedef __bf16 bf16x8 __attribute__((ext_vector_type(8)));
typedef float  f32x4  __attribute__((ext_vector_type(4)));

__device__ __forceinline__ unsigned short f2bf(float f) {
    unsigned u = __float_as_uint(f);
    u += 0x7fffu + ((u >> 16) & 1u);   // RNE
    return (unsigned short)(u >> 16);
}
__device__ __forceinline__ float bflo(unsigned x) { return __uint_as_float((x & 0xffffu) << 16); }
__device__ __forceinline__ float bfhi(unsigned x) { return __uint_as_float(x & 0xffff0000u); }

__device__ __forceinline__ void async16(const void* g, void* l) {
    __builtin_amdgcn_global_load_lds(
        (const __attribute__((address_space(1))) void*)g,
        (__attribute__((address_space(3))) void*)l, 16, 0, 0);
}

// ---------------- prep (cells only): f32 -> bf16 x and v=x*w ----------------
__global__ void prep_x(const float* __restrict__ x, const float* __restrict__ w,
                       unsigned short* __restrict__ dx, unsigned short* __restrict__ dv,
                       long stride, int rows) {
    int i = blockIdx.x * blockDim.x + threadIdx.x;   // one per 4 elements
    if (i >= rows * (D / 4)) return;
    int row = i >> 6, c4 = (i & 63) * 4;
    float4 xv = *reinterpret_cast<const float4*>(x + (size_t)row * D + c4);
    float wv = w[row];
    uint2 ox, ov;
    ox.x = (unsigned)f2bf(xv.x) | ((unsigned)f2bf(xv.y) << 16);
    ox.y = (unsigned)f2bf(xv.z) | ((unsigned)f2bf(xv.w) << 16);
    ov.x = (unsigned)f2bf(xv.x * wv) | ((unsigned)f2bf(xv.y * wv) << 16);
    ov.y = (unsigned)f2bf(xv.z * wv) | ((unsigned)f2bf(xv.w * wv) << 16);
    *reinterpret_cast<uint2*>(dx + (size_t)row * stride + c4) = ox;
    *reinterpret_cast<uint2*>(dv + (size_t)row * stride + c4) = ov;
}

// -------- build all 3 concatenated bf16 weight mats [256][768] + bias sums --
// y=0: gene L0 (ia=1, ib=2); y=1: cell L0 (0,3); y=2: cell L1 (4,7)
__global__ void build_wcat3(const float* __restrict__ Wrel, const float* __restrict__ Wroot,
                            const float* __restrict__ brel,
                            unsigned short* __restrict__ Wg0, unsigned short* __restrict__ Wc0,
                            unsigned short* __restrict__ Wc1,
                            float* __restrict__ bg0, float* __restrict__ bc0,
                            float* __restrict__ bc1) {
    int i = blockIdx.x * blockDim.x + threadIdx.x;
    if (i >= D * D) return;
    int ia, ib; unsigned short* wout; float* bsum;
    if (blockIdx.y == 0)      { ia = 1; ib = 2; wout = Wg0; bsum = bg0; }
    else if (blockIdx.y == 1) { ia = 0; ib = 3; wout = Wc0; bsum = bc0; }
    else                      { ia = 4; ib = 7; wout = Wc1; bsum = bc1; }
    const int WW = D * D;
    int n = i >> 8, k = i & 255;
    wout[(size_t)n * KCAT + k]        = f2bf(Wrel[ia * WW + i]);
    wout[(size_t)n * KCAT + 256 + k]  = f2bf(Wroot[ia * WW + i] + Wroot[ib * WW + i]);
    wout[(size_t)n * KCAT + 512 + k]  = f2bf(Wrel[ib * WW + i]);
    if (i < D) bsum[i] = brel[ia * D + i] + brel[ib * D + i];
}

// ------ coarse histogram (256 bins/relation) + fused x_gene conversion ------
static constexpr int CC_CHUNK = 8192;
static constexpr int CCB = (NE + CC_CHUNK - 1) / CC_CHUNK;   // 123
static constexpr int CONVB = NG * (D / 4) / 256;             // 25000
__global__ __launch_bounds__(256) void coarse_count_conv(
        const int* __restrict__ dst_g2c, const int* __restrict__ dst_c2g,
        int* __restrict__ hist,                               // [512]
        const float* __restrict__ x_gene, unsigned short* __restrict__ xg0b) {
    __shared__ int h[512];
    if (blockIdx.x >= CCB) {
        int i = (blockIdx.x - CCB) * 256 + threadIdx.x;       // quarter-row id
        int row = i >> 6, c4 = (i & 63) * 4;
        float4 xv = *reinterpret_cast<const float4*>(x_gene + (size_t)row * D + c4);
        uint2 xo;
        xo.x = (unsigned)f2bf(xv.x) | ((unsigned)f2bf(xv.y) << 16);
        xo.y = (unsigned)f2bf(xv.z) | ((unsigned)f2bf(xv.w) << 16);
        *reinterpret_cast<uint2*>(xg0b + (size_t)row * D + c4) = xo;
        return;
    }
    h[threadIdx.x] = 0; h[256 + threadIdx.x] = 0;
    __syncthreads();
    int base = blockIdx.x * CC_CHUNK;
#pragma unroll 4
    for (int t = 0; t < CC_CHUNK / 256; ++t) {
        int e = base + t * 256 + threadIdx.x;
        if (e < NE) {
            atomicAdd(&h[dst_g2c[e] >> 3], 1);          // cell bins
            atomicAdd(&h[256 + (dst_c2g[e] >> 9)], 1);  // gene bins
        }
    }
    __syncthreads();
    if (h[threadIdx.x]) atomicAdd(&hist[threadIdx.x], h[threadIdx.x]);
    if (h[256 + threadIdx.x]) atomicAdd(&hist[256 + threadIdx.x], h[256 + threadIdx.x]);
}

// ---- coarse scan: cbase[0..256]=cells, cbase[257..513]=genes; init cursors -
__global__ __launch_bounds__(256) void coarse_scan(const int* __restrict__ hist,
                                                   int* __restrict__ cbase,
                                                   int* __restrict__ ccur_c, int* __restrict__ ccur_g,
                                                   int* __restrict__ rp_c, int* __restrict__ rp_g) {
    __shared__ int sd[256];
    int t = threadIdx.x;
    {
        int v = hist[t];
        sd[t] = v; __syncthreads();
        for (int off = 1; off < 256; off <<= 1) {
            int u = (t >= off) ? sd[t - off] : 0; __syncthreads();
            sd[t] += u; __syncthreads();
        }
        int e = sd[t] - v;
        cbase[t] = e; ccur_c[t] = e;
        if (t == 255) cbase[256] = sd[255];
        __syncthreads();
    }
    {
        int v = hist[256 + t];
        sd[t] = v; __syncthreads();
        for (int off = 1; off < 256; off <<= 1) {
            int u = (t >= off) ? sd[t - off] : 0; __syncthreads();
            sd[t] += u; __syncthreads();
        }
        int e = sd[t] - v;
        cbase[257 + t] = e; ccur_g[t] = e;
        if (t == 255) cbase[513] = sd[255];
    }
    if (t == 0) { rp_c[NC] = NE; rp_g[NG] = NE; }
}

// pass1 (fused c/g via blockIdx.y): scatter edges into 256 coarse buckets
static constexpr int P1_CHUNK = 8192;
__global__ __launch_bounds__(256) void bucket_pass1(
        const int* __restrict__ srcA, const int* __restrict__ dstA, const float* __restrict__ wA,
        int* __restrict__ curA, int2* __restrict__ outA,
        const int* __restrict__ srcB, const int* __restrict__ dstB, const float* __restrict__ wB,
        int* __restrict__ curB, int2* __restrict__ outB) {
    __shared__ int hist[256], lcur[256], gbase[256];
    const int* src; const int* dst; const float* w; int* coarse_cur; int2* out;
    int shift, packshift;
    if (blockIdx.y == 0) { src = srcA; dst = dstA; w = wA; coarse_cur = curA; out = outA; shift = 3; packshift = 17; }
    else { src = srcB; dst = dstB; w = wB; coarse_cur = curB; out = outB; shift = 9; packshift = 11; }
    int tid = threadIdx.x;
    hist[tid] = 0;
    __syncthreads();
    int base = blockIdx.x * P1_CHUNK;
    int mybin[P1_CHUNK / 256];
#pragma unroll
    for (int t = 0; t < P1_CHUNK / 256; ++t) {
        int e = base + t * 256 + tid;
        if (e < NE) {
            int b = dst[e] >> shift;
            mybin[t] = b;
            atomicAdd(&hist[b], 1);
        } else mybin[t] = -1;
    }
    __syncthreads();
    int v = hist[tid];
    gbase[tid] = v ? atomicAdd(&coarse_cur[tid], v) : 0;
    lcur[tid] = 0;
    __syncthreads();
#pragma unroll
    for (int t = 0; t < P1_CHUNK / 256; ++t) {
        int b = mybin[t];
        if (b < 0) continue;
        int e = base + t * 256 + tid;
        int pos = gbase[b] + atomicAdd(&lcur[b], 1);
        int dl = dst[e] & ((1 << shift) - 1);
        out[pos] = make_int2(src[e] | (dl << packshift), __float_as_int(w[e]));
    }
}

// pass2 (fused): per bucket — fine LDS histogram + scan emits rp, then scatter
static constexpr int P2_CBLK = NC / 8;                 // 250
static constexpr int P2_GBLK = (NG + 511) / 512;       // 196
__global__ __launch_bounds__(256) void bucket_pass2(
        const int2* __restrict__ stC, int2* __restrict__ outC, int* __restrict__ rpC,
        const int2* __restrict__ stG, int2* __restrict__ outG, int* __restrict__ rpG,
        const int* __restrict__ cbase) {
    __shared__ int hist[512], cur[512], sd[256];
    const int2* staged; int2* out; int* rp; const int* cb;
    int shift, packshift, ndst, b;
    if (blockIdx.x < P2_CBLK) {
        staged = stC; out = outC; rp = rpC; cb = cbase;
        shift = 3; packshift = 17; ndst = NC; b = blockIdx.x;
    } else {
        staged = stG; out = outG; rp = rpG; cb = cbase + 257;
        shift = 9; packshift = 11; ndst = NG; b = blockIdx.x - P2_CBLK;
    }
    int tid = threadIdx.x;
    int nf = 1 << shift;
    int d0 = b << shift;
    int j0 = cb[b], j1 = cb[b + 1];
    for (int f = tid; f < nf; f += 256) hist[f] = 0;
    __syncthreads();
    for (int j = j0 + tid; j < j1; j += 256)
        atomicAdd(&hist[((unsigned)staged[j].x) >> packshift], 1);
    __syncthreads();
    // exclusive scan over hist[0..nf)
    int chunk = (nf + 255) >> 8;                 // 1 or 2
    int s = 0;
#pragma unroll 2
    for (int k = 0; k < chunk; ++k) {
        int idx = tid * chunk + k;
        if (idx < nf) s += hist[idx];
    }
    sd[tid] = s; __syncthreads();
    for (int off = 1; off < 256; off <<= 1) {
        int u = (tid >= off) ? sd[tid - off] : 0; __syncthreads();
        sd[tid] += u; __syncthreads();
    }
    int run = sd[tid] - s;                       // exclusive base for this thread's chunk
#pragma unroll 2
    for (int k = 0; k < chunk; ++k) {
        int idx = tid * chunk + k;
        if (idx < nf) {
            int h = hist[idx];
            int pos = j0 + run;
            cur[idx] = pos;
            int d = d0 + idx;
            if (d < ndst) rp[d] = pos;
            run += h;
        }
    }
    __syncthreads();
    // scatter within the bucket's contiguous (cache-local) output region
    for (int j = j0 + tid; j < j1; j += 256) {
        int2 e = staged[j];
        int f = ((unsigned)e.x) >> packshift;
        int pos = atomicAdd(&cur[f], 1);
        out[pos] = make_int2(e.x & ((1 << packshift) - 1), e.y);
    }
}

// ------- cheap per-cell gene-grouping: LDS counting-bucket by gene>>9 -------
// Round 13: restores the cross-block "gene sweep" locality the old bitonic
// sort provided (all 2000 cell blocks gather within a synchronized narrow
// gene window -> L2/L3 hits) at ~1/6 the cost: 256-bin counting group
// instead of a 10-stage bitonic sort. Perf-only reordering (sum is
// order-independent); n>1024 segments are left ungrouped (never happens:
// Binomial(1M,1/2000) max ~600).
__global__ __launch_bounds__(256) void group_cell_edges(const int* __restrict__ rp,
                                                        int2* __restrict__ ec) {
    __shared__ int2 s[1024];
    __shared__ int hist[256], cur[256], sd[256];
    int c = blockIdx.x;
    int j0 = rp[c], j1 = rp[c + 1];
    int n = j1 - j0;
    if (n <= 1 || n > 1024) return;
    int tid = threadIdx.x;
    for (int i = tid; i < n; i += 256) s[i] = ec[j0 + i];
    hist[tid] = 0;
    __syncthreads();
    for (int i = tid; i < n; i += 256)
        atomicAdd(&hist[((unsigned)s[i].x) >> 9], 1);    // gene>>9: 0..195
    __syncthreads();
    int v = hist[tid];
    sd[tid] = v; __syncthreads();
    for (int off = 1; off < 256; off <<= 1) {
        int u = (tid >= off) ? sd[tid - off] : 0; __syncthreads();
        sd[tid] += u; __syncthreads();
    }
    cur[tid] = sd[tid] - v;                              // exclusive base
    __syncthreads();
    for (int i = tid; i < n; i += 256) {
        int2 e = s[i];
        int pos = atomicAdd(&cur[((unsigned)e.x) >> 9], 1);
        ec[j0 + pos] = e;
    }
}

// --------------- gene aggregation: one wave per destination row -------------
// Pure gather. Scalar edge records (readfirstlane'd j0/j1 -> s_loads),
// half-wave 2-edges-per-uint4 gathers, 2 in flight.
__global__ void agg_gene(const int* __restrict__ rp, const int2* __restrict__ eg,
                         const unsigned short* __restrict__ src, long sstride,
                         unsigned short* __restrict__ agg_out, int nrows) {
    int wave = (blockIdx.x * blockDim.x + threadIdx.x) >> 6;
    int lane = threadIdx.x & 63;
    if (wave >= nrows) return;
    int j0 = __builtin_amdgcn_readfirstlane(rp[wave]);
    int j1 = __builtin_amdgcn_readfirstlane(rp[wave + 1]);
    int half = lane >> 5;        // 0: edge A, 1: edge B of each gather pair
    int lh = lane & 31;          // 16B slot within the 512B row
    float a0=0.f,a1=0.f,a2=0.f,a3=0.f,a4=0.f,a5=0.f,a6=0.f,a7=0.f;
    int j = j0;
    for (; j + 4 <= j1; j += 4) {
        int2 e0 = eg[j], e1 = eg[j + 1], e2 = eg[j + 2], e3 = eg[j + 3];
        int   rA = half ? e1.x : e0.x;
        float wA = __int_as_float(half ? e1.y : e0.y);
        int   rB = half ? e3.x : e2.x;
        float wB = __int_as_float(half ? e3.y : e2.y);
        uint4 pA = *reinterpret_cast<const uint4*>(src + (size_t)rA * sstride + lh * 8);
        uint4 pB = *reinterpret_cast<const uint4*>(src + (size_t)rB * sstride + lh * 8);
        a0 += wA * bflo(pA.x) + wB * bflo(pB.x);
        a1 += wA * bfhi(pA.x) + wB * bfhi(pB.x);
        a2 += wA * bflo(pA.y) + wB * bflo(pB.y);
        a3 += wA * bfhi(pA.y) + wB * bfhi(pB.y);
        a4 += wA * bflo(pA.z) + wB * bflo(pB.z);
        a5 += wA * bfhi(pA.z) + wB * bfhi(pB.z);
        a6 += wA * bflo(pA.w) + wB * bflo(pB.w);
        a7 += wA * bfhi(pA.w) + wB * bfhi(pB.w);
    }
    for (; j < j1; j += 2) {
        int2 e0 = eg[j];
        int2 e1 = (j + 1 < j1) ? eg[j + 1] : make_int2(e0.x, 0);  // w=0 pad
        int   r = half ? e1.x : e0.x;
        float w = __int_as_float(half ? e1.y : e0.y);
        uint4 p = *reinterpret_cast<const uint4*>(src + (size_t)r * sstride + lh * 8);
        a0 += w * bflo(p.x); a1 += w * bfhi(p.x);
        a2 += w * bflo(p.y); a3 += w * bfhi(p.y);
        a4 += w * bflo(p.z); a5 += w * bfhi(p.z);
        a6 += w * bflo(p.w); a7 += w * bfhi(p.w);
    }
    // combine the two half-wave partials
    a0 += __shfl_xor(a0, 32, 64); a1 += __shfl_xor(a1, 32, 64);
    a2 += __shfl_xor(a2, 32, 64); a3 += __shfl_xor(a3, 32, 64);
    a4 += __shfl_xor(a4, 32, 64); a5 += __shfl_xor(a5, 32, 64);
    a6 += __shfl_xor(a6, 32, 64); a7 += __shfl_xor(a7, 32, 64);
    if (lane < 32) {
        uint4 o;
        o.x = (unsigned)f2bf(a0) | ((unsigned)f2bf(a1) << 16);
        o.y = (unsigned)f2bf(a2) | ((unsigned)f2bf(a3) << 16);
        o.z = (unsigned)f2bf(a4) | ((unsigned)f2bf(a5) << 16);
        o.w = (unsigned)f2bf(a6) | ((unsigned)f2bf(a7) << 16);
        *reinterpret_cast<uint4*>(agg_out + (size_t)wave * D + lane * 8) = o;
    }
}

// ---------------- gene GEMM: xg1 = relu(agg@W1^T + x@Wc^T + w*(x@W2^T) + b) -
// Round-7 form (best measured): dual accumulator derives the w_gg term in
// registers; A + W async16-staged through 48 KB LDS.
__global__ __launch_bounds__(256, 2) void gene_gemm(
        const unsigned short* __restrict__ Agg,  // [NG][256] bf16
        const unsigned short* __restrict__ Xb,   // [NG][256] bf16
        const float* __restrict__ w_gg,          // [NG]
        const unsigned short* __restrict__ W,    // [256][768]: rel1|rootc|rel2
        const float* __restrict__ bias,          // [256]
        unsigned short* __restrict__ xg1) {      // out [NG][256]
    __shared__ unsigned short As[128 * 64];      // 16 KB
    __shared__ unsigned short Bs1[128 * 64];     // 16 KB
    __shared__ unsigned short Bs2[128 * 64];     // 16 KB
    int tid = threadIdx.x;
    int wv = tid >> 6, ln = tid & 63;
    int lm = ln & 15, lq = ln >> 4;
    int m0 = blockIdx.x * 128;
    int nb = blockIdx.y * 128;
    int m0w = m0 + (wv >> 1) * 64;
    int n0w = nb + (wv & 1) * 64;

    f32x4 accA[4][4], accV[4][4];
#pragma unroll
    for (int i = 0; i < 4; ++i)
#pragma unroll
        for (int j = 0; j < 4; ++j) { accA[i][j] = f32x4{0,0,0,0}; accV[i][j] = f32x4{0,0,0,0}; }

    // ---- segment A: agg @ Wrel1^T ----
    for (int k0 = 0; k0 < 256; k0 += 64) {
#pragma unroll
        for (int t = 0; t < 4; ++t) {
            int ci = t * 256 + tid;
            int r = ci >> 3, s = ci & 7;
            int cg = s ^ (r & 7);
            int row = m0 + r; if (row >= NG) row = NG - 1;
            async16(Agg + (size_t)row * D + k0 + cg * 8, (unsigned char*)As + ci * 16);
            async16(W + (size_t)(nb + r) * KCAT + k0 + cg * 8, (unsigned char*)Bs1 + ci * 16);
        }
        __syncthreads();
#pragma unroll
        for (int kk = 0; kk < 2; ++kk) {
            bf16x8 a[4], b[4];
#pragma unroll
            for (int i = 0; i < 4; ++i) {
                int r = (wv >> 1) * 64 + i * 16 + lm;
                int s = (kk * 4 + lq) ^ (r & 7);
                a[i] = *reinterpret_cast<const bf16x8*>(As + (r * 8 + s) * 8);
            }
#pragma unroll
            for (int j = 0; j < 4; ++j) {
                int r = (wv & 1) * 64 + j * 16 + lm;
                int s = (kk * 4 + lq) ^ (r & 7);
                b[j] = *reinterpret_cast<const bf16x8*>(Bs1 + (r * 8 + s) * 8);
            }
#pragma unroll
            for (int i = 0; i < 4; ++i)
#pragma unroll
                for (int j = 0; j < 4; ++j)
                    accA[i][j] = __builtin_amdgcn_mfma_f32_16x16x32_bf16(a[i], b[j], accA[i][j], 0, 0, 0);
        }
        __syncthreads();
    }

    // ---- segment X: x @ (Wroot1+Wroot2)^T into accA, x @ Wrel2^T into accV -
    for (int k0 = 0; k0 < 256; k0 += 64) {
#pragma unroll
        for (int t = 0; t < 4; ++t) {
            int ci = t * 256 + tid;
            int r = ci >> 3, s = ci & 7;
            int cg = s ^ (r & 7);
            int row = m0 + r; if (row >= NG) row = NG - 1;
            async16(Xb + (size_t)row * D + k0 + cg * 8, (unsigned char*)As + ci * 16);
            async16(W + (size_t)(nb + r) * KCAT + 256 + k0 + cg * 8, (unsigned char*)Bs1 + ci * 16);
            async16(W + (size_t)(nb + r) * KCAT + 512 + k0 + cg * 8, (unsigned char*)Bs2 + ci * 16);
        }
        __syncthreads();
#pragma unroll
        for (int kk = 0; kk < 2; ++kk) {
            bf16x8 a[4], b1[4], b2[4];
#pragma unroll
            for (int i = 0; i < 4; ++i) {
                int r = (wv >> 1) * 64 + i * 16 + lm;
                int s = (kk * 4 + lq) ^ (r & 7);
                a[i] = *reinterpret_cast<const bf16x8*>(As + (r * 8 + s) * 8);
            }
#pragma unroll
            for (int j = 0; j < 4; ++j) {
                int r = (wv & 1) * 64 + j * 16 + lm;
                int s = (kk * 4 + lq) ^ (r & 7);
                b1[j] = *reinterpret_cast<const bf16x8*>(Bs1 + (r * 8 + s) * 8);
                b2[j] = *reinterpret_cast<const bf16x8*>(Bs2 + (r * 8 + s) * 8);
            }
#pragma unroll
            for (int i = 0; i < 4; ++i)
#pragma unroll
                for (int j = 0; j < 4; ++j) {
                    accA[i][j] = __builtin_amdgcn_mfma_f32_16x16x32_bf16(a[i], b1[j], accA[i][j], 0, 0, 0);
                    accV[i][j] = __builtin_amdgcn_mfma_f32_16x16x32_bf16(a[i], b2[j], accV[i][j], 0, 0, 0);
                }
        }
        __syncthreads();
    }

    // ---- epilogue ----
#pragma unroll
    for (int i = 0; i < 4; ++i) {
#pragma unroll
        for (int r4 = 0; r4 < 4; ++r4) {
            int row = m0w + i * 16 + lq * 4 + r4;
            if (row >= NG) continue;
            float wr = w_gg[row];
#pragma unroll
            for (int j = 0; j < 4; ++j) {
                int col = n0w + j * 16 + lm;
                float v = accA[i][j][r4] + wr * accV[i][j][r4] + bias[col];
                v = v > 0.f ? v : 0.f;
                xg1[(size_t)row * D + col] = f2bf(v);
            }
        }
    }
}

// ---------------- cell aggregation: one block per cell, LDS reduce ----------
// 8 edges/wave/iter (4 uint4 gathers in flight), scalar edge records,
// half-wave 2-edges-per-uint4 gathers; tail = pair loop with w=0 padding.
__global__ __launch_bounds__(256) void agg_cell(const int* __restrict__ rp,
                                                const int2* __restrict__ ec,
                                                const unsigned short* __restrict__ src, long sstride,
                                                unsigned short* __restrict__ out, long ostride) {
    __shared__ float red[4][D];
    int c = blockIdx.x;
    int wv = threadIdx.x >> 6, ln = threadIdx.x & 63;
    int half = ln >> 5, lh = ln & 31;
    int j0 = __builtin_amdgcn_readfirstlane(rp[c]);
    int j1 = __builtin_amdgcn_readfirstlane(rp[c + 1]);
    float a0=0.f,a1=0.f,a2=0.f,a3=0.f,a4=0.f,a5=0.f,a6=0.f,a7=0.f;
    int n32 = (j1 - j0) & ~31;         // chunks of 32 = 4 waves x 8 edges
    for (int j = j0 + wv * 8; j < j0 + n32; j += 32) {
        int2 e0 = ec[j],     e1 = ec[j + 1], e2 = ec[j + 2], e3 = ec[j + 3];
        int2 e4 = ec[j + 4], e5 = ec[j + 5], e6 = ec[j + 6], e7 = ec[j + 7];
        int   rA = half ? e1.x : e0.x;  float wA = __int_as_float(half ? e1.y : e0.y);
        int   rB = half ? e3.x : e2.x;  float wB = __int_as_float(half ? e3.y : e2.y);
        int   rC = half ? e5.x : e4.x;  float wC = __int_as_float(half ? e5.y : e4.y);
        int   rD = half ? e7.x : e6.x;  float wD = __int_as_float(half ? e7.y : e6.y);
        uint4 pA = *reinterpret_cast<const uint4*>(src + (size_t)rA * sstride + lh * 8);
        uint4 pB = *reinterpret_cast<const uint4*>(src + (size_t)rB * sstride + lh * 8);
        uint4 pC = *reinterpret_cast<const uint4*>(src + (size_t)rC * sstride + lh * 8);
        uint4 pD = *reinterpret_cast<const uint4*>(src + (size_t)rD * sstride + lh * 8);
        a0 += wA * bflo(pA.x) + wB * bflo(pB.x) + wC * bflo(pC.x) + wD * bflo(pD.x);
        a1 += wA * bfhi(pA.x) + wB * bfhi(pB.x) + wC * bfhi(pC.x) + wD * bfhi(pD.x);
        a2 += wA * bflo(pA.y) + wB * bflo(pB.y) + wC * bflo(pC.y) + wD * bflo(pD.y);
        a3 += wA * bfhi(pA.y) + wB * bfhi(pB.y) + wC * bfhi(pC.y) + wD * bfhi(pD.y);
        a4 += wA * bflo(pA.z) + wB * bflo(pB.z) + wC * bflo(pC.z) + wD * bflo(pD.z);
        a5 += wA * bfhi(pA.z) + wB * bfhi(pB.z) + wC * bfhi(pC.z) + wD * bfhi(pD.z);
        a6 += wA * bflo(pA.w) + wB * bflo(pB.w) + wC * bflo(pC.w) + wD * bflo(pD.w);
        a7 += wA * bfhi(pA.w) + wB * bfhi(pB.w) + wC * bfhi(pC.w) + wD * bfhi(pD.w);
    }
    // tail: <=31 edges, pairs round-robin across waves, w=0 padding
    for (int j = j0 + n32 + wv * 2; j < j1; j += 8) {
        int2 e0 = ec[j];
        int2 e1 = (j + 1 < j1) ? ec[j + 1] : make_int2(e0.x, 0);
        int   r = half ? e1.x : e0.x;
        float w = __int_as_float(half ? e1.y : e0.y);
        uint4 p = *reinterpret_cast<const uint4*>(src + (size_t)r * sstride + lh * 8);
        a0 += w * bflo(p.x); a1 += w * bfhi(p.x);
        a2 += w * bflo(p.y); a3 += w * bfhi(p.y);
        a4 += w * bflo(p.z); a5 += w * bfhi(p.z);
        a6 += w * bflo(p.w); a7 += w * bfhi(p.w);
    }
    // combine half-wave partials, then cross-wave LDS reduce
    a0 += __shfl_xor(a0, 32, 64); a1 += __shfl_xor(a1, 32, 64);
    a2 += __shfl_xor(a2, 32, 64); a3 += __shfl_xor(a3, 32, 64);
    a4 += __shfl_xor(a4, 32, 64); a5 += __shfl_xor(a5, 32, 64);
    a6 += __shfl_xor(a6, 32, 64); a7 += __shfl_xor(a7, 32, 64);
    if (ln < 32) {
        *reinterpret_cast<float4*>(&red[wv][lh * 8])     = make_float4(a0, a1, a2, a3);
        *reinterpret_cast<float4*>(&red[wv][lh * 8 + 4]) = make_float4(a4, a5, a6, a7);
    }
    __syncthreads();
    int col = threadIdx.x;
    float s = red[0][col] + red[1][col] + red[2][col] + red[3][col];
    out[(size_t)c * ostride + col] = f2bf(s);
}

// ---------------- m97-style GEMM (cells): relu(A[M,768] @ W^T + bias) -------
__global__ __launch_bounds__(256, 2) void gemm_tile(
        const unsigned short* __restrict__ A,    // [M][768]
        const unsigned short* __restrict__ W,    // [256][768]
        const float* __restrict__ bias,          // [256]
        const float* __restrict__ wrow,          // nullable per-row scale for vout
        unsigned short* __restrict__ xout, long xstride,
        unsigned short* __restrict__ vout,       // nullable, same stride
        int M) {
    __shared__ unsigned short As[128 * 64];
    __shared__ unsigned short Bs[128 * 64];
    int tid = threadIdx.x;
    int wv = tid >> 6, ln = tid & 63;
    int lm = ln & 15, lq = ln >> 4;
    int m0 = blockIdx.x * 128;
    int nb = blockIdx.y * 128;
    int m0w = m0 + (wv >> 1) * 64;
    int n0w = nb + (wv & 1) * 64;

    f32x4 acc[4][4];
#pragma unroll
    for (int i = 0; i < 4; ++i)
#pragma unroll
        for (int j = 0; j < 4; ++j) acc[i][j] = f32x4{0.f, 0.f, 0.f, 0.f};

    for (int k0 = 0; k0 < KCAT; k0 += 64) {
#pragma unroll
        for (int t = 0; t < 4; ++t) {
            int ci = t * 256 + tid;
            int r = ci >> 3, s = ci & 7;
            int cg = s ^ (r & 7);
            int row = m0 + r; if (row >= M) row = M - 1;
            async16(A + (size_t)row * KCAT + k0 + cg * 8,
                    (unsigned char*)As + ci * 16);
        }
#pragma unroll
        for (int t = 0; t < 4; ++t) {
            int ci = t * 256 + tid;
            int r = ci >> 3, s = ci & 7;
            int cg = s ^ (r & 7);
            async16(W + (size_t)(nb + r) * KCAT + k0 + cg * 8,
                    (unsigned char*)Bs + ci * 16);
        }
        __syncthreads();
#pragma unroll
        for (int kk = 0; kk < 2; ++kk) {
            bf16x8 a[4], b[4];
#pragma unroll
            for (int i = 0; i < 4; ++i) {
                int r = (wv >> 1) * 64 + i * 16 + lm;
                int c = kk * 4 + lq;
                int s = c ^ (r & 7);
                a[i] = *reinterpret_cast<const bf16x8*>(As + (r * 8 + s) * 8);
            }
#pragma unroll
            for (int j = 0; j < 4; ++j) {
                int r = (wv & 1) * 64 + j * 16 + lm;
                int c = kk * 4 + lq;
                int s = c ^ (r & 7);
                b[j] = *reinterpret_cast<const bf16x8*>(Bs + (r * 8 + s) * 8);
            }
#pragma unroll
            for (int i = 0; i < 4; ++i)
#pragma unroll
                for (int j = 0; j < 4; ++j)
                    acc[i][j] = __builtin_amdgcn_mfma_f32_16x16x32_bf16(a[i], b[j], acc[i][j], 0, 0, 0);
        }
        __syncthreads();
    }

#pragma unroll
    for (int i = 0; i < 4; ++i) {
#pragma unroll
        for (int r4 = 0; r4 < 4; ++r4) {
            int rr = m0w + i * 16 + lq * 4 + r4;
            if (rr >= M) continue;
            float wr = wrow ? wrow[rr] : 0.f;
#pragma unroll
            for (int j = 0; j < 4; ++j) {
                int col = n0w + j * 16 + lm;
                float v = acc[i][j][r4] + bias[col];
                v = v > 0.f ? v : 0.f;
                xout[(size_t)rr * xstride + col] = f2bf(v);
                if (vout) vout[(size_t)rr * xstride + col] = f2bf(v * wr);
            }
        }
    }
}

// ---------------- final projection: out = xc2 @ Wout^T + bout (fp32) --------
// Wout staged in LDS (f32, +1 pad -> conflict-free) in two 32-row passes;
// Block = 8 cells x 32 outs per pass.
__global__ __launch_bounds__(256) void out_kernel(const unsigned short* __restrict__ xc,
                                                  const float* __restrict__ Wout,
                                                  const float* __restrict__ bout,
                                                  float* __restrict__ out) {
    __shared__ float srow[8][D];            // 8 KB
    __shared__ float wlds[32][D + 1];       // 32.1 KB
    int tid = threadIdx.x;
    // stage 8 cell rows (bf16 -> f32)
    for (int t = tid; t < 8 * D; t += 256) {
        int rr = blockIdx.x * 8 + (t >> 8);
        unsigned short h = xc[(size_t)rr * D + (t & 255)];
        srow[t >> 8][t & 255] = __uint_as_float(((unsigned)h) << 16);
    }
    int r = tid >> 5, ol = tid & 31;
    float res[2];
#pragma unroll
    for (int p = 0; p < 2; ++p) {
        __syncthreads();
        // stage 32 Wout rows (coalesced float4 global, scalar LDS writes)
        for (int t = tid; t < 32 * (D / 4); t += 256) {
            int o = t >> 6, k4 = (t & 63) * 4;
            float4 wv = *reinterpret_cast<const float4*>(Wout + (size_t)(p * 32 + o) * D + k4);
            wlds[o][k4 + 0] = wv.x; wlds[o][k4 + 1] = wv.y;
            wlds[o][k4 + 2] = wv.z; wlds[o][k4 + 3] = wv.w;
        }
        __syncthreads();
        float s = 0.f;
        for (int k = 0; k < D; ++k) s += srow[r][k] * wlds[ol][k];
        res[p] = s;
    }
    int c = blockIdx.x * 8 + r;
    out[(size_t)c * NOUTD + ol] = res[0] + bout[ol];
    out[(size_t)c * NOUTD + 32 + ol] = res[1] + bout[32 + ol];
}

// ---------------- orchestration ---------------------------------------------
extern "C" void kernel_launch(void* const* d_in, const int* in_sizes, int n_in,
                              void* d_out, int out_size, void* d_ws, size_t ws_size,
                              hipStream_t stream) {
    const float* x_gene = (const float*)d_in[0];
    const float* x_cell = (const float*)d_in[1];
    const int*   src_g2c = (const int*)d_in[2];
    const int*   dst_g2c = (const int*)d_in[3];
    const int*   src_c2g = (const int*)d_in[4];
    const int*   dst_c2g = (const int*)d_in[5];
    const float* w_g2c = (const float*)d_in[8];
    const float* w_c2g = (const float*)d_in[9];
    const float* w_gg  = (const float*)d_in[10];
    const float* w_cc  = (const float*)d_in[11];
    const float* Wrel  = (const float*)d_in[12];
    const float* brel  = (const float*)d_in[13];
    const float* Wroot = (const float*)d_in[14];
    const float* Wout  = (const float*)d_in[15];
    const float* bout  = (const float*)d_in[16];
    float* out = (float*)d_out;

    char* p = (char*)d_ws;
    auto alloc = [&](size_t bytes) -> char* {
        char* r = p;
        p += (bytes + 255) & ~(size_t)255;
        return r;
    };

    unsigned short* xg0b    = (unsigned short*)alloc((size_t)NG * D * 2);
    unsigned short* xg1     = (unsigned short*)alloc((size_t)NG * D * 2);
    unsigned short* agg_g   = (unsigned short*)alloc((size_t)NG * D * 2);
    unsigned short* Acat_c0 = (unsigned short*)alloc((size_t)NC * KCAT * 2);
    unsigned short* Acat_c1 = (unsigned short*)alloc((size_t)NC * KCAT * 2);
    unsigned short* xc2     = (unsigned short*)alloc((size_t)NC * D * 2);
    int* rp_g  = (int*)alloc((NG + 1) * 4);
    int* rp_c  = (int*)alloc((NC + 1) * 4);
    int2* ec = (int2*)alloc((size_t)NE * 8);       // g2c edges grouped by cell
    int2* eg = (int2*)alloc((size_t)NE * 8);       // c2g edges grouped by gene
    int2* st_c = (int2*)alloc((size_t)NE * 8);     // coarse-bucketed staging
    int2* st_g = (int2*)alloc((size_t)NE * 8);
    int* hist512 = (int*)alloc(512 * 4);
    int* cbase   = (int*)alloc(514 * 4);
    int* ccur_c  = (int*)alloc(256 * 4);
    int* ccur_g  = (int*)alloc(256 * 4);
    unsigned short* Wg0 = (unsigned short*)alloc((size_t)D * KCAT * 2);
    unsigned short* Wc0 = (unsigned short*)alloc((size_t)D * KCAT * 2);
    unsigned short* Wc1 = (unsigned short*)alloc((size_t)D * KCAT * 2);
    float* bg0 = (float*)alloc(D * 4);
    float* bc0 = (float*)alloc(D * 4);
    float* bc1 = (float*)alloc(D * 4);

    hipMemsetAsync(hist512, 0, 512 * 4, stream);

    // cell prep (x + v into Acat_c0 cols)
    prep_x<<<(NC * 64 + 255) / 256, 256, 0, stream>>>(x_cell, w_cc, Acat_c0 + 256, Acat_c0 + 512, KCAT, NC);

    // all 3 weight matrices in one launch
    build_wcat3<<<dim3((D * D + 255) / 256, 3), 256, 0, stream>>>(
        Wrel, Wroot, brel, Wg0, Wc0, Wc1, bg0, bc0, bc1);

    // ---- CSR build (+ fused x_gene conversion) ----
    coarse_count_conv<<<CCB + CONVB, 256, 0, stream>>>(dst_g2c, dst_c2g, hist512, x_gene, xg0b);
    coarse_scan<<<1, 256, 0, stream>>>(hist512, cbase, ccur_c, ccur_g, rp_c, rp_g);
    const int P1B = (NE + P1_CHUNK - 1) / P1_CHUNK;
    bucket_pass1<<<dim3(P1B, 2), 256, 0, stream>>>(
        src_g2c, dst_g2c, w_g2c, ccur_c, st_c,
        src_c2g, dst_c2g, w_c2g, ccur_g, st_g);
    bucket_pass2<<<P2_CBLK + P2_GBLK, 256, 0, stream>>>(
        st_c, ec, rp_c, st_g, eg, rp_g, cbase);
    // cheap per-cell gene-grouping (replaces the deleted bitonic sort at ~1/6 cost)
    group_cell_edges<<<NC, 256, 0, stream>>>(rp_c, ec);

    // ---- gene path ----
    agg_gene<<<(NG + 3) / 4, 256, 0, stream>>>(
        rp_g, eg, Acat_c0 + 256, KCAT, agg_g, NG);
    gene_gemm<<<dim3((NG + 127) / 128, 2), 256, 0, stream>>>(
        agg_g, xg0b, w_gg, Wg0, bg0, xg1);

    // ---- Layer 0 cells ----
    agg_cell<<<NC, 256, 0, stream>>>(rp_c, ec, xg0b, D, Acat_c0, KCAT);
    gemm_tile<<<dim3((NC + 127) / 128, 2), 256, 0, stream>>>(
        Acat_c0, Wc0, bc0, w_cc, Acat_c1 + 256, KCAT, Acat_c1 + 512, NC);

    // ---- Layer 1 cells ----
    agg_cell<<<NC, 256, 0, stream>>>(rp_c, ec, xg1, D, Acat_c1, KCAT);
    gemm_tile<<<dim3((NC + 127) / 128, 2), 256, 0, stream>>>(
        Acat_c1, Wc1, bc1, nullptr, xc2, D, nullptr, NC);

    // ---- output projection ----
    out_kernel<<<NC / 8, 256, 0, stream>>>(xc2, Wout, bout, out);
}

// Round 14
// 550.102 us; speedup vs baseline: 1.0651x; 1.0194x over previous
//
#include <hip/hip_runtime.h>

// Problem constants
static constexpr int NG   = 100000;
static constexpr int NC   = 2000;
static constexpr int D    = 256;
static constexpr int NE   = 1000000;
static constexpr int NOUTD= 64;
static constexpr int KCAT = 768;          // concatenated K: [agg | x | v]

typedef __bf16 bf16x8 __attribute__((ext_vector_type(8)));
typedef float  f32x4  __attribute__((ext_vector_type(4)));

__device__ __forceinline__ unsigned short f2bf(float f) {
    unsigned u = __float_as_uint(f);
    u += 0x7fffu + ((u >> 16) & 1u);   // RNE
    return (unsigned short)(u >> 16);
}
__device__ __forceinline__ float bflo(unsigned x) { return __uint_as_float((x & 0xffffu) << 16); }
__device__ __forceinline__ float bfhi(unsigned x) { return __uint_as_float(x & 0xffff0000u); }

__device__ __forceinline__ void async16(const void* g, void* l) {
    __builtin_amdgcn_global_load_lds(
        (const __attribute__((address_space(1))) void*)g,
        (__attribute__((address_space(3))) void*)l, 16, 0, 0);
}

// ---------------- prep (cells only): f32 -> bf16 x and v=x*w ----------------
__global__ void prep_x(const float* __restrict__ x, const float* __restrict__ w,
                       unsigned short* __restrict__ dx, unsigned short* __restrict__ dv,
                       long stride, int rows) {
    int i = blockIdx.x * blockDim.x + threadIdx.x;   // one per 4 elements
    if (i >= rows * (D / 4)) return;
    int row = i >> 6, c4 = (i & 63) * 4;
    float4 xv = *reinterpret_cast<const float4*>(x + (size_t)row * D + c4);
    float wv = w[row];
    uint2 ox, ov;
    ox.x = (unsigned)f2bf(xv.x) | ((unsigned)f2bf(xv.y) << 16);
    ox.y = (unsigned)f2bf(xv.z) | ((unsigned)f2bf(xv.w) << 16);
    ov.x = (unsigned)f2bf(xv.x * wv) | ((unsigned)f2bf(xv.y * wv) << 16);
    ov.y = (unsigned)f2bf(xv.z * wv) | ((unsigned)f2bf(xv.w * wv) << 16);
    *reinterpret_cast<uint2*>(dx + (size_t)row * stride + c4) = ox;
    *reinterpret_cast<uint2*>(dv + (size_t)row * stride + c4) = ov;
}

// -------- build all 3 concatenated bf16 weight mats [256][768] + bias sums --
// y=0: gene L0 (ia=1, ib=2); y=1: cell L0 (0,3); y=2: cell L1 (4,7)
__global__ void build_wcat3(const float* __restrict__ Wrel, const float* __restrict__ Wroot,
                            const float* __restrict__ brel,
                            unsigned short* __restrict__ Wg0, unsigned short* __restrict__ Wc0,
                            unsigned short* __restrict__ Wc1,
                            float* __restrict__ bg0, float* __restrict__ bc0,
                            float* __restrict__ bc1) {
    int i = blockIdx.x * blockDim.x + threadIdx.x;
    if (i >= D * D) return;
    int ia, ib; unsigned short* wout; float* bsum;
    if (blockIdx.y == 0)      { ia = 1; ib = 2; wout = Wg0; bsum = bg0; }
    else if (blockIdx.y == 1) { ia = 0; ib = 3; wout = Wc0; bsum = bc0; }
    else                      { ia = 4; ib = 7; wout = Wc1; bsum = bc1; }
    const int WW = D * D;
    int n = i >> 8, k = i & 255;
    wout[(size_t)n * KCAT + k]        = f2bf(Wrel[ia * WW + i]);
    wout[(size_t)n * KCAT + 256 + k]  = f2bf(Wroot[ia * WW + i] + Wroot[ib * WW + i]);
    wout[(size_t)n * KCAT + 512 + k]  = f2bf(Wrel[ib * WW + i]);
    if (i < D) bsum[i] = brel[ia * D + i] + brel[ib * D + i];
}

// ------ coarse histogram (256 bins/relation) + fused x_gene conversion ------
static constexpr int CC_CHUNK = 8192;
static constexpr int CCB = (NE + CC_CHUNK - 1) / CC_CHUNK;   // 123
static constexpr int CONVB = NG * (D / 4) / 256;             // 25000
__global__ __launch_bounds__(256) void coarse_count_conv(
        const int* __restrict__ dst_g2c, const int* __restrict__ dst_c2g,
        int* __restrict__ hist,                               // [512]
        const float* __restrict__ x_gene, unsigned short* __restrict__ xg0b) {
    __shared__ int h[512];
    if (blockIdx.x >= CCB) {
        int i = (blockIdx.x - CCB) * 256 + threadIdx.x;       // quarter-row id
        int row = i >> 6, c4 = (i & 63) * 4;
        float4 xv = *reinterpret_cast<const float4*>(x_gene + (size_t)row * D + c4);
        uint2 xo;
        xo.x = (unsigned)f2bf(xv.x) | ((unsigned)f2bf(xv.y) << 16);
        xo.y = (unsigned)f2bf(xv.z) | ((unsigned)f2bf(xv.w) << 16);
        *reinterpret_cast<uint2*>(xg0b + (size_t)row * D + c4) = xo;
        return;
    }
    h[threadIdx.x] = 0; h[256 + threadIdx.x] = 0;
    __syncthreads();
    int base = blockIdx.x * CC_CHUNK;
#pragma unroll 4
    for (int t = 0; t < CC_CHUNK / 256; ++t) {
        int e = base + t * 256 + threadIdx.x;
        if (e < NE) {
            atomicAdd(&h[dst_g2c[e] >> 3], 1);          // cell bins
            atomicAdd(&h[256 + (dst_c2g[e] >> 9)], 1);  // gene bins
        }
    }
    __syncthreads();
    if (h[threadIdx.x]) atomicAdd(&hist[threadIdx.x], h[threadIdx.x]);
    if (h[256 + threadIdx.x]) atomicAdd(&hist[256 + threadIdx.x], h[256 + threadIdx.x]);
}

// ---- coarse scan: cbase[0..256]=cells, cbase[257..513]=genes; init cursors -
__global__ __launch_bounds__(256) void coarse_scan(const int* __restrict__ hist,
                                                   int* __restrict__ cbase,
                                                   int* __restrict__ ccur_c, int* __restrict__ ccur_g,
                                                   int* __restrict__ rp_c, int* __restrict__ rp_g) {
    __shared__ int sd[256];
    int t = threadIdx.x;
    {
        int v = hist[t];
        sd[t] = v; __syncthreads();
        for (int off = 1; off < 256; off <<= 1) {
            int u = (t >= off) ? sd[t - off] : 0; __syncthreads();
            sd[t] += u; __syncthreads();
        }
        int e = sd[t] - v;
        cbase[t] = e; ccur_c[t] = e;
        if (t == 255) cbase[256] = sd[255];
        __syncthreads();
    }
    {
        int v = hist[256 + t];
        sd[t] = v; __syncthreads();
        for (int off = 1; off < 256; off <<= 1) {
            int u = (t >= off) ? sd[t - off] : 0; __syncthreads();
            sd[t] += u; __syncthreads();
        }
        int e = sd[t] - v;
        cbase[257 + t] = e; ccur_g[t] = e;
        if (t == 255) cbase[513] = sd[255];
    }
    if (t == 0) { rp_c[NC] = NE; rp_g[NG] = NE; }
}

// pass1 (fused c/g via blockIdx.y): scatter edges into 256 coarse buckets
static constexpr int P1_CHUNK = 8192;
__global__ __launch_bounds__(256) void bucket_pass1(
        const int* __restrict__ srcA, const int* __restrict__ dstA, const float* __restrict__ wA,
        int* __restrict__ curA, int2* __restrict__ outA,
        const int* __restrict__ srcB, const int* __restrict__ dstB, const float* __restrict__ wB,
        int* __restrict__ curB, int2* __restrict__ outB) {
    __shared__ int hist[256], lcur[256], gbase[256];
    const int* src; const int* dst; const float* w; int* coarse_cur; int2* out;
    int shift, packshift;
    if (blockIdx.y == 0) { src = srcA; dst = dstA; w = wA; coarse_cur = curA; out = outA; shift = 3; packshift = 17; }
    else { src = srcB; dst = dstB; w = wB; coarse_cur = curB; out = outB; shift = 9; packshift = 11; }
    int tid = threadIdx.x;
    hist[tid] = 0;
    __syncthreads();
    int base = blockIdx.x * P1_CHUNK;
    int mybin[P1_CHUNK / 256];
#pragma unroll
    for (int t = 0; t < P1_CHUNK / 256; ++t) {
        int e = base + t * 256 + tid;
        if (e < NE) {
            int b = dst[e] >> shift;
            mybin[t] = b;
            atomicAdd(&hist[b], 1);
        } else mybin[t] = -1;
    }
    __syncthreads();
    int v = hist[tid];
    gbase[tid] = v ? atomicAdd(&coarse_cur[tid], v) : 0;
    lcur[tid] = 0;
    __syncthreads();
#pragma unroll
    for (int t = 0; t < P1_CHUNK / 256; ++t) {
        int b = mybin[t];
        if (b < 0) continue;
        int e = base + t * 256 + tid;
        int pos = gbase[b] + atomicAdd(&lcur[b], 1);
        int dl = dst[e] & ((1 << shift) - 1);
        out[pos] = make_int2(src[e] | (dl << packshift), __float_as_int(w[e]));
    }
}

// pass2 (fused): per bucket — fine LDS histogram + scan emits rp, then scatter
static constexpr int P2_CBLK = NC / 8;                 // 250
static constexpr int P2_GBLK = (NG + 511) / 512;       // 196
__global__ __launch_bounds__(256) void bucket_pass2(
        const int2* __restrict__ stC, int2* __restrict__ outC, int* __restrict__ rpC,
        const int2* __restrict__ stG, int2* __restrict__ outG, int* __restrict__ rpG,
        const int* __restrict__ cbase) {
    __shared__ int hist[512], cur[512], sd[256];
    const int2* staged; int2* out; int* rp; const int* cb;
    int shift, packshift, ndst, b;
    if (blockIdx.x < P2_CBLK) {
        staged = stC; out = outC; rp = rpC; cb = cbase;
        shift = 3; packshift = 17; ndst = NC; b = blockIdx.x;
    } else {
        staged = stG; out = outG; rp = rpG; cb = cbase + 257;
        shift = 9; packshift = 11; ndst = NG; b = blockIdx.x - P2_CBLK;
    }
    int tid = threadIdx.x;
    int nf = 1 << shift;
    int d0 = b << shift;
    int j0 = cb[b], j1 = cb[b + 1];
    for (int f = tid; f < nf; f += 256) hist[f] = 0;
    __syncthreads();
    for (int j = j0 + tid; j < j1; j += 256)
        atomicAdd(&hist[((unsigned)staged[j].x) >> packshift], 1);
    __syncthreads();
    // exclusive scan over hist[0..nf)
    int chunk = (nf + 255) >> 8;                 // 1 or 2
    int s = 0;
#pragma unroll 2
    for (int k = 0; k < chunk; ++k) {
        int idx = tid * chunk + k;
        if (idx < nf) s += hist[idx];
    }
    sd[tid] = s; __syncthreads();
    for (int off = 1; off < 256; off <<= 1) {
        int u = (tid >= off) ? sd[tid - off] : 0; __syncthreads();
        sd[tid] += u; __syncthreads();
    }
    int run = sd[tid] - s;                       // exclusive base for this thread's chunk
#pragma unroll 2
    for (int k = 0; k < chunk; ++k) {
        int idx = tid * chunk + k;
        if (idx < nf) {
            int h = hist[idx];
            int pos = j0 + run;
            cur[idx] = pos;
            int d = d0 + idx;
            if (d < ndst) rp[d] = pos;
            run += h;
        }
    }
    __syncthreads();
    // scatter within the bucket's contiguous (cache-local) output region
    for (int j = j0 + tid; j < j1; j += 256) {
        int2 e = staged[j];
        int f = ((unsigned)e.x) >> packshift;
        int pos = atomicAdd(&cur[f], 1);
        out[pos] = make_int2(e.x & ((1 << packshift) - 1), e.y);
    }
}

// ------- cheap per-cell gene-grouping: LDS counting-bucket by gene>>9 -------
// Restores the cross-block "gene sweep" locality (synchronized narrow gene
// window -> L2/L3 hits) at ~1/6 the old bitonic sort's cost. Perf-only
// reordering; n>1024 segments left ungrouped (never happens at this size).
__global__ __launch_bounds__(256) void group_cell_edges(const int* __restrict__ rp,
                                                        int2* __restrict__ ec) {
    __shared__ int2 s[1024];
    __shared__ int hist[256], cur[256], sd[256];
    int c = blockIdx.x;
    int j0 = rp[c], j1 = rp[c + 1];
    int n = j1 - j0;
    if (n <= 1 || n > 1024) return;
    int tid = threadIdx.x;
    for (int i = tid; i < n; i += 256) s[i] = ec[j0 + i];
    hist[tid] = 0;
    __syncthreads();
    for (int i = tid; i < n; i += 256)
        atomicAdd(&hist[((unsigned)s[i].x) >> 9], 1);    // gene>>9: 0..195
    __syncthreads();
    int v = hist[tid];
    sd[tid] = v; __syncthreads();
    for (int off = 1; off < 256; off <<= 1) {
        int u = (tid >= off) ? sd[tid - off] : 0; __syncthreads();
        sd[tid] += u; __syncthreads();
    }
    cur[tid] = sd[tid] - v;                              // exclusive base
    __syncthreads();
    for (int i = tid; i < n; i += 256) {
        int2 e = s[i];
        int pos = atomicAdd(&cur[((unsigned)e.x) >> 9], 1);
        ec[j0 + pos] = e;
    }
}

// ---- FUSED aggregation: agg_cell L0 (blocks [0,NC)) ∥ agg_gene (rest) ------
// Round 14: the two phases are data-independent (cell-L0 reads {rp_c,ec,
// xg0b}, writes Acat_c0 cols [0,256); gene reads {rp_g,eg, cell-x cols
// [256,768)}, writes agg_g) and use complementary resources (cell: 42% HBM
// BW; gene: latency-bound at 24% HBM). Grid fusion overlaps them without
// multi-stream (forbidden under graph capture). Long cell blocks dispatch
// first and fill the GPU; gene blocks backfill as they retire.
__global__ __launch_bounds__(256) void agg_fused(
        const int* __restrict__ rp_g, const int2* __restrict__ eg,
        const unsigned short* __restrict__ cellx,   // Acat_c0+256, stride KCAT
        unsigned short* __restrict__ agg_g,         // [NG][256]
        const int* __restrict__ rp_c, const int2* __restrict__ ec,
        const unsigned short* __restrict__ genex,   // xg0b, stride D
        unsigned short* __restrict__ cell_out) {    // Acat_c0, stride KCAT
    __shared__ float red[4][D];
    if (blockIdx.x < NC) {
        // ----- agg_cell L0 body (verbatim round-12/13 form) -----
        const int2* ecp = ec;
        const unsigned short* src = genex; long sstride = D;
        int c = blockIdx.x;
        int wv = threadIdx.x >> 6, ln = threadIdx.x & 63;
        int half = ln >> 5, lh = ln & 31;
        int j0 = __builtin_amdgcn_readfirstlane(rp_c[c]);
        int j1 = __builtin_amdgcn_readfirstlane(rp_c[c + 1]);
        float a0=0.f,a1=0.f,a2=0.f,a3=0.f,a4=0.f,a5=0.f,a6=0.f,a7=0.f;
        int n32 = (j1 - j0) & ~31;     // chunks of 32 = 4 waves x 8 edges
        for (int j = j0 + wv * 8; j < j0 + n32; j += 32) {
            int2 e0 = ecp[j],     e1 = ecp[j + 1], e2 = ecp[j + 2], e3 = ecp[j + 3];
            int2 e4 = ecp[j + 4], e5 = ecp[j + 5], e6 = ecp[j + 6], e7 = ecp[j + 7];
            int   rA = half ? e1.x : e0.x;  float wA = __int_as_float(half ? e1.y : e0.y);
            int   rB = half ? e3.x : e2.x;  float wB = __int_as_float(half ? e3.y : e2.y);
            int   rC = half ? e5.x : e4.x;  float wC = __int_as_float(half ? e5.y : e4.y);
            int   rD = half ? e7.x : e6.x;  float wD = __int_as_float(half ? e7.y : e6.y);
            uint4 pA = *reinterpret_cast<const uint4*>(src + (size_t)rA * sstride + lh * 8);
            uint4 pB = *reinterpret_cast<const uint4*>(src + (size_t)rB * sstride + lh * 8);
            uint4 pC = *reinterpret_cast<const uint4*>(src + (size_t)rC * sstride + lh * 8);
            uint4 pD = *reinterpret_cast<const uint4*>(src + (size_t)rD * sstride + lh * 8);
            a0 += wA * bflo(pA.x) + wB * bflo(pB.x) + wC * bflo(pC.x) + wD * bflo(pD.x);
            a1 += wA * bfhi(pA.x) + wB * bfhi(pB.x) + wC * bfhi(pC.x) + wD * bfhi(pD.x);
            a2 += wA * bflo(pA.y) + wB * bflo(pB.y) + wC * bflo(pC.y) + wD * bflo(pD.y);
            a3 += wA * bfhi(pA.y) + wB * bfhi(pB.y) + wC * bfhi(pC.y) + wD * bfhi(pD.y);
            a4 += wA * bflo(pA.z) + wB * bflo(pB.z) + wC * bflo(pC.z) + wD * bflo(pD.z);
            a5 += wA * bfhi(pA.z) + wB * bfhi(pB.z) + wC * bfhi(pC.z) + wD * bfhi(pD.z);
            a6 += wA * bflo(pA.w) + wB * bflo(pB.w) + wC * bflo(pC.w) + wD * bflo(pD.w);
            a7 += wA * bfhi(pA.w) + wB * bfhi(pB.w) + wC * bfhi(pC.w) + wD * bfhi(pD.w);
        }
        for (int j = j0 + n32 + wv * 2; j < j1; j += 8) {
            int2 e0 = ecp[j];
            int2 e1 = (j + 1 < j1) ? ecp[j + 1] : make_int2(e0.x, 0);
            int   r = half ? e1.x : e0.x;
            float w = __int_as_float(half ? e1.y : e0.y);
            uint4 p = *reinterpret_cast<const uint4*>(src + (size_t)r * sstride + lh * 8);
            a0 += w * bflo(p.x); a1 += w * bfhi(p.x);
            a2 += w * bflo(p.y); a3 += w * bfhi(p.y);
            a4 += w * bflo(p.z); a5 += w * bfhi(p.z);
            a6 += w * bflo(p.w); a7 += w * bfhi(p.w);
        }
        a0 += __shfl_xor(a0, 32, 64); a1 += __shfl_xor(a1, 32, 64);
        a2 += __shfl_xor(a2, 32, 64); a3 += __shfl_xor(a3, 32, 64);
        a4 += __shfl_xor(a4, 32, 64); a5 += __shfl_xor(a5, 32, 64);
        a6 += __shfl_xor(a6, 32, 64); a7 += __shfl_xor(a7, 32, 64);
        if (ln < 32) {
            *reinterpret_cast<float4*>(&red[wv][lh * 8])     = make_float4(a0, a1, a2, a3);
            *reinterpret_cast<float4*>(&red[wv][lh * 8 + 4]) = make_float4(a4, a5, a6, a7);
        }
        __syncthreads();
        int col = threadIdx.x;
        float s = red[0][col] + red[1][col] + red[2][col] + red[3][col];
        cell_out[(size_t)c * KCAT + col] = f2bf(s);
        return;
    }
    // ----- agg_gene body (verbatim round-13 form) -----
    int wave = (blockIdx.x - NC) * 4 + (threadIdx.x >> 6);
    int lane = threadIdx.x & 63;
    if (wave >= NG) return;
    const unsigned short* src = cellx; long sstride = KCAT;
    int j0 = __builtin_amdgcn_readfirstlane(rp_g[wave]);
    int j1 = __builtin_amdgcn_readfirstlane(rp_g[wave + 1]);
    int half = lane >> 5;
    int lh = lane & 31;
    float a0=0.f,a1=0.f,a2=0.f,a3=0.f,a4=0.f,a5=0.f,a6=0.f,a7=0.f;
    int j = j0;
    for (; j + 4 <= j1; j += 4) {
        int2 e0 = eg[j], e1 = eg[j + 1], e2 = eg[j + 2], e3 = eg[j + 3];
        int   rA = half ? e1.x : e0.x;
        float wA = __int_as_float(half ? e1.y : e0.y);
        int   rB = half ? e3.x : e2.x;
        float wB = __int_as_float(half ? e3.y : e2.y);
        uint4 pA = *reinterpret_cast<const uint4*>(src + (size_t)rA * sstride + lh * 8);
        uint4 pB = *reinterpret_cast<const uint4*>(src + (size_t)rB * sstride + lh * 8);
        a0 += wA * bflo(pA.x) + wB * bflo(pB.x);
        a1 += wA * bfhi(pA.x) + wB * bfhi(pB.x);
        a2 += wA * bflo(pA.y) + wB * bflo(pB.y);
        a3 += wA * bfhi(pA.y) + wB * bfhi(pB.y);
        a4 += wA * bflo(pA.z) + wB * bflo(pB.z);
        a5 += wA * bfhi(pA.z) + wB * bfhi(pB.z);
        a6 += wA * bflo(pA.w) + wB * bflo(pB.w);
        a7 += wA * bfhi(pA.w) + wB * bfhi(pB.w);
    }
    for (; j < j1; j += 2) {
        int2 e0 = eg[j];
        int2 e1 = (j + 1 < j1) ? eg[j + 1] : make_int2(e0.x, 0);  // w=0 pad
        int   r = half ? e1.x : e0.x;
        float w = __int_as_float(half ? e1.y : e0.y);
        uint4 p = *reinterpret_cast<const uint4*>(src + (size_t)r * sstride + lh * 8);
        a0 += w * bflo(p.x); a1 += w * bfhi(p.x);
        a2 += w * bflo(p.y); a3 += w * bfhi(p.y);
        a4 += w * bflo(p.z); a5 += w * bfhi(p.z);
        a6 += w * bflo(p.w); a7 += w * bfhi(p.w);
    }
    a0 += __shfl_xor(a0, 32, 64); a1 += __shfl_xor(a1, 32, 64);
    a2 += __shfl_xor(a2, 32, 64); a3 += __shfl_xor(a3, 32, 64);
    a4 += __shfl_xor(a4, 32, 64); a5 += __shfl_xor(a5, 32, 64);
    a6 += __shfl_xor(a6, 32, 64); a7 += __shfl_xor(a7, 32, 64);
    if (lane < 32) {
        uint4 o;
        o.x = (unsigned)f2bf(a0) | ((unsigned)f2bf(a1) << 16);
        o.y = (unsigned)f2bf(a2) | ((unsigned)f2bf(a3) << 16);
        o.z = (unsigned)f2bf(a4) | ((unsigned)f2bf(a5) << 16);
        o.w = (unsigned)f2bf(a6) | ((unsigned)f2bf(a7) << 16);
        *reinterpret_cast<uint4*>(agg_g + (size_t)wave * D + lane * 8) = o;
    }
}

// ---------------- gene GEMM: xg1 = relu(agg@W1^T + x@Wc^T + w*(x@W2^T) + b) -
// Round-7 form (best measured): dual accumulator derives the w_gg term in
// registers; A + W async16-staged through 48 KB LDS.
__global__ __launch_bounds__(256, 2) void gene_gemm(
        const unsigned short* __restrict__ Agg,  // [NG][256] bf16
        const unsigned short* __restrict__ Xb,   // [NG][256] bf16
        const float* __restrict__ w_gg,          // [NG]
        const unsigned short* __restrict__ W,    // [256][768]: rel1|rootc|rel2
        const float* __restrict__ bias,          // [256]
        unsigned short* __restrict__ xg1) {      // out [NG][256]
    __shared__ unsigned short As[128 * 64];      // 16 KB
    __shared__ unsigned short Bs1[128 * 64];     // 16 KB
    __shared__ unsigned short Bs2[128 * 64];     // 16 KB
    int tid = threadIdx.x;
    int wv = tid >> 6, ln = tid & 63;
    int lm = ln & 15, lq = ln >> 4;
    int m0 = blockIdx.x * 128;
    int nb = blockIdx.y * 128;
    int m0w = m0 + (wv >> 1) * 64;
    int n0w = nb + (wv & 1) * 64;

    f32x4 accA[4][4], accV[4][4];
#pragma unroll
    for (int i = 0; i < 4; ++i)
#pragma unroll
        for (int j = 0; j < 4; ++j) { accA[i][j] = f32x4{0,0,0,0}; accV[i][j] = f32x4{0,0,0,0}; }

    // ---- segment A: agg @ Wrel1^T ----
    for (int k0 = 0; k0 < 256; k0 += 64) {
#pragma unroll
        for (int t = 0; t < 4; ++t) {
            int ci = t * 256 + tid;
            int r = ci >> 3, s = ci & 7;
            int cg = s ^ (r & 7);
            int row = m0 + r; if (row >= NG) row = NG - 1;
            async16(Agg + (size_t)row * D + k0 + cg * 8, (unsigned char*)As + ci * 16);
            async16(W + (size_t)(nb + r) * KCAT + k0 + cg * 8, (unsigned char*)Bs1 + ci * 16);
        }
        __syncthreads();
#pragma unroll
        for (int kk = 0; kk < 2; ++kk) {
            bf16x8 a[4], b[4];
#pragma unroll
            for (int i = 0; i < 4; ++i) {
                int r = (wv >> 1) * 64 + i * 16 + lm;
                int s = (kk * 4 + lq) ^ (r & 7);
                a[i] = *reinterpret_cast<const bf16x8*>(As + (r * 8 + s) * 8);
            }
#pragma unroll
            for (int j = 0; j < 4; ++j) {
                int r = (wv & 1) * 64 + j * 16 + lm;
                int s = (kk * 4 + lq) ^ (r & 7);
                b[j] = *reinterpret_cast<const bf16x8*>(Bs1 + (r * 8 + s) * 8);
            }
#pragma unroll
            for (int i = 0; i < 4; ++i)
#pragma unroll
                for (int j = 0; j < 4; ++j)
                    accA[i][j] = __builtin_amdgcn_mfma_f32_16x16x32_bf16(a[i], b[j], accA[i][j], 0, 0, 0);
        }
        __syncthreads();
    }

    // ---- segment X: x @ (Wroot1+Wroot2)^T into accA, x @ Wrel2^T into accV -
    for (int k0 = 0; k0 < 256; k0 += 64) {
#pragma unroll
        for (int t = 0; t < 4; ++t) {
            int ci = t * 256 + tid;
            int r = ci >> 3, s = ci & 7;
            int cg = s ^ (r & 7);
            int row = m0 + r; if (row >= NG) row = NG - 1;
            async16(Xb + (size_t)row * D + k0 + cg * 8, (unsigned char*)As + ci * 16);
            async16(W + (size_t)(nb + r) * KCAT + 256 + k0 + cg * 8, (unsigned char*)Bs1 + ci * 16);
            async16(W + (size_t)(nb + r) * KCAT + 512 + k0 + cg * 8, (unsigned char*)Bs2 + ci * 16);
        }
        __syncthreads();
#pragma unroll
        for (int kk = 0; kk < 2; ++kk) {
            bf16x8 a[4], b1[4], b2[4];
#pragma unroll
            for (int i = 0; i < 4; ++i) {
                int r = (wv >> 1) * 64 + i * 16 + lm;
                int s = (kk * 4 + lq) ^ (r & 7);
                a[i] = *reinterpret_cast<const bf16x8*>(As + (r * 8 + s) * 8);
            }
#pragma unroll
            for (int j = 0; j < 4; ++j) {
                int r = (wv & 1) * 64 + j * 16 + lm;
                int s = (kk * 4 + lq) ^ (r & 7);
                b1[j] = *reinterpret_cast<const bf16x8*>(Bs1 + (r * 8 + s) * 8);
                b2[j] = *reinterpret_cast<const bf16x8*>(Bs2 + (r * 8 + s) * 8);
            }
#pragma unroll
            for (int i = 0; i < 4; ++i)
#pragma unroll
                for (int j = 0; j < 4; ++j) {
                    accA[i][j] = __builtin_amdgcn_mfma_f32_16x16x32_bf16(a[i], b1[j], accA[i][j], 0, 0, 0);
                    accV[i][j] = __builtin_amdgcn_mfma_f32_16x16x32_bf16(a[i], b2[j], accV[i][j], 0, 0, 0);
                }
        }
        __syncthreads();
    }

    // ---- epilogue ----
#pragma unroll
    for (int i = 0; i < 4; ++i) {
#pragma unroll
        for (int r4 = 0; r4 < 4; ++r4) {
            int row = m0w + i * 16 + lq * 4 + r4;
            if (row >= NG) continue;
            float wr = w_gg[row];
#pragma unroll
            for (int j = 0; j < 4; ++j) {
                int col = n0w + j * 16 + lm;
                float v = accA[i][j][r4] + wr * accV[i][j][r4] + bias[col];
                v = v > 0.f ? v : 0.f;
                xg1[(size_t)row * D + col] = f2bf(v);
            }
        }
    }
}

// ---------------- cell aggregation (L1): one block per cell, LDS reduce -----
__global__ __launch_bounds__(256) void agg_cell(const int* __restrict__ rp,
                                                const int2* __restrict__ ec,
                                                const unsigned short* __restrict__ src, long sstride,
                                                unsigned short* __restrict__ out, long ostride) {
    __shared__ float red[4][D];
    int c = blockIdx.x;
    int wv = threadIdx.x >> 6, ln = threadIdx.x & 63;
    int half = ln >> 5, lh = ln & 31;
    int j0 = __builtin_amdgcn_readfirstlane(rp[c]);
    int j1 = __builtin_amdgcn_readfirstlane(rp[c + 1]);
    float a0=0.f,a1=0.f,a2=0.f,a3=0.f,a4=0.f,a5=0.f,a6=0.f,a7=0.f;
    int n32 = (j1 - j0) & ~31;         // chunks of 32 = 4 waves x 8 edges
    for (int j = j0 + wv * 8; j < j0 + n32; j += 32) {
        int2 e0 = ec[j],     e1 = ec[j + 1], e2 = ec[j + 2], e3 = ec[j + 3];
        int2 e4 = ec[j + 4], e5 = ec[j + 5], e6 = ec[j + 6], e7 = ec[j + 7];
        int   rA = half ? e1.x : e0.x;  float wA = __int_as_float(half ? e1.y : e0.y);
        int   rB = half ? e3.x : e2.x;  float wB = __int_as_float(half ? e3.y : e2.y);
        int   rC = half ? e5.x : e4.x;  float wC = __int_as_float(half ? e5.y : e4.y);
        int   rD = half ? e7.x : e6.x;  float wD = __int_as_float(half ? e7.y : e6.y);
        uint4 pA = *reinterpret_cast<const uint4*>(src + (size_t)rA * sstride + lh * 8);
        uint4 pB = *reinterpret_cast<const uint4*>(src + (size_t)rB * sstride + lh * 8);
        uint4 pC = *reinterpret_cast<const uint4*>(src + (size_t)rC * sstride + lh * 8);
        uint4 pD = *reinterpret_cast<const uint4*>(src + (size_t)rD * sstride + lh * 8);
        a0 += wA * bflo(pA.x) + wB * bflo(pB.x) + wC * bflo(pC.x) + wD * bflo(pD.x);
        a1 += wA * bfhi(pA.x) + wB * bfhi(pB.x) + wC * bfhi(pC.x) + wD * bfhi(pD.x);
        a2 += wA * bflo(pA.y) + wB * bflo(pB.y) + wC * bflo(pC.y) + wD * bflo(pD.y);
        a3 += wA * bfhi(pA.y) + wB * bfhi(pB.y) + wC * bfhi(pC.y) + wD * bfhi(pD.y);
        a4 += wA * bflo(pA.z) + wB * bflo(pB.z) + wC * bflo(pC.z) + wD * bflo(pD.z);
        a5 += wA * bfhi(pA.z) + wB * bfhi(pB.z) + wC * bfhi(pC.z) + wD * bfhi(pD.z);
        a6 += wA * bflo(pA.w) + wB * bflo(pB.w) + wC * bflo(pC.w) + wD * bflo(pD.w);
        a7 += wA * bfhi(pA.w) + wB * bfhi(pB.w) + wC * bfhi(pC.w) + wD * bfhi(pD.w);
    }
    // tail: <=31 edges, pairs round-robin across waves, w=0 padding
    for (int j = j0 + n32 + wv * 2; j < j1; j += 8) {
        int2 e0 = ec[j];
        int2 e1 = (j + 1 < j1) ? ec[j + 1] : make_int2(e0.x, 0);
        int   r = half ? e1.x : e0.x;
        float w = __int_as_float(half ? e1.y : e0.y);
        uint4 p = *reinterpret_cast<const uint4*>(src + (size_t)r * sstride + lh * 8);
        a0 += w * bflo(p.x); a1 += w * bfhi(p.x);
        a2 += w * bflo(p.y); a3 += w * bfhi(p.y);
        a4 += w * bflo(p.z); a5 += w * bfhi(p.z);
        a6 += w * bflo(p.w); a7 += w * bfhi(p.w);
    }
    // combine half-wave partials, then cross-wave LDS reduce
    a0 += __shfl_xor(a0, 32, 64); a1 += __shfl_xor(a1, 32, 64);
    a2 += __shfl_xor(a2, 32, 64); a3 += __shfl_xor(a3, 32, 64);
    a4 += __shfl_xor(a4, 32, 64); a5 += __shfl_xor(a5, 32, 64);
    a6 += __shfl_xor(a6, 32, 64); a7 += __shfl_xor(a7, 32, 64);
    if (ln < 32) {
        *reinterpret_cast<float4*>(&red[wv][lh * 8])     = make_float4(a0, a1, a2, a3);
        *reinterpret_cast<float4*>(&red[wv][lh * 8 + 4]) = make_float4(a4, a5, a6, a7);
    }
    __syncthreads();
    int col = threadIdx.x;
    float s = red[0][col] + red[1][col] + red[2][col] + red[3][col];
    out[(size_t)c * ostride + col] = f2bf(s);
}

// ---------------- m97-style GEMM (cells): relu(A[M,768] @ W^T + bias) -------
__global__ __launch_bounds__(256, 2) void gemm_tile(
        const unsigned short* __restrict__ A,    // [M][768]
        const unsigned short* __restrict__ W,    // [256][768]
        const float* __restrict__ bias,          // [256]
        const float* __restrict__ wrow,          // nullable per-row scale for vout
        unsigned short* __restrict__ xout, long xstride,
        unsigned short* __restrict__ vout,       // nullable, same stride
        int M) {
    __shared__ unsigned short As[128 * 64];
    __shared__ unsigned short Bs[128 * 64];
    int tid = threadIdx.x;
    int wv = tid >> 6, ln = tid & 63;
    int lm = ln & 15, lq = ln >> 4;
    int m0 = blockIdx.x * 128;
    int nb = blockIdx.y * 128;
    int m0w = m0 + (wv >> 1) * 64;
    int n0w = nb + (wv & 1) * 64;

    f32x4 acc[4][4];
#pragma unroll
    for (int i = 0; i < 4; ++i)
#pragma unroll
        for (int j = 0; j < 4; ++j) acc[i][j] = f32x4{0.f, 0.f, 0.f, 0.f};

    for (int k0 = 0; k0 < KCAT; k0 += 64) {
#pragma unroll
        for (int t = 0; t < 4; ++t) {
            int ci = t * 256 + tid;
            int r = ci >> 3, s = ci & 7;
            int cg = s ^ (r & 7);
            int row = m0 + r; if (row >= M) row = M - 1;
            async16(A + (size_t)row * KCAT + k0 + cg * 8,
                    (unsigned char*)As + ci * 16);
        }
#pragma unroll
        for (int t = 0; t < 4; ++t) {
            int ci = t * 256 + tid;
            int r = ci >> 3, s = ci & 7;
            int cg = s ^ (r & 7);
            async16(W + (size_t)(nb + r) * KCAT + k0 + cg * 8,
                    (unsigned char*)Bs + ci * 16);
        }
        __syncthreads();
#pragma unroll
        for (int kk = 0; kk < 2; ++kk) {
            bf16x8 a[4], b[4];
#pragma unroll
            for (int i = 0; i < 4; ++i) {
                int r = (wv >> 1) * 64 + i * 16 + lm;
                int c = kk * 4 + lq;
                int s = c ^ (r & 7);
                a[i] = *reinterpret_cast<const bf16x8*>(As + (r * 8 + s) * 8);
            }
#pragma unroll
            for (int j = 0; j < 4; ++j) {
                int r = (wv & 1) * 64 + j * 16 + lm;
                int c = kk * 4 + lq;
                int s = c ^ (r & 7);
                b[j] = *reinterpret_cast<const bf16x8*>(Bs + (r * 8 + s) * 8);
            }
#pragma unroll
            for (int i = 0; i < 4; ++i)
#pragma unroll
                for (int j = 0; j < 4; ++j)
                    acc[i][j] = __builtin_amdgcn_mfma_f32_16x16x32_bf16(a[i], b[j], acc[i][j], 0, 0, 0);
        }
        __syncthreads();
    }

#pragma unroll
    for (int i = 0; i < 4; ++i) {
#pragma unroll
        for (int r4 = 0; r4 < 4; ++r4) {
            int rr = m0w + i * 16 + lq * 4 + r4;
            if (rr >= M) continue;
            float wr = wrow ? wrow[rr] : 0.f;
#pragma unroll
            for (int j = 0; j < 4; ++j) {
                int col = n0w + j * 16 + lm;
                float v = acc[i][j][r4] + bias[col];
                v = v > 0.f ? v : 0.f;
                xout[(size_t)rr * xstride + col] = f2bf(v);
                if (vout) vout[(size_t)rr * xstride + col] = f2bf(v * wr);
            }
        }
    }
}

// ---------------- final projection: out = xc2 @ Wout^T + bout (fp32) --------
// Wout staged in LDS (f32, +1 pad -> conflict-free) in two 32-row passes;
// Block = 8 cells x 32 outs per pass.
__global__ __launch_bounds__(256) void out_kernel(const unsigned short* __restrict__ xc,
                                                  const float* __restrict__ Wout,
                                                  const float* __restrict__ bout,
                                                  float* __restrict__ out) {
    __shared__ float srow[8][D];            // 8 KB
    __shared__ float wlds[32][D + 1];       // 32.1 KB
    int tid = threadIdx.x;
    // stage 8 cell rows (bf16 -> f32)
    for (int t = tid; t < 8 * D; t += 256) {
        int rr = blockIdx.x * 8 + (t >> 8);
        unsigned short h = xc[(size_t)rr * D + (t & 255)];
        srow[t >> 8][t & 255] = __uint_as_float(((unsigned)h) << 16);
    }
    int r = tid >> 5, ol = tid & 31;
    float res[2];
#pragma unroll
    for (int p = 0; p < 2; ++p) {
        __syncthreads();
        // stage 32 Wout rows (coalesced float4 global, scalar LDS writes)
        for (int t = tid; t < 32 * (D / 4); t += 256) {
            int o = t >> 6, k4 = (t & 63) * 4;
            float4 wv = *reinterpret_cast<const float4*>(Wout + (size_t)(p * 32 + o) * D + k4);
            wlds[o][k4 + 0] = wv.x; wlds[o][k4 + 1] = wv.y;
            wlds[o][k4 + 2] = wv.z; wlds[o][k4 + 3] = wv.w;
        }
        __syncthreads();
        float s = 0.f;
        for (int k = 0; k < D; ++k) s += srow[r][k] * wlds[ol][k];
        res[p] = s;
    }
    int c = blockIdx.x * 8 + r;
    out[(size_t)c * NOUTD + ol] = res[0] + bout[ol];
    out[(size_t)c * NOUTD + 32 + ol] = res[1] + bout[32 + ol];
}

// ---------------- orchestration ---------------------------------------------
extern "C" void kernel_launch(void* const* d_in, const int* in_sizes, int n_in,
                              void* d_out, int out_size, void* d_ws, size_t ws_size,
                              hipStream_t stream) {
    const float* x_gene = (const float*)d_in[0];
    const float* x_cell = (const float*)d_in[1];
    const int*   src_g2c = (const int*)d_in[2];
    const int*   dst_g2c = (const int*)d_in[3];
    const int*   src_c2g = (const int*)d_in[4];
    const int*   dst_c2g = (const int*)d_in[5];
    const float* w_g2c = (const float*)d_in[8];
    const float* w_c2g = (const float*)d_in[9];
    const float* w_gg  = (const float*)d_in[10];
    const float* w_cc  = (const float*)d_in[11];
    const float* Wrel  = (const float*)d_in[12];
    const float* brel  = (const float*)d_in[13];
    const float* Wroot = (const float*)d_in[14];
    const float* Wout  = (const float*)d_in[15];
    const float* bout  = (const float*)d_in[16];
    float* out = (float*)d_out;

    char* p = (char*)d_ws;
    auto alloc = [&](size_t bytes) -> char* {
        char* r = p;
        p += (bytes + 255) & ~(size_t)255;
        return r;
    };

    unsigned short* xg0b    = (unsigned short*)alloc((size_t)NG * D * 2);
    unsigned short* xg1     = (unsigned short*)alloc((size_t)NG * D * 2);
    unsigned short* agg_g   = (unsigned short*)alloc((size_t)NG * D * 2);
    unsigned short* Acat_c0 = (unsigned short*)alloc((size_t)NC * KCAT * 2);
    unsigned short* Acat_c1 = (unsigned short*)alloc((size_t)NC * KCAT * 2);
    unsigned short* xc2     = (unsigned short*)alloc((size_t)NC * D * 2);
    int* rp_g  = (int*)alloc((NG + 1) * 4);
    int* rp_c  = (int*)alloc((NC + 1) * 4);
    int2* ec = (int2*)alloc((size_t)NE * 8);       // g2c edges grouped by cell
    int2* eg = (int2*)alloc((size_t)NE * 8);       // c2g edges grouped by gene
    int2* st_c = (int2*)alloc((size_t)NE * 8);     // coarse-bucketed staging
    int2* st_g = (int2*)alloc((size_t)NE * 8);
    int* hist512 = (int*)alloc(512 * 4);
    int* cbase   = (int*)alloc(514 * 4);
    int* ccur_c  = (int*)alloc(256 * 4);
    int* ccur_g  = (int*)alloc(256 * 4);
    unsigned short* Wg0 = (unsigned short*)alloc((size_t)D * KCAT * 2);
    unsigned short* Wc0 = (unsigned short*)alloc((size_t)D * KCAT * 2);
    unsigned short* Wc1 = (unsigned short*)alloc((size_t)D * KCAT * 2);
    float* bg0 = (float*)alloc(D * 4);
    float* bc0 = (float*)alloc(D * 4);
    float* bc1 = (float*)alloc(D * 4);

    hipMemsetAsync(hist512, 0, 512 * 4, stream);

    // cell prep (x + v into Acat_c0 cols)
    prep_x<<<(NC * 64 + 255) / 256, 256, 0, stream>>>(x_cell, w_cc, Acat_c0 + 256, Acat_c0 + 512, KCAT, NC);

    // all 3 weight matrices in one launch
    build_wcat3<<<dim3((D * D + 255) / 256, 3), 256, 0, stream>>>(
        Wrel, Wroot, brel, Wg0, Wc0, Wc1, bg0, bc0, bc1);

    // ---- CSR build (+ fused x_gene conversion) ----
    coarse_count_conv<<<CCB + CONVB, 256, 0, stream>>>(dst_g2c, dst_c2g, hist512, x_gene, xg0b);
    coarse_scan<<<1, 256, 0, stream>>>(hist512, cbase, ccur_c, ccur_g, rp_c, rp_g);
    const int P1B = (NE + P1_CHUNK - 1) / P1_CHUNK;
    bucket_pass1<<<dim3(P1B, 2), 256, 0, stream>>>(
        src_g2c, dst_g2c, w_g2c, ccur_c, st_c,
        src_c2g, dst_c2g, w_c2g, ccur_g, st_g);
    bucket_pass2<<<P2_CBLK + P2_GBLK, 256, 0, stream>>>(
        st_c, ec, rp_c, st_g, eg, rp_g, cbase);
    // cheap per-cell gene-grouping (replaces the deleted bitonic sort)
    group_cell_edges<<<NC, 256, 0, stream>>>(rp_c, ec);

    // ---- FUSED: agg_cell L0 (blocks 0..NC) ∥ agg_gene (rest) ----
    agg_fused<<<NC + (NG + 3) / 4, 256, 0, stream>>>(
        rp_g, eg, Acat_c0 + 256, agg_g,
        rp_c, ec, xg0b, Acat_c0);

    // ---- gene GEMM ----
    gene_gemm<<<dim3((NG + 127) / 128, 2), 256, 0, stream>>>(
        agg_g, xg0b, w_gg, Wg0, bg0, xg1);

    // ---- Layer 0 cell GEMM ----
    gemm_tile<<<dim3((NC + 127) / 128, 2), 256, 0, stream>>>(
        Acat_c0, Wc0, bc0, w_cc, Acat_c1 + 256, KCAT, Acat_c1 + 512, NC);

    // ---- Layer 1 cells ----
    agg_cell<<<NC, 256, 0, stream>>>(rp_c, ec, xg1, D, Acat_c1, KCAT);
    gemm_tile<<<dim3((NC + 127) / 128, 2), 256, 0, stream>>>(
        Acat_c1, Wc1, bc1, nullptr, xc2, D, nullptr, NC);

    // ---- output projection ----
    out_kernel<<<NC / 8, 256, 0, stream>>>(xc2, Wout, bout, out);
}

// Round 15
// 545.119 us; speedup vs baseline: 1.0748x; 1.0091x over previous
//
#include <hip/hip_runtime.h>

// Problem constants
static constexpr int NG   = 100000;
static constexpr int NC   = 2000;
static constexpr int D    = 256;
static constexpr int NE   = 1000000;
static constexpr int NOUTD= 64;
static constexpr int KCAT = 768;          // concatenated K: [agg | x | v]

typedef __bf16 bf16x8 __attribute__((ext_vector_type(8)));
typedef float  f32x4  __attribute__((ext_vector_type(4)));

__device__ __forceinline__ unsigned short f2bf(float f) {
    unsigned u = __float_as_uint(f);
    u += 0x7fffu + ((u >> 16) & 1u);   // RNE
    return (unsigned short)(u >> 16);
}
__device__ __forceinline__ float bflo(unsigned x) { return __uint_as_float((x & 0xffffu) << 16); }
__device__ __forceinline__ float bfhi(unsigned x) { return __uint_as_float(x & 0xffff0000u); }

__device__ __forceinline__ void async16(const void* g, void* l) {
    __builtin_amdgcn_global_load_lds(
        (const __attribute__((address_space(1))) void*)g,
        (__attribute__((address_space(3))) void*)l, 16, 0, 0);
}

// ---- FUSED front end: coarse hist | x_gene conv | cell prep | weight build -
// All four phases are data-independent; one grid removes 2 launches + bubbles.
// blocks [0,CCB):               edge histograms (cell + gene coarse bins)
// blocks [CCB, CCB+CONVB):      x_gene f32->bf16 into xg0b
// blocks [.., +PREPB):          x_cell -> bf16 x and v=x*w_cc into Acat_c0
// blocks [.., +WB3):            3 concatenated bf16 weight mats + bias sums
static constexpr int CC_CHUNK = 8192;
static constexpr int CCB   = (NE + CC_CHUNK - 1) / CC_CHUNK;   // 123
static constexpr int CONVB = NG * (D / 4) / 256;               // 25000
static constexpr int PREPB = NC * (D / 4) / 256;               // 500
static constexpr int WB3   = 3 * (D * D / 256);                // 768
__global__ __launch_bounds__(256) void front_fused(
        const int* __restrict__ dst_g2c, const int* __restrict__ dst_c2g,
        int* __restrict__ hist512,
        const float* __restrict__ x_gene, unsigned short* __restrict__ xg0b,
        const float* __restrict__ x_cell, const float* __restrict__ w_cc,
        unsigned short* __restrict__ cdx, unsigned short* __restrict__ cdv,  // stride KCAT
        const float* __restrict__ Wrel, const float* __restrict__ Wroot,
        const float* __restrict__ brel,
        unsigned short* __restrict__ Wg0, unsigned short* __restrict__ Wc0,
        unsigned short* __restrict__ Wc1,
        float* __restrict__ bg0, float* __restrict__ bc0, float* __restrict__ bc1) {
    __shared__ int h[512];
    unsigned bx = blockIdx.x;
    if (bx >= (unsigned)(CCB + CONVB + PREPB)) {           // weight build
        int blk = bx - (CCB + CONVB + PREPB);
        int y = blk >> 8;                                  // 0..2
        int i = (blk & 255) * 256 + threadIdx.x;           // 0..65535
        const int WW = D * D;
        int ia, ib; unsigned short* wout; float* bsum;
        if (y == 0)      { ia = 1; ib = 2; wout = Wg0; bsum = bg0; }
        else if (y == 1) { ia = 0; ib = 3; wout = Wc0; bsum = bc0; }
        else             { ia = 4; ib = 7; wout = Wc1; bsum = bc1; }
        int n = i >> 8, k = i & 255;
        wout[(size_t)n * KCAT + k]        = f2bf(Wrel[ia * WW + i]);
        wout[(size_t)n * KCAT + 256 + k]  = f2bf(Wroot[ia * WW + i] + Wroot[ib * WW + i]);
        wout[(size_t)n * KCAT + 512 + k]  = f2bf(Wrel[ib * WW + i]);
        if (i < D) bsum[i] = brel[ia * D + i] + brel[ib * D + i];
        return;
    }
    if (bx >= (unsigned)(CCB + CONVB)) {                   // cell prep
        int i = (bx - (CCB + CONVB)) * 256 + threadIdx.x;  // quarter-row id
        int row = i >> 6, c4 = (i & 63) * 4;
        float4 xv = *reinterpret_cast<const float4*>(x_cell + (size_t)row * D + c4);
        float wv = w_cc[row];
        uint2 ox, ov;
        ox.x = (unsigned)f2bf(xv.x) | ((unsigned)f2bf(xv.y) << 16);
        ox.y = (unsigned)f2bf(xv.z) | ((unsigned)f2bf(xv.w) << 16);
        ov.x = (unsigned)f2bf(xv.x * wv) | ((unsigned)f2bf(xv.y * wv) << 16);
        ov.y = (unsigned)f2bf(xv.z * wv) | ((unsigned)f2bf(xv.w * wv) << 16);
        *reinterpret_cast<uint2*>(cdx + (size_t)row * KCAT + c4) = ox;
        *reinterpret_cast<uint2*>(cdv + (size_t)row * KCAT + c4) = ov;
        return;
    }
    if (bx >= (unsigned)CCB) {                             // x_gene conversion
        int i = (bx - CCB) * 256 + threadIdx.x;            // quarter-row id
        int row = i >> 6, c4 = (i & 63) * 4;
        float4 xv = *reinterpret_cast<const float4*>(x_gene + (size_t)row * D + c4);
        uint2 xo;
        xo.x = (unsigned)f2bf(xv.x) | ((unsigned)f2bf(xv.y) << 16);
        xo.y = (unsigned)f2bf(xv.z) | ((unsigned)f2bf(xv.w) << 16);
        *reinterpret_cast<uint2*>(xg0b + (size_t)row * D + c4) = xo;
        return;
    }
    // edge histograms
    h[threadIdx.x] = 0; h[256 + threadIdx.x] = 0;
    __syncthreads();
    int base = bx * CC_CHUNK;
#pragma unroll 4
    for (int t = 0; t < CC_CHUNK / 256; ++t) {
        int e = base + t * 256 + threadIdx.x;
        if (e < NE) {
            atomicAdd(&h[dst_g2c[e] >> 3], 1);          // cell bins
            atomicAdd(&h[256 + (dst_c2g[e] >> 9)], 1);  // gene bins
        }
    }
    __syncthreads();
    if (h[threadIdx.x]) atomicAdd(&hist512[threadIdx.x], h[threadIdx.x]);
    if (h[256 + threadIdx.x]) atomicAdd(&hist512[256 + threadIdx.x], h[256 + threadIdx.x]);
}

// ---- coarse scan: cbase[0..256]=cells, cbase[257..513]=genes; init cursors -
__global__ __launch_bounds__(256) void coarse_scan(const int* __restrict__ hist,
                                                   int* __restrict__ cbase,
                                                   int* __restrict__ ccur_c, int* __restrict__ ccur_g,
                                                   int* __restrict__ rp_c, int* __restrict__ rp_g) {
    __shared__ int sd[256];
    int t = threadIdx.x;
    {
        int v = hist[t];
        sd[t] = v; __syncthreads();
        for (int off = 1; off < 256; off <<= 1) {
            int u = (t >= off) ? sd[t - off] : 0; __syncthreads();
            sd[t] += u; __syncthreads();
        }
        int e = sd[t] - v;
        cbase[t] = e; ccur_c[t] = e;
        if (t == 255) cbase[256] = sd[255];
        __syncthreads();
    }
    {
        int v = hist[256 + t];
        sd[t] = v; __syncthreads();
        for (int off = 1; off < 256; off <<= 1) {
            int u = (t >= off) ? sd[t - off] : 0; __syncthreads();
            sd[t] += u; __syncthreads();
        }
        int e = sd[t] - v;
        cbase[257 + t] = e; ccur_g[t] = e;
        if (t == 255) cbase[513] = sd[255];
    }
    if (t == 0) { rp_c[NC] = NE; rp_g[NG] = NE; }
}

// pass1 (fused c/g via blockIdx.y): scatter edges into 256 coarse buckets
static constexpr int P1_CHUNK = 8192;
__global__ __launch_bounds__(256) void bucket_pass1(
        const int* __restrict__ srcA, const int* __restrict__ dstA, const float* __restrict__ wA,
        int* __restrict__ curA, int2* __restrict__ outA,
        const int* __restrict__ srcB, const int* __restrict__ dstB, const float* __restrict__ wB,
        int* __restrict__ curB, int2* __restrict__ outB) {
    __shared__ int hist[256], lcur[256], gbase[256];
    const int* src; const int* dst; const float* w; int* coarse_cur; int2* out;
    int shift, packshift;
    if (blockIdx.y == 0) { src = srcA; dst = dstA; w = wA; coarse_cur = curA; out = outA; shift = 3; packshift = 17; }
    else { src = srcB; dst = dstB; w = wB; coarse_cur = curB; out = outB; shift = 9; packshift = 11; }
    int tid = threadIdx.x;
    hist[tid] = 0;
    __syncthreads();
    int base = blockIdx.x * P1_CHUNK;
    int mybin[P1_CHUNK / 256];
#pragma unroll
    for (int t = 0; t < P1_CHUNK / 256; ++t) {
        int e = base + t * 256 + tid;
        if (e < NE) {
            int b = dst[e] >> shift;
            mybin[t] = b;
            atomicAdd(&hist[b], 1);
        } else mybin[t] = -1;
    }
    __syncthreads();
    int v = hist[tid];
    gbase[tid] = v ? atomicAdd(&coarse_cur[tid], v) : 0;
    lcur[tid] = 0;
    __syncthreads();
#pragma unroll
    for (int t = 0; t < P1_CHUNK / 256; ++t) {
        int b = mybin[t];
        if (b < 0) continue;
        int e = base + t * 256 + tid;
        int pos = gbase[b] + atomicAdd(&lcur[b], 1);
        int dl = dst[e] & ((1 << shift) - 1);
        out[pos] = make_int2(src[e] | (dl << packshift), __float_as_int(w[e]));
    }
}

// pass2 (fused): per bucket — fine LDS histogram + scan emits rp, then scatter
static constexpr int P2_CBLK = NC / 8;                 // 250
static constexpr int P2_GBLK = (NG + 511) / 512;       // 196
__global__ __launch_bounds__(256) void bucket_pass2(
        const int2* __restrict__ stC, int2* __restrict__ outC, int* __restrict__ rpC,
        const int2* __restrict__ stG, int2* __restrict__ outG, int* __restrict__ rpG,
        const int* __restrict__ cbase) {
    __shared__ int hist[512], cur[512], sd[256];
    const int2* staged; int2* out; int* rp; const int* cb;
    int shift, packshift, ndst, b;
    if (blockIdx.x < P2_CBLK) {
        staged = stC; out = outC; rp = rpC; cb = cbase;
        shift = 3; packshift = 17; ndst = NC; b = blockIdx.x;
    } else {
        staged = stG; out = outG; rp = rpG; cb = cbase + 257;
        shift = 9; packshift = 11; ndst = NG; b = blockIdx.x - P2_CBLK;
    }
    int tid = threadIdx.x;
    int nf = 1 << shift;
    int d0 = b << shift;
    int j0 = cb[b], j1 = cb[b + 1];
    for (int f = tid; f < nf; f += 256) hist[f] = 0;
    __syncthreads();
    for (int j = j0 + tid; j < j1; j += 256)
        atomicAdd(&hist[((unsigned)staged[j].x) >> packshift], 1);
    __syncthreads();
    // exclusive scan over hist[0..nf)
    int chunk = (nf + 255) >> 8;                 // 1 or 2
    int s = 0;
#pragma unroll 2
    for (int k = 0; k < chunk; ++k) {
        int idx = tid * chunk + k;
        if (idx < nf) s += hist[idx];
    }
    sd[tid] = s; __syncthreads();
    for (int off = 1; off < 256; off <<= 1) {
        int u = (tid >= off) ? sd[tid - off] : 0; __syncthreads();
        sd[tid] += u; __syncthreads();
    }
    int run = sd[tid] - s;                       // exclusive base for this thread's chunk
#pragma unroll 2
    for (int k = 0; k < chunk; ++k) {
        int idx = tid * chunk + k;
        if (idx < nf) {
            int h = hist[idx];
            int pos = j0 + run;
            cur[idx] = pos;
            int d = d0 + idx;
            if (d < ndst) rp[d] = pos;
            run += h;
        }
    }
    __syncthreads();
    // scatter within the bucket's contiguous (cache-local) output region
    for (int j = j0 + tid; j < j1; j += 256) {
        int2 e = staged[j];
        int f = ((unsigned)e.x) >> packshift;
        int pos = atomicAdd(&cur[f], 1);
        out[pos] = make_int2(e.x & ((1 << packshift) - 1), e.y);
    }
}

// ------- per-cell gene-grouping: LDS counting-bucket by gene>>8 -------------
// Round 15: finer windows (391 bins, 256-gene / 128 KB) vs gene>>9 — the
// narrower the synchronized sweep window, the higher the L2/L3 hit rate in
// the aggregation gathers. Chunked 2-per-thread scan over 512 slots.
// Perf-only reordering; n>1024 segments left ungrouped (never happens).
__global__ __launch_bounds__(256) void group_cell_edges(const int* __restrict__ rp,
                                                        int2* __restrict__ ec) {
    __shared__ int2 s[1024];
    __shared__ int hist[512], cur[512], sd[256];
    int c = blockIdx.x;
    int j0 = rp[c], j1 = rp[c + 1];
    int n = j1 - j0;
    if (n <= 1 || n > 1024) return;
    int tid = threadIdx.x;
    for (int i = tid; i < n; i += 256) s[i] = ec[j0 + i];
    hist[tid] = 0; hist[256 + tid] = 0;
    __syncthreads();
    for (int i = tid; i < n; i += 256)
        atomicAdd(&hist[((unsigned)s[i].x) >> 8], 1);    // gene>>8: 0..390
    __syncthreads();
    int a = hist[tid * 2], b = hist[tid * 2 + 1];
    sd[tid] = a + b; __syncthreads();
    for (int off = 1; off < 256; off <<= 1) {
        int u = (tid >= off) ? sd[tid - off] : 0; __syncthreads();
        sd[tid] += u; __syncthreads();
    }
    int base = sd[tid] - (a + b);                        // exclusive base
    cur[tid * 2] = base; cur[tid * 2 + 1] = base + a;
    __syncthreads();
    for (int i = tid; i < n; i += 256) {
        int2 e = s[i];
        int pos = atomicAdd(&cur[((unsigned)e.x) >> 8], 1);
        ec[j0 + pos] = e;
    }
}

// ---- FUSED aggregation: agg_cell L0 (blocks [0,NC)) ∥ agg_gene (rest) ------
// The two phases are data-independent and use complementary resources
// (cell: BW-heavy; gene: latency-bound). Grid fusion overlaps them without
// multi-stream. Long cell blocks dispatch first; gene blocks backfill.
__global__ __launch_bounds__(256) void agg_fused(
        const int* __restrict__ rp_g, const int2* __restrict__ eg,
        const unsigned short* __restrict__ cellx,   // Acat_c0+256, stride KCAT
        unsigned short* __restrict__ agg_g,         // [NG][256]
        const int* __restrict__ rp_c, const int2* __restrict__ ec,
        const unsigned short* __restrict__ genex,   // xg0b, stride D
        unsigned short* __restrict__ cell_out) {    // Acat_c0, stride KCAT
    __shared__ float red[4][D];
    if (blockIdx.x < NC) {
        // ----- agg_cell L0 body -----
        const int2* ecp = ec;
        const unsigned short* src = genex; long sstride = D;
        int c = blockIdx.x;
        int wv = threadIdx.x >> 6, ln = threadIdx.x & 63;
        int half = ln >> 5, lh = ln & 31;
        int j0 = __builtin_amdgcn_readfirstlane(rp_c[c]);
        int j1 = __builtin_amdgcn_readfirstlane(rp_c[c + 1]);
        float a0=0.f,a1=0.f,a2=0.f,a3=0.f,a4=0.f,a5=0.f,a6=0.f,a7=0.f;
        int n32 = (j1 - j0) & ~31;     // chunks of 32 = 4 waves x 8 edges
        for (int j = j0 + wv * 8; j < j0 + n32; j += 32) {
            int2 e0 = ecp[j],     e1 = ecp[j + 1], e2 = ecp[j + 2], e3 = ecp[j + 3];
            int2 e4 = ecp[j + 4], e5 = ecp[j + 5], e6 = ecp[j + 6], e7 = ecp[j + 7];
            int   rA = half ? e1.x : e0.x;  float wA = __int_as_float(half ? e1.y : e0.y);
            int   rB = half ? e3.x : e2.x;  float wB = __int_as_float(half ? e3.y : e2.y);
            int   rC = half ? e5.x : e4.x;  float wC = __int_as_float(half ? e5.y : e4.y);
            int   rD = half ? e7.x : e6.x;  float wD = __int_as_float(half ? e7.y : e6.y);
            uint4 pA = *reinterpret_cast<const uint4*>(src + (size_t)rA * sstride + lh * 8);
            uint4 pB = *reinterpret_cast<const uint4*>(src + (size_t)rB * sstride + lh * 8);
            uint4 pC = *reinterpret_cast<const uint4*>(src + (size_t)rC * sstride + lh * 8);
            uint4 pD = *reinterpret_cast<const uint4*>(src + (size_t)rD * sstride + lh * 8);
            a0 += wA * bflo(pA.x) + wB * bflo(pB.x) + wC * bflo(pC.x) + wD * bflo(pD.x);
            a1 += wA * bfhi(pA.x) + wB * bfhi(pB.x) + wC * bfhi(pC.x) + wD * bfhi(pD.x);
            a2 += wA * bflo(pA.y) + wB * bflo(pB.y) + wC * bflo(pC.y) + wD * bflo(pD.y);
            a3 += wA * bfhi(pA.y) + wB * bfhi(pB.y) + wC * bfhi(pC.y) + wD * bfhi(pD.y);
            a4 += wA * bflo(pA.z) + wB * bflo(pB.z) + wC * bflo(pC.z) + wD * bflo(pD.z);
            a5 += wA * bfhi(pA.z) + wB * bfhi(pB.z) + wC * bfhi(pC.z) + wD * bfhi(pD.z);
            a6 += wA * bflo(pA.w) + wB * bflo(pB.w) + wC * bflo(pC.w) + wD * bflo(pD.w);
            a7 += wA * bfhi(pA.w) + wB * bfhi(pB.w) + wC * bfhi(pC.w) + wD * bfhi(pD.w);
        }
        for (int j = j0 + n32 + wv * 2; j < j1; j += 8) {
            int2 e0 = ecp[j];
            int2 e1 = (j + 1 < j1) ? ecp[j + 1] : make_int2(e0.x, 0);
            int   r = half ? e1.x : e0.x;
            float w = __int_as_float(half ? e1.y : e0.y);
            uint4 p = *reinterpret_cast<const uint4*>(src + (size_t)r * sstride + lh * 8);
            a0 += w * bflo(p.x); a1 += w * bfhi(p.x);
            a2 += w * bflo(p.y); a3 += w * bfhi(p.y);
            a4 += w * bflo(p.z); a5 += w * bfhi(p.z);
            a6 += w * bflo(p.w); a7 += w * bfhi(p.w);
        }
        a0 += __shfl_xor(a0, 32, 64); a1 += __shfl_xor(a1, 32, 64);
        a2 += __shfl_xor(a2, 32, 64); a3 += __shfl_xor(a3, 32, 64);
        a4 += __shfl_xor(a4, 32, 64); a5 += __shfl_xor(a5, 32, 64);
        a6 += __shfl_xor(a6, 32, 64); a7 += __shfl_xor(a7, 32, 64);
        if (ln < 32) {
            *reinterpret_cast<float4*>(&red[wv][lh * 8])     = make_float4(a0, a1, a2, a3);
            *reinterpret_cast<float4*>(&red[wv][lh * 8 + 4]) = make_float4(a4, a5, a6, a7);
        }
        __syncthreads();
        int col = threadIdx.x;
        float s = red[0][col] + red[1][col] + red[2][col] + red[3][col];
        cell_out[(size_t)c * KCAT + col] = f2bf(s);
        return;
    }
    // ----- agg_gene body -----
    int wave = (blockIdx.x - NC) * 4 + (threadIdx.x >> 6);
    int lane = threadIdx.x & 63;
    if (wave >= NG) return;
    const unsigned short* src = cellx; long sstride = KCAT;
    int j0 = __builtin_amdgcn_readfirstlane(rp_g[wave]);
    int j1 = __builtin_amdgcn_readfirstlane(rp_g[wave + 1]);
    int half = lane >> 5;
    int lh = lane & 31;
    float a0=0.f,a1=0.f,a2=0.f,a3=0.f,a4=0.f,a5=0.f,a6=0.f,a7=0.f;
    int j = j0;
    for (; j + 4 <= j1; j += 4) {
        int2 e0 = eg[j], e1 = eg[j + 1], e2 = eg[j + 2], e3 = eg[j + 3];
        int   rA = half ? e1.x : e0.x;
        float wA = __int_as_float(half ? e1.y : e0.y);
        int   rB = half ? e3.x : e2.x;
        float wB = __int_as_float(half ? e3.y : e2.y);
        uint4 pA = *reinterpret_cast<const uint4*>(src + (size_t)rA * sstride + lh * 8);
        uint4 pB = *reinterpret_cast<const uint4*>(src + (size_t)rB * sstride + lh * 8);
        a0 += wA * bflo(pA.x) + wB * bflo(pB.x);
        a1 += wA * bfhi(pA.x) + wB * bfhi(pB.x);
        a2 += wA * bflo(pA.y) + wB * bflo(pB.y);
        a3 += wA * bfhi(pA.y) + wB * bfhi(pB.y);
        a4 += wA * bflo(pA.z) + wB * bflo(pB.z);
        a5 += wA * bfhi(pA.z) + wB * bfhi(pB.z);
        a6 += wA * bflo(pA.w) + wB * bflo(pB.w);
        a7 += wA * bfhi(pA.w) + wB * bfhi(pB.w);
    }
    for (; j < j1; j += 2) {
        int2 e0 = eg[j];
        int2 e1 = (j + 1 < j1) ? eg[j + 1] : make_int2(e0.x, 0);  // w=0 pad
        int   r = half ? e1.x : e0.x;
        float w = __int_as_float(half ? e1.y : e0.y);
        uint4 p = *reinterpret_cast<const uint4*>(src + (size_t)r * sstride + lh * 8);
        a0 += w * bflo(p.x); a1 += w * bfhi(p.x);
        a2 += w * bflo(p.y); a3 += w * bfhi(p.y);
        a4 += w * bflo(p.z); a5 += w * bfhi(p.z);
        a6 += w * bflo(p.w); a7 += w * bfhi(p.w);
    }
    a0 += __shfl_xor(a0, 32, 64); a1 += __shfl_xor(a1, 32, 64);
    a2 += __shfl_xor(a2, 32, 64); a3 += __shfl_xor(a3, 32, 64);
    a4 += __shfl_xor(a4, 32, 64); a5 += __shfl_xor(a5, 32, 64);
    a6 += __shfl_xor(a6, 32, 64); a7 += __shfl_xor(a7, 32, 64);
    if (lane < 32) {
        uint4 o;
        o.x = (unsigned)f2bf(a0) | ((unsigned)f2bf(a1) << 16);
        o.y = (unsigned)f2bf(a2) | ((unsigned)f2bf(a3) << 16);
        o.z = (unsigned)f2bf(a4) | ((unsigned)f2bf(a5) << 16);
        o.w = (unsigned)f2bf(a6) | ((unsigned)f2bf(a7) << 16);
        *reinterpret_cast<uint4*>(agg_g + (size_t)wave * D + lane * 8) = o;
    }
}

// ---------------- gene GEMM: xg1 = relu(agg@W1^T + x@Wc^T + w*(x@W2^T) + b) -
// Round-7 form (best measured): dual accumulator derives the w_gg term in
// registers; A + W async16-staged through 48 KB LDS.
__global__ __launch_bounds__(256, 2) void gene_gemm(
        const unsigned short* __restrict__ Agg,  // [NG][256] bf16
        const unsigned short* __restrict__ Xb,   // [NG][256] bf16
        const float* __restrict__ w_gg,          // [NG]
        const unsigned short* __restrict__ W,    // [256][768]: rel1|rootc|rel2
        const float* __restrict__ bias,          // [256]
        unsigned short* __restrict__ xg1) {      // out [NG][256]
    __shared__ unsigned short As[128 * 64];      // 16 KB
    __shared__ unsigned short Bs1[128 * 64];     // 16 KB
    __shared__ unsigned short Bs2[128 * 64];     // 16 KB
    int tid = threadIdx.x;
    int wv = tid >> 6, ln = tid & 63;
    int lm = ln & 15, lq = ln >> 4;
    int m0 = blockIdx.x * 128;
    int nb = blockIdx.y * 128;
    int m0w = m0 + (wv >> 1) * 64;
    int n0w = nb + (wv & 1) * 64;

    f32x4 accA[4][4], accV[4][4];
#pragma unroll
    for (int i = 0; i < 4; ++i)
#pragma unroll
        for (int j = 0; j < 4; ++j) { accA[i][j] = f32x4{0,0,0,0}; accV[i][j] = f32x4{0,0,0,0}; }

    // ---- segment A: agg @ Wrel1^T ----
    for (int k0 = 0; k0 < 256; k0 += 64) {
#pragma unroll
        for (int t = 0; t < 4; ++t) {
            int ci = t * 256 + tid;
            int r = ci >> 3, s = ci & 7;
            int cg = s ^ (r & 7);
            int row = m0 + r; if (row >= NG) row = NG - 1;
            async16(Agg + (size_t)row * D + k0 + cg * 8, (unsigned char*)As + ci * 16);
            async16(W + (size_t)(nb + r) * KCAT + k0 + cg * 8, (unsigned char*)Bs1 + ci * 16);
        }
        __syncthreads();
#pragma unroll
        for (int kk = 0; kk < 2; ++kk) {
            bf16x8 a[4], b[4];
#pragma unroll
            for (int i = 0; i < 4; ++i) {
                int r = (wv >> 1) * 64 + i * 16 + lm;
                int s = (kk * 4 + lq) ^ (r & 7);
                a[i] = *reinterpret_cast<const bf16x8*>(As + (r * 8 + s) * 8);
            }
#pragma unroll
            for (int j = 0; j < 4; ++j) {
                int r = (wv & 1) * 64 + j * 16 + lm;
                int s = (kk * 4 + lq) ^ (r & 7);
                b[j] = *reinterpret_cast<const bf16x8*>(Bs1 + (r * 8 + s) * 8);
            }
#pragma unroll
            for (int i = 0; i < 4; ++i)
#pragma unroll
                for (int j = 0; j < 4; ++j)
                    accA[i][j] = __builtin_amdgcn_mfma_f32_16x16x32_bf16(a[i], b[j], accA[i][j], 0, 0, 0);
        }
        __syncthreads();
    }

    // ---- segment X: x @ (Wroot1+Wroot2)^T into accA, x @ Wrel2^T into accV -
    for (int k0 = 0; k0 < 256; k0 += 64) {
#pragma unroll
        for (int t = 0; t < 4; ++t) {
            int ci = t * 256 + tid;
            int r = ci >> 3, s = ci & 7;
            int cg = s ^ (r & 7);
            int row = m0 + r; if (row >= NG) row = NG - 1;
            async16(Xb + (size_t)row * D + k0 + cg * 8, (unsigned char*)As + ci * 16);
            async16(W + (size_t)(nb + r) * KCAT + 256 + k0 + cg * 8, (unsigned char*)Bs1 + ci * 16);
            async16(W + (size_t)(nb + r) * KCAT + 512 + k0 + cg * 8, (unsigned char*)Bs2 + ci * 16);
        }
        __syncthreads();
#pragma unroll
        for (int kk = 0; kk < 2; ++kk) {
            bf16x8 a[4], b1[4], b2[4];
#pragma unroll
            for (int i = 0; i < 4; ++i) {
                int r = (wv >> 1) * 64 + i * 16 + lm;
                int s = (kk * 4 + lq) ^ (r & 7);
                a[i] = *reinterpret_cast<const bf16x8*>(As + (r * 8 + s) * 8);
            }
#pragma unroll
            for (int j = 0; j < 4; ++j) {
                int r = (wv & 1) * 64 + j * 16 + lm;
                int s = (kk * 4 + lq) ^ (r & 7);
                b1[j] = *reinterpret_cast<const bf16x8*>(Bs1 + (r * 8 + s) * 8);
                b2[j] = *reinterpret_cast<const bf16x8*>(Bs2 + (r * 8 + s) * 8);
            }
#pragma unroll
            for (int i = 0; i < 4; ++i)
#pragma unroll
                for (int j = 0; j < 4; ++j) {
                    accA[i][j] = __builtin_amdgcn_mfma_f32_16x16x32_bf16(a[i], b1[j], accA[i][j], 0, 0, 0);
                    accV[i][j] = __builtin_amdgcn_mfma_f32_16x16x32_bf16(a[i], b2[j], accV[i][j], 0, 0, 0);
                }
        }
        __syncthreads();
    }

    // ---- epilogue ----
#pragma unroll
    for (int i = 0; i < 4; ++i) {
#pragma unroll
        for (int r4 = 0; r4 < 4; ++r4) {
            int row = m0w + i * 16 + lq * 4 + r4;
            if (row >= NG) continue;
            float wr = w_gg[row];
#pragma unroll
            for (int j = 0; j < 4; ++j) {
                int col = n0w + j * 16 + lm;
                float v = accA[i][j][r4] + wr * accV[i][j][r4] + bias[col];
                v = v > 0.f ? v : 0.f;
                xg1[(size_t)row * D + col] = f2bf(v);
            }
        }
    }
}

// ---------------- cell aggregation (L1): one block per cell, LDS reduce -----
__global__ __launch_bounds__(256) void agg_cell(const int* __restrict__ rp,
                                                const int2* __restrict__ ec,
                                                const unsigned short* __restrict__ src, long sstride,
                                                unsigned short* __restrict__ out, long ostride) {
    __shared__ float red[4][D];
    int c = blockIdx.x;
    int wv = threadIdx.x >> 6, ln = threadIdx.x & 63;
    int half = ln >> 5, lh = ln & 31;
    int j0 = __builtin_amdgcn_readfirstlane(rp[c]);
    int j1 = __builtin_amdgcn_readfirstlane(rp[c + 1]);
    float a0=0.f,a1=0.f,a2=0.f,a3=0.f,a4=0.f,a5=0.f,a6=0.f,a7=0.f;
    int n32 = (j1 - j0) & ~31;         // chunks of 32 = 4 waves x 8 edges
    for (int j = j0 + wv * 8; j < j0 + n32; j += 32) {
        int2 e0 = ec[j],     e1 = ec[j + 1], e2 = ec[j + 2], e3 = ec[j + 3];
        int2 e4 = ec[j + 4], e5 = ec[j + 5], e6 = ec[j + 6], e7 = ec[j + 7];
        int   rA = half ? e1.x : e0.x;  float wA = __int_as_float(half ? e1.y : e0.y);
        int   rB = half ? e3.x : e2.x;  float wB = __int_as_float(half ? e3.y : e2.y);
        int   rC = half ? e5.x : e4.x;  float wC = __int_as_float(half ? e5.y : e4.y);
        int   rD = half ? e7.x : e6.x;  float wD = __int_as_float(half ? e7.y : e6.y);
        uint4 pA = *reinterpret_cast<const uint4*>(src + (size_t)rA * sstride + lh * 8);
        uint4 pB = *reinterpret_cast<const uint4*>(src + (size_t)rB * sstride + lh * 8);
        uint4 pC = *reinterpret_cast<const uint4*>(src + (size_t)rC * sstride + lh * 8);
        uint4 pD = *reinterpret_cast<const uint4*>(src + (size_t)rD * sstride + lh * 8);
        a0 += wA * bflo(pA.x) + wB * bflo(pB.x) + wC * bflo(pC.x) + wD * bflo(pD.x);
        a1 += wA * bfhi(pA.x) + wB * bfhi(pB.x) + wC * bfhi(pC.x) + wD * bfhi(pD.x);
        a2 += wA * bflo(pA.y) + wB * bflo(pB.y) + wC * bflo(pC.y) + wD * bflo(pD.y);
        a3 += wA * bfhi(pA.y) + wB * bfhi(pB.y) + wC * bfhi(pC.y) + wD * bfhi(pD.y);
        a4 += wA * bflo(pA.z) + wB * bflo(pB.z) + wC * bflo(pC.z) + wD * bflo(pD.z);
        a5 += wA * bfhi(pA.z) + wB * bfhi(pB.z) + wC * bfhi(pC.z) + wD * bfhi(pD.z);
        a6 += wA * bflo(pA.w) + wB * bflo(pB.w) + wC * bflo(pC.w) + wD * bflo(pD.w);
        a7 += wA * bfhi(pA.w) + wB * bfhi(pB.w) + wC * bfhi(pC.w) + wD * bfhi(pD.w);
    }
    // tail: <=31 edges, pairs round-robin across waves, w=0 padding
    for (int j = j0 + n32 + wv * 2; j < j1; j += 8) {
        int2 e0 = ec[j];
        int2 e1 = (j + 1 < j1) ? ec[j + 1] : make_int2(e0.x, 0);
        int   r = half ? e1.x : e0.x;
        float w = __int_as_float(half ? e1.y : e0.y);
        uint4 p = *reinterpret_cast<const uint4*>(src + (size_t)r * sstride + lh * 8);
        a0 += w * bflo(p.x); a1 += w * bfhi(p.x);
        a2 += w * bflo(p.y); a3 += w * bfhi(p.y);
        a4 += w * bflo(p.z); a5 += w * bfhi(p.z);
        a6 += w * bflo(p.w); a7 += w * bfhi(p.w);
    }
    // combine half-wave partials, then cross-wave LDS reduce
    a0 += __shfl_xor(a0, 32, 64); a1 += __shfl_xor(a1, 32, 64);
    a2 += __shfl_xor(a2, 32, 64); a3 += __shfl_xor(a3, 32, 64);
    a4 += __shfl_xor(a4, 32, 64); a5 += __shfl_xor(a5, 32, 64);
    a6 += __shfl_xor(a6, 32, 64); a7 += __shfl_xor(a7, 32, 64);
    if (ln < 32) {
        *reinterpret_cast<float4*>(&red[wv][lh * 8])     = make_float4(a0, a1, a2, a3);
        *reinterpret_cast<float4*>(&red[wv][lh * 8 + 4]) = make_float4(a4, a5, a6, a7);
    }
    __syncthreads();
    int col = threadIdx.x;
    float s = red[0][col] + red[1][col] + red[2][col] + red[3][col];
    out[(size_t)c * ostride + col] = f2bf(s);
}

// ---------------- m97-style GEMM (cells): relu(A[M,768] @ W^T + bias) -------
__global__ __launch_bounds__(256, 2) void gemm_tile(
        const unsigned short* __restrict__ A,    // [M][768]
        const unsigned short* __restrict__ W,    // [256][768]
        const float* __restrict__ bias,          // [256]
        const float* __restrict__ wrow,          // nullable per-row scale for vout
        unsigned short* __restrict__ xout, long xstride,
        unsigned short* __restrict__ vout,       // nullable, same stride
        int M) {
    __shared__ unsigned short As[128 * 64];
    __shared__ unsigned short Bs[128 * 64];
    int tid = threadIdx.x;
    int wv = tid >> 6, ln = tid & 63;
    int lm = ln & 15, lq = ln >> 4;
    int m0 = blockIdx.x * 128;
    int nb = blockIdx.y * 128;
    int m0w = m0 + (wv >> 1) * 64;
    int n0w = nb + (wv & 1) * 64;

    f32x4 acc[4][4];
#pragma unroll
    for (int i = 0; i < 4; ++i)
#pragma unroll
        for (int j = 0; j < 4; ++j) acc[i][j] = f32x4{0.f, 0.f, 0.f, 0.f};

    for (int k0 = 0; k0 < KCAT; k0 += 64) {
#pragma unroll
        for (int t = 0; t < 4; ++t) {
            int ci = t * 256 + tid;
            int r = ci >> 3, s = ci & 7;
            int cg = s ^ (r & 7);
            int row = m0 + r; if (row >= M) row = M - 1;
            async16(A + (size_t)row * KCAT + k0 + cg * 8,
                    (unsigned char*)As + ci * 16);
        }
#pragma unroll
        for (int t = 0; t < 4; ++t) {
            int ci = t * 256 + tid;
            int r = ci >> 3, s = ci & 7;
            int cg = s ^ (r & 7);
            async16(W + (size_t)(nb + r) * KCAT + k0 + cg * 8,
                    (unsigned char*)Bs + ci * 16);
        }
        __syncthreads();
#pragma unroll
        for (int kk = 0; kk < 2; ++kk) {
            bf16x8 a[4], b[4];
#pragma unroll
            for (int i = 0; i < 4; ++i) {
                int r = (wv >> 1) * 64 + i * 16 + lm;
                int c = kk * 4 + lq;
                int s = c ^ (r & 7);
                a[i] = *reinterpret_cast<const bf16x8*>(As + (r * 8 + s) * 8);
            }
#pragma unroll
            for (int j = 0; j < 4; ++j) {
                int r = (wv & 1) * 64 + j * 16 + lm;
                int c = kk * 4 + lq;
                int s = c ^ (r & 7);
                b[j] = *reinterpret_cast<const bf16x8*>(Bs + (r * 8 + s) * 8);
            }
#pragma unroll
            for (int i = 0; i < 4; ++i)
#pragma unroll
                for (int j = 0; j < 4; ++j)
                    acc[i][j] = __builtin_amdgcn_mfma_f32_16x16x32_bf16(a[i], b[j], acc[i][j], 0, 0, 0);
        }
        __syncthreads();
    }

#pragma unroll
    for (int i = 0; i < 4; ++i) {
#pragma unroll
        for (int r4 = 0; r4 < 4; ++r4) {
            int rr = m0w + i * 16 + lq * 4 + r4;
            if (rr >= M) continue;
            float wr = wrow ? wrow[rr] : 0.f;
#pragma unroll
            for (int j = 0; j < 4; ++j) {
                int col = n0w + j * 16 + lm;
                float v = acc[i][j][r4] + bias[col];
                v = v > 0.f ? v : 0.f;
                xout[(size_t)rr * xstride + col] = f2bf(v);
                if (vout) vout[(size_t)rr * xstride + col] = f2bf(v * wr);
            }
        }
    }
}

// ---------------- final projection: out = xc2 @ Wout^T + bout (fp32) --------
// Wout staged in LDS (f32, +1 pad -> conflict-free) in two 32-row passes;
// Block = 8 cells x 32 outs per pass.
__global__ __launch_bounds__(256) void out_kernel(const unsigned short* __restrict__ xc,
                                                  const float* __restrict__ Wout,
                                                  const float* __restrict__ bout,
                                                  float* __restrict__ out) {
    __shared__ float srow[8][D];            // 8 KB
    __shared__ float wlds[32][D + 1];       // 32.1 KB
    int tid = threadIdx.x;
    // stage 8 cell rows (bf16 -> f32)
    for (int t = tid; t < 8 * D; t += 256) {
        int rr = blockIdx.x * 8 + (t >> 8);
        unsigned short h = xc[(size_t)rr * D + (t & 255)];
        srow[t >> 8][t & 255] = __uint_as_float(((unsigned)h) << 16);
    }
    int r = tid >> 5, ol = tid & 31;
    float res[2];
#pragma unroll
    for (int p = 0; p < 2; ++p) {
        __syncthreads();
        // stage 32 Wout rows (coalesced float4 global, scalar LDS writes)
        for (int t = tid; t < 32 * (D / 4); t += 256) {
            int o = t >> 6, k4 = (t & 63) * 4;
            float4 wv = *reinterpret_cast<const float4*>(Wout + (size_t)(p * 32 + o) * D + k4);
            wlds[o][k4 + 0] = wv.x; wlds[o][k4 + 1] = wv.y;
            wlds[o][k4 + 2] = wv.z; wlds[o][k4 + 3] = wv.w;
        }
        __syncthreads();
        float s = 0.f;
        for (int k = 0; k < D; ++k) s += srow[r][k] * wlds[ol][k];
        res[p] = s;
    }
    int c = blockIdx.x * 8 + r;
    out[(size_t)c * NOUTD + ol] = res[0] + bout[ol];
    out[(size_t)c * NOUTD + 32 + ol] = res[1] + bout[32 + ol];
}

// ---------------- orchestration ---------------------------------------------
extern "C" void kernel_launch(void* const* d_in, const int* in_sizes, int n_in,
                              void* d_out, int out_size, void* d_ws, size_t ws_size,
                              hipStream_t stream) {
    const float* x_gene = (const float*)d_in[0];
    const float* x_cell = (const float*)d_in[1];
    const int*   src_g2c = (const int*)d_in[2];
    const int*   dst_g2c = (const int*)d_in[3];
    const int*   src_c2g = (const int*)d_in[4];
    const int*   dst_c2g = (const int*)d_in[5];
    const float* w_g2c = (const float*)d_in[8];
    const float* w_c2g = (const float*)d_in[9];
    const float* w_gg  = (const float*)d_in[10];
    const float* w_cc  = (const float*)d_in[11];
    const float* Wrel  = (const float*)d_in[12];
    const float* brel  = (const float*)d_in[13];
    const float* Wroot = (const float*)d_in[14];
    const float* Wout  = (const float*)d_in[15];
    const float* bout  = (const float*)d_in[16];
    float* out = (float*)d_out;

    char* p = (char*)d_ws;
    auto alloc = [&](size_t bytes) -> char* {
        char* r = p;
        p += (bytes + 255) & ~(size_t)255;
        return r;
    };

    unsigned short* xg0b    = (unsigned short*)alloc((size_t)NG * D * 2);
    unsigned short* xg1     = (unsigned short*)alloc((size_t)NG * D * 2);
    unsigned short* agg_g   = (unsigned short*)alloc((size_t)NG * D * 2);
    unsigned short* Acat_c0 = (unsigned short*)alloc((size_t)NC * KCAT * 2);
    unsigned short* Acat_c1 = (unsigned short*)alloc((size_t)NC * KCAT * 2);
    unsigned short* xc2     = (unsigned short*)alloc((size_t)NC * D * 2);
    int* rp_g  = (int*)alloc((NG + 1) * 4);
    int* rp_c  = (int*)alloc((NC + 1) * 4);
    int2* ec = (int2*)alloc((size_t)NE * 8);       // g2c edges grouped by cell
    int2* eg = (int2*)alloc((size_t)NE * 8);       // c2g edges grouped by gene
    int2* st_c = (int2*)alloc((size_t)NE * 8);     // coarse-bucketed staging
    int2* st_g = (int2*)alloc((size_t)NE * 8);
    int* hist512 = (int*)alloc(512 * 4);
    int* cbase   = (int*)alloc(514 * 4);
    int* ccur_c  = (int*)alloc(256 * 4);
    int* ccur_g  = (int*)alloc(256 * 4);
    unsigned short* Wg0 = (unsigned short*)alloc((size_t)D * KCAT * 2);
    unsigned short* Wc0 = (unsigned short*)alloc((size_t)D * KCAT * 2);
    unsigned short* Wc1 = (unsigned short*)alloc((size_t)D * KCAT * 2);
    float* bg0 = (float*)alloc(D * 4);
    float* bc0 = (float*)alloc(D * 4);
    float* bc1 = (float*)alloc(D * 4);

    hipMemsetAsync(hist512, 0, 512 * 4, stream);

    // ---- FUSED front end: hist | x_gene conv | cell prep | weight build ----
    front_fused<<<CCB + CONVB + PREPB + WB3, 256, 0, stream>>>(
        dst_g2c, dst_c2g, hist512, x_gene, xg0b,
        x_cell, w_cc, Acat_c0 + 256, Acat_c0 + 512,
        Wrel, Wroot, brel, Wg0, Wc0, Wc1, bg0, bc0, bc1);

    coarse_scan<<<1, 256, 0, stream>>>(hist512, cbase, ccur_c, ccur_g, rp_c, rp_g);
    const int P1B = (NE + P1_CHUNK - 1) / P1_CHUNK;
    bucket_pass1<<<dim3(P1B, 2), 256, 0, stream>>>(
        src_g2c, dst_g2c, w_g2c, ccur_c, st_c,
        src_c2g, dst_c2g, w_c2g, ccur_g, st_g);
    bucket_pass2<<<P2_CBLK + P2_GBLK, 256, 0, stream>>>(
        st_c, ec, rp_c, st_g, eg, rp_g, cbase);
    // per-cell gene-grouping (finer gene>>8 windows, round 15)
    group_cell_edges<<<NC, 256, 0, stream>>>(rp_c, ec);

    // ---- FUSED: agg_cell L0 (blocks 0..NC) ∥ agg_gene (rest) ----
    agg_fused<<<NC + (NG + 3) / 4, 256, 0, stream>>>(
        rp_g, eg, Acat_c0 + 256, agg_g,
        rp_c, ec, xg0b, Acat_c0);

    // ---- gene GEMM ----
    gene_gemm<<<dim3((NG + 127) / 128, 2), 256, 0, stream>>>(
        agg_g, xg0b, w_gg, Wg0, bg0, xg1);

    // ---- Layer 0 cell GEMM ----
    gemm_tile<<<dim3((NC + 127) / 128, 2), 256, 0, stream>>>(
        Acat_c0, Wc0, bc0, w_cc, Acat_c1 + 256, KCAT, Acat_c1 + 512, NC);

    // ---- Layer 1 cells ----
    agg_cell<<<NC, 256, 0, stream>>>(rp_c, ec, xg1, D, Acat_c1, KCAT);
    gemm_tile<<<dim3((NC + 127) / 128, 2), 256, 0, stream>>>(
        Acat_c1, Wc1, bc1, nullptr, xc2, D, nullptr, NC);

    // ---- output projection ----
    out_kernel<<<NC / 8, 256, 0, stream>>>(xc2, Wout, bout, out);
}